// Round 6
// baseline (1730.700 us; speedup 1.0000x reference)
//
#include <hip/hip_runtime.h>
#include <stdint.h>

typedef __attribute__((ext_vector_type(8))) short bf16x8;
typedef __attribute__((ext_vector_type(4))) float f32x4;
typedef __attribute__((ext_vector_type(8))) unsigned short u16x8;
typedef __attribute__((ext_vector_type(4))) unsigned short u16x4;

#define DI static __device__ __forceinline__

constexpr int CB = 8;          // batch (total)
constexpr int BCH = 4;         // batches per chunk (2 chunks)
constexpr int CC = 512;        // channels
constexpr int CN = 4096;       // H*W
constexpr int K1 = CC * 9;     // 4608
constexpr int K2 = 2 * K1;     // 9216: packed A = [W_hi | W_lo]
constexpr int MR = 3 * CC;     // 1536 output rows (q|k|v)
constexpr int KSPL = 4;        // QK^T split-K factor
constexpr size_t XSPLIT = (size_t)BCH * 66 * 66 * 512;

DI unsigned short f2bf(float f) {
  union { float f; uint32_t u; } v; v.f = f;
  uint32_t r = (v.u + 0x7FFFu + ((v.u >> 16) & 1u)) >> 16;  // RNE
  return (unsigned short)r;
}
DI float bf2f(unsigned short h) {
  union { uint32_t u; float f; } v; v.u = ((uint32_t)h) << 16;
  return v.f;
}

DI void g2lds16(const void* g, void* l) {
  __builtin_amdgcn_global_load_lds((const __attribute__((address_space(1))) void*)g,
                                   (__attribute__((address_space(3))) void*)l, 16, 0, 0);
}
#define SBAR()  __builtin_amdgcn_s_barrier()
#define SCHED() __builtin_amdgcn_sched_barrier(0)

// ---- prep 1: padded channels-last hi/lo copies of x (one chunk) ------------
__global__ __launch_bounds__(256) void prep_xpad(const float* __restrict__ x,
                                                 unsigned short* __restrict__ Xpad) {
  int tid = threadIdx.x;
  int w = tid & 63;
  int ccl = tid >> 6;
  int blk = blockIdx.x;               // 4096 = b(4) * ccg(16) * h(64)
  int h = blk & 63;
  int ccg = (blk >> 6) & 15;
  int b = blk >> 10;
  int c0 = (ccg * 4 + ccl) * 8;
  const float* xp = x + ((size_t)b * CC) * CN + h * 64 + w;
  u16x8 hi, lo;
#pragma unroll
  for (int j = 0; j < 8; ++j) {
    float v = xp[(size_t)(c0 + j) * CN];
    unsigned short h16 = f2bf(v);
    hi[j] = h16;
    lo[j] = f2bf(v - bf2f(h16));
  }
  size_t po = (((size_t)b * 66 + (h + 1)) * 66 + (w + 1)) * 512 + c0;
  *(u16x8*)&Xpad[po] = hi;
  *(u16x8*)&Xpad[XSPLIT + po] = lo;
}

// ---- prep 2: packed A matrix [1536 x 9216] + bias[1536] --------------------
__global__ __launch_bounds__(256) void prep_abig(
    const float* __restrict__ wq, const float* __restrict__ wk,
    const float* __restrict__ wv, const float* __restrict__ bq,
    const float* __restrict__ bk, const float* __restrict__ bv,
    unsigned short* __restrict__ Abig, float* __restrict__ bias) {
  unsigned id = blockIdx.x * 256 + threadIdx.x;   // total 1536*9216
  int m = id / K2;
  int kk = id - m * K2;
  int third = kk / K1;
  int r = kk - third * K1;
  int t = r >> 9;
  int c = r & 511;
  int ky = t / 3;
  int kx = t - ky * 3;
  unsigned short oval;
  if (m < 1024) {
    const float* wp = (m < 512) ? wq : wk;
    int mm = (m < 512) ? m : m - 512;
    float wval = wp[(((size_t)mm * 512 + c) * 3 + ky) * 3 + kx];
    unsigned short h16 = f2bf(wval);
    oval = (third == 0) ? h16 : f2bf(wval - bf2f(h16));
  } else {
    oval = 0;
    if (third == 0) oval = f2bf(wv[(((size_t)(m - 1024) * 512 + c) * 3 + ky) * 3 + kx]);
  }
  Abig[id] = oval;
  if (id < 1536) {
    int mm = (int)id;
    bias[mm] = (mm < 512) ? bq[mm] : (mm < 1024) ? bk[mm - 512] : bv[mm - 1024];
  }
}

// ---- conv GEMM: 256x256 tile, BK=32, 3-slot LDS ring, counted vmcnt --------
// 8 waves (2M x 4N), per-wave 128x64 = 8x4 frags of 16x16x32.
// Slot = A[256][32] + B[256][32] bf16 (linear; 64B rows are bank-uniform for
// ds_read_b128 so no swizzle needed). Stage(t+2) issued at ktile t; vmcnt(8)
// (= 2 stages x 4 loads in flight) guarantees stage(t) landed. Raw s_barrier
// (no compiler vmcnt(0) drain) + sched_barrier fences.
__global__ __launch_bounds__(512, 2) void conv_k(
    const unsigned short* __restrict__ Abig,
    const unsigned short* __restrict__ Xpad,
    const float* __restrict__ bias,
    unsigned short* __restrict__ Qhi, unsigned short* __restrict__ Qlo,
    unsigned short* __restrict__ Khi, unsigned short* __restrict__ Klo,
    unsigned short* __restrict__ Vt)
{
  __shared__ __align__(16) unsigned char smem[3 * 32768];
  const int tid = threadIdx.x;
  const int lane = tid & 63;
  const int wid = tid >> 6;           // 0..7
  const int wr = wid >> 2;            // 0..1 (M)
  const int wc = wid & 3;             // 0..3 (N)

  // bijective XCD swizzle (nwg=384, %8==0): 48 consecutive per XCD =
  // 8 n-panels x 6 m-blocks -> B window reused 6x, A panels via L3.
  constexpr int nwg = 6 * (BCH * CN / 256);   // 384
  int orig = blockIdx.x;
  int swz = (orig & 7) * (nwg >> 3) + (orig >> 3);
  int mb = swz % 6;
  int nb = swz / 6;
  const int m0 = mb * 256;
  const int n0 = nb * 256;
  const int bidx = n0 >> 12;
  const int nl0 = n0 & (CN - 1);
  const int h0 = nl0 >> 6;
  const int NT = (m0 >= 1024) ? 144 : 432;    // BK=32 ktiles (v: s=0 only)

  // per-thread staging bases (once): thread covers 16B chunk (row=tid>>2, cu=tid&3)
  // in each 128-row half of A and B.
  const int srow = tid >> 2;          // 0..127
  const int scu = tid & 3;
  const unsigned short* gA0 = Abig + (size_t)(m0 + srow) * K2 + scu * 8;
  const unsigned short* gA1 = gA0 + (size_t)128 * K2;
  const unsigned short* gB0 = Xpad +
      (((size_t)(bidx * 66 + h0 + (srow >> 6))) * 66 + (srow & 63)) * 512 + scu * 8;
  const unsigned short* gB1 = gB0 + (size_t)2 * 66 * 512;
  const int wofs = wid * 1024;        // wave-uniform LDS byte base within half

  // stage cursor (block-uniform scalars): K order = s / tap(ky,kx) / c0
  int c0S = 0, tapS = 0, kxS = 0, sS = 0, aT = 0;
  size_t sh = 0, tapOfs = 0;

  auto stageS = [&](int slot) {
    int aOfs = aT + tapS * 512 + c0S;
    size_t bOfs = sh + tapOfs + (size_t)c0S;
    unsigned char* lA = smem + slot * 32768 + wofs;
    unsigned char* lB = smem + slot * 32768 + 16384 + wofs;
    g2lds16(gA0 + aOfs, lA);
    g2lds16(gA1 + aOfs, lA + 8192);
    g2lds16(gB0 + bOfs, lB);
    g2lds16(gB1 + bOfs, lB + 8192);
    // advance cursor
    c0S += 32;
    if (c0S == 512) {
      c0S = 0;
      ++tapS;
      if (tapS == 9) {
        tapS = 0; kxS = 0; tapOfs = 0;
        ++sS;
        aT = (sS == 2) ? K1 : 0;
        sh = (sS == 1) ? XSPLIT : 0;
      } else if (kxS == 2) { kxS = 0; tapOfs += (size_t)64 * 512; }  // ky++
      else { ++kxS; tapOfs += 512; }
    }
  };

  f32x4 acc[8][4];
  const f32x4 fz = {0.f, 0.f, 0.f, 0.f};
#pragma unroll
  for (int i = 0; i < 8; ++i)
#pragma unroll
    for (int j = 0; j < 4; ++j) acc[i][j] = fz;

  const int rA = wr * 128 + (lane & 15);
  const int rB = wc * 64 + (lane & 15);
  const int kq = (lane >> 4) * 16;    // byte offset in 64B LDS row

  stageS(0);
  stageS(1);
  int slotC = 0, slotS = 2;

  for (int t = 0; t < NT; ++t) {
    if (t + 2 < NT) {
      stageS(slotS);
      slotS = (slotS == 2) ? 0 : slotS + 1;
      asm volatile("s_waitcnt vmcnt(8)" ::: "memory");
    } else if (t + 2 == NT) {
      asm volatile("s_waitcnt vmcnt(4)" ::: "memory");
    } else {
      asm volatile("s_waitcnt vmcnt(0)" ::: "memory");
    }
    SCHED();
    SBAR();                           // slot slotC fully staged, all waves
    SCHED();

    const unsigned char* lA = smem + slotC * 32768;
    const unsigned char* lB = lA + 16384;
    bf16x8 af0[4], af1[4], bfr[4];
#pragma unroll
    for (int mf = 0; mf < 4; ++mf)
      af0[mf] = *(const bf16x8*)(lA + (rA + mf * 16) * 64 + kq);
#pragma unroll
    for (int nf = 0; nf < 4; ++nf)
      bfr[nf] = *(const bf16x8*)(lB + (rB + nf * 16) * 64 + kq);
#pragma unroll
    for (int mf = 0; mf < 4; ++mf)
      af1[mf] = *(const bf16x8*)(lA + (rA + 64 + mf * 16) * 64 + kq);

    __builtin_amdgcn_s_setprio(1);
#pragma unroll
    for (int mf = 0; mf < 4; ++mf)
#pragma unroll
      for (int nf = 0; nf < 4; ++nf)
        acc[mf][nf] = __builtin_amdgcn_mfma_f32_16x16x32_bf16(
            af0[mf], bfr[nf], acc[mf][nf], 0, 0, 0);
    __builtin_amdgcn_s_setprio(0);
    __builtin_amdgcn_s_setprio(1);
#pragma unroll
    for (int mf = 0; mf < 4; ++mf)
#pragma unroll
      for (int nf = 0; nf < 4; ++nf)
        acc[mf + 4][nf] = __builtin_amdgcn_mfma_f32_16x16x32_bf16(
            af1[mf], bfr[nf], acc[mf + 4][nf], 0, 0, 0);
    __builtin_amdgcn_s_setprio(0);

    slotC = (slotC == 2) ? 0 : slotC + 1;
    SCHED();
    SBAR();                           // slot slotC reads done -> reusable
    SCHED();
  }

  // ---- epilogue: C/D layout col=lane&15, row=(lane>>4)*4+j ----
#pragma unroll
  for (int mf = 0; mf < 8; ++mf) {
#pragma unroll
    for (int nf = 0; nf < 4; ++nf) {
      f32x4 a = acc[mf][nf];
      int mrow = m0 + wr * 128 + mf * 16 + ((lane >> 4) << 2);
      int ncol = nl0 + wc * 64 + nf * 16 + (lane & 15);
      if (m0 < 512) {
#pragma unroll
        for (int j = 0; j < 4; ++j) {
          float v = a[j] + bias[mrow + j];
          unsigned short h16 = f2bf(v);
          size_t o = ((size_t)bidx * CC + (mrow + j)) * CN + ncol;
          Qhi[o] = h16;
          Qlo[o] = f2bf(v - bf2f(h16));
        }
      } else if (m0 < 1024) {
#pragma unroll
        for (int j = 0; j < 4; ++j) {
          float v = a[j] + bias[mrow + j];
          unsigned short h16 = f2bf(v);
          size_t o = ((size_t)bidx * CC + (mrow + j - 512)) * CN + ncol;
          Khi[o] = h16;
          Klo[o] = f2bf(v - bf2f(h16));
        }
      } else {
        u16x4 vs;                     // V written transposed: Vt[b][n][d]
#pragma unroll
        for (int j = 0; j < 4; ++j) vs[j] = f2bf(a[j] + bias[mrow + j]);
        *(u16x4*)&Vt[((size_t)bidx * CN + ncol) * CC + (mrow - 1024)] = vs;
      }
    }
  }
}

// ---- MFMA GEMM: MODE 1=QK^T (3-phase hi/lo, split-K), 2=PV -----------------
// (round-5 verified structure: 128x128, 4 waves, gload_lds + XOR-swizzled LDS)
DI int sofs(int row, int kb) { return row * 128 + (kb ^ ((row & 7) << 4)); }

template<int MODE>
__global__ __launch_bounds__(256) void gemm_k(
    const unsigned short* __restrict__ Qhi, const unsigned short* __restrict__ Qlo,
    const unsigned short* __restrict__ Khi, const unsigned short* __restrict__ Klo,
    const unsigned short* __restrict__ Vt,
    float* __restrict__ attn,
    const unsigned short* __restrict__ P,
    const float* __restrict__ xin,
    const float* __restrict__ gamma,
    float* __restrict__ out)
{
  __shared__ __align__(16) unsigned char sA[16384];
  __shared__ __align__(16) unsigned char sB[16384];
  const int tid = threadIdx.x;
  const int lane = tid & 63;
  const int wav = tid >> 6;
  const int wr = wav >> 1, wc = wav & 1;

  int m0, n0, bidx, Kbeg = 0, Kend, ks = 0;
  if constexpr (MODE == 1) {
    int tile = blockIdx.x & 15;
    ks = blockIdx.x >> 4;
    m0 = (tile & 3) * 128;
    n0 = (tile >> 2) * 128;
    bidx = blockIdx.z;
    Kbeg = ks * (3 * CN / KSPL);
    Kend = Kbeg + (3 * CN / KSPL);
  } else {
    m0 = (blockIdx.x & 3) * 128;
    n0 = (blockIdx.x >> 2) * 128;
    bidx = blockIdx.z;
    Kend = CC;
  }

  auto stage = [&](int k0) {
#pragma unroll
    for (int q = 0; q < 4; ++q) {
      int ci = q * 256 + tid;
      int row = ci >> 3;
      int ke = ((ci & 7) ^ (row & 7)) * 8;
      const unsigned short* ap;
      const unsigned short* bp;
      if constexpr (MODE == 1) {
        int ph = k0 >> 12;
        int kin = k0 & (CN - 1);
        const unsigned short* Aq = (ph == 2) ? Qlo : Qhi;
        const unsigned short* Bk = (ph == 1) ? Klo : Khi;
        ap = Aq + ((size_t)bidx * CC + (m0 + row)) * CN + (kin + ke);
        bp = Bk + ((size_t)bidx * CC + (n0 + row)) * CN + (kin + ke);
      } else {
        ap = P + ((size_t)bidx * CC + (m0 + row)) * CC + (k0 + ke);
        bp = Vt + ((size_t)bidx * CN + (n0 + row)) * CC + (k0 + ke);
      }
      int wbase = (q * 256 + wav * 64) * 16;
      g2lds16(ap, sA + wbase);
      g2lds16(bp, sB + wbase);
    }
  };

  f32x4 acc[4][4];
  const f32x4 fz = {0.f, 0.f, 0.f, 0.f};
#pragma unroll
  for (int i = 0; i < 4; ++i)
#pragma unroll
    for (int j = 0; j < 4; ++j) acc[i][j] = fz;

  for (int k0 = Kbeg; k0 < Kend; k0 += 64) {
    stage(k0);
    __syncthreads();
#pragma unroll
    for (int kkp = 0; kkp < 2; ++kkp) {
      bf16x8 af[4], bfv[4];
#pragma unroll
      for (int mf = 0; mf < 4; ++mf)
        af[mf] = *(const bf16x8*)&sA[sofs(wr * 64 + mf * 16 + (lane & 15),
                                          kkp * 64 + (lane >> 4) * 16)];
#pragma unroll
      for (int nf = 0; nf < 4; ++nf)
        bfv[nf] = *(const bf16x8*)&sB[sofs(wc * 64 + nf * 16 + (lane & 15),
                                           kkp * 64 + (lane >> 4) * 16)];
#pragma unroll
      for (int mf = 0; mf < 4; ++mf)
#pragma unroll
        for (int nf = 0; nf < 4; ++nf)
          acc[mf][nf] = __builtin_amdgcn_mfma_f32_16x16x32_bf16(
              af[mf], bfv[nf], acc[mf][nf], 0, 0, 0);
    }
    __syncthreads();
  }

  float g = 0.f;
  if constexpr (MODE == 2) g = gamma[0];
#pragma unroll
  for (int mf = 0; mf < 4; ++mf) {
#pragma unroll
    for (int nf = 0; nf < 4; ++nf) {
      f32x4 a = acc[mf][nf];
      int mrow = m0 + wr * 64 + mf * 16 + ((lane >> 4) << 2);
      int ncol = n0 + wc * 64 + nf * 16 + (lane & 15);
      if constexpr (MODE == 1) {
        size_t pbase = (size_t)ks * ((size_t)BCH * CC * CC);
#pragma unroll
        for (int j = 0; j < 4; ++j)
          attn[pbase + ((size_t)bidx * CC + (mrow + j)) * CC + ncol] = a[j];
      } else {
#pragma unroll
        for (int j = 0; j < 4; ++j) {
          size_t o = ((size_t)bidx * CC + (mrow + j)) * CN + ncol;
          out[o] = g * a[j] + xin[o];
        }
      }
    }
  }
}

// ---- softmax over d (512): sum KSPL split-K partials, one wave per row -----
__global__ __launch_bounds__(256) void softmax_k(const float* __restrict__ attn,
                                                 unsigned short* __restrict__ P) {
  int row = blockIdx.x * 4 + (threadIdx.x >> 6);
  int lane = threadIdx.x & 63;
  constexpr size_t PS = (size_t)BCH * CC * CC;
  const float* rp = attn + (size_t)row * 512 + lane * 8;
  f32x4 a = {0.f, 0.f, 0.f, 0.f};
  f32x4 b = {0.f, 0.f, 0.f, 0.f};
#pragma unroll
  for (int ksp = 0; ksp < KSPL; ++ksp) {
    a += *(const f32x4*)(rp + (size_t)ksp * PS);
    b += *(const f32x4*)(rp + (size_t)ksp * PS + 4);
  }
  float mx = fmaxf(fmaxf(fmaxf(a[0], a[1]), fmaxf(a[2], a[3])),
                   fmaxf(fmaxf(b[0], b[1]), fmaxf(b[2], b[3])));
#pragma unroll
  for (int s = 32; s > 0; s >>= 1) mx = fmaxf(mx, __shfl_xor(mx, s, 64));
  float e[8];
  float sum = 0.f;
#pragma unroll
  for (int j = 0; j < 4; ++j) { e[j] = __expf(a[j] - mx); sum += e[j]; }
#pragma unroll
  for (int j = 0; j < 4; ++j) { e[4 + j] = __expf(b[j] - mx); sum += e[4 + j]; }
#pragma unroll
  for (int s = 32; s > 0; s >>= 1) sum += __shfl_xor(sum, s, 64);
  float inv = 1.0f / sum;
  u16x8 o;
#pragma unroll
  for (int j = 0; j < 8; ++j) o[j] = f2bf(e[j] * inv);
  *(u16x8*)&P[(size_t)row * 512 + lane * 8] = o;
}

// ---- diagnostic: fill out with sentinel if workspace is too small ----------
__global__ __launch_bounds__(256) void fill_sentinel(float* __restrict__ out, int n) {
  int i = blockIdx.x * 256 + threadIdx.x;
  if (i < n) out[i] = 1.0e4f;
}

// ---------------------------------------------------------------------------
extern "C" void kernel_launch(void* const* d_in, const int* in_sizes, int n_in,
                              void* d_out, int out_size, void* d_ws, size_t ws_size,
                              hipStream_t stream) {
  (void)in_sizes; (void)n_in;
  const float* x  = (const float*)d_in[0];
  const float* wq = (const float*)d_in[1];
  const float* bq = (const float*)d_in[2];
  const float* wk = (const float*)d_in[3];
  const float* bk = (const float*)d_in[4];
  const float* wv = (const float*)d_in[5];
  const float* bv = (const float*)d_in[6];
  const float* gm = (const float*)d_in[7];
  float* out = (float*)d_out;

  uint8_t* wsp = (uint8_t*)d_ws;
  auto take = [&](size_t bytes) {
    uint8_t* p = wsp;
    wsp += (bytes + 255) & ~(size_t)255;
    return p;
  };
  unsigned short* Xpad = (unsigned short*)take(2 * XSPLIT * sizeof(unsigned short)); // 35.7 MB
  unsigned short* Abig = (unsigned short*)take((size_t)MR * K2 * 2);                 // 28.3 MB
  float* bias          = (float*)take((size_t)MR * 4);
  unsigned short* Khi  = (unsigned short*)take((size_t)BCH * CC * CN * 2);           // 16.8 MB
  unsigned short* Klo  = (unsigned short*)take((size_t)BCH * CC * CN * 2);           // 16.8 MB
  unsigned short* Vt   = (unsigned short*)take((size_t)BCH * CN * CC * 2);           // 16.8 MB
  float* attn          = (float*)Xpad;   // aliases Xpad (dead after conv)
  unsigned short* P    = (unsigned short*)((uint8_t*)Xpad +
                           (size_t)KSPL * BCH * CC * CC * 4 + 256);

  size_t needed = (size_t)(wsp - (uint8_t*)d_ws);   // ~114.5 MB
  if (ws_size < needed) {
    fill_sentinel<<<(out_size + 255) / 256, 256, 0, stream>>>(out, out_size);
    return;
  }

  for (int ch = 0; ch < CB / BCH; ++ch) {
    const float* xch = x + (size_t)ch * BCH * CC * CN;
    float* outch = out + (size_t)ch * BCH * CC * CN;
    unsigned short* Qhi = (unsigned short*)outch;   // Q pair lives in d_out
    unsigned short* Qlo = Qhi + (size_t)BCH * CC * CN;

    hipMemsetAsync(Xpad, 0, 2 * XSPLIT * sizeof(unsigned short), stream);
    prep_xpad<<<BCH * 16 * 64, 256, 0, stream>>>(xch, Xpad);
    if (ch == 0)
      prep_abig<<<(MR * K2) / 256, 256, 0, stream>>>(wq, wk, wv, bq, bk, bv, Abig, bias);
    conv_k<<<dim3(6 * BCH * 16), 512, 0, stream>>>(Abig, Xpad, bias, Qhi, Qlo,
                                                   Khi, Klo, Vt);
    gemm_k<1><<<dim3(16 * KSPL, 1, BCH), 256, 0, stream>>>(Qhi, Qlo, Khi, Klo, Vt,
                                                           attn, P, xch, gm, outch);
    softmax_k<<<BCH * 128, 256, 0, stream>>>(attn, P);
    gemm_k<2><<<dim3(128, 1, BCH), 256, 0, stream>>>(Qhi, Qlo, Khi, Klo, Vt,
                                                     attn, P, xch, gm, outch);
  }
}

// Round 7
// 1583.590 us; speedup vs baseline: 1.0929x; 1.0929x over previous
//
#include <hip/hip_runtime.h>
#include <stdint.h>

typedef __attribute__((ext_vector_type(8))) short bf16x8;
typedef __attribute__((ext_vector_type(4))) float f32x4;
typedef __attribute__((ext_vector_type(8))) unsigned short u16x8;
typedef __attribute__((ext_vector_type(4))) unsigned short u16x4;

#define DI static __device__ __forceinline__

constexpr int CB = 8;          // batch (total)
constexpr int BCH = 4;         // batches per chunk (2 chunks)
constexpr int CC = 512;        // channels
constexpr int CN = 4096;       // H*W
constexpr int K1 = CC * 9;     // 4608
constexpr int K2 = 2 * K1;     // 9216: packed A = [W_hi | W_lo]
constexpr int MR = 3 * CC;     // 1536 output rows (q|k|v)
constexpr int KSPL = 4;        // QK^T split-K factor
constexpr size_t XSPLIT = (size_t)BCH * 66 * 66 * 512;

DI unsigned short f2bf(float f) {
  union { float f; uint32_t u; } v; v.f = f;
  uint32_t r = (v.u + 0x7FFFu + ((v.u >> 16) & 1u)) >> 16;  // RNE
  return (unsigned short)r;
}
DI float bf2f(unsigned short h) {
  union { uint32_t u; float f; } v; v.u = ((uint32_t)h) << 16;
  return v.f;
}

DI void g2lds16(const void* g, void* l) {
  __builtin_amdgcn_global_load_lds((const __attribute__((address_space(1))) void*)g,
                                   (__attribute__((address_space(3))) void*)l, 16, 0, 0);
}
#define SBAR()  __builtin_amdgcn_s_barrier()
#define SCHED() __builtin_amdgcn_sched_barrier(0)

// ---- prep 1: padded channels-last hi/lo copies of x (one chunk) ------------
__global__ __launch_bounds__(256) void prep_xpad(const float* __restrict__ x,
                                                 unsigned short* __restrict__ Xpad) {
  int tid = threadIdx.x;
  int w = tid & 63;
  int ccl = tid >> 6;
  int blk = blockIdx.x;               // 4096 = b(4) * ccg(16) * h(64)
  int h = blk & 63;
  int ccg = (blk >> 6) & 15;
  int b = blk >> 10;
  int c0 = (ccg * 4 + ccl) * 8;
  const float* xp = x + ((size_t)b * CC) * CN + h * 64 + w;
  u16x8 hi, lo;
#pragma unroll
  for (int j = 0; j < 8; ++j) {
    float v = xp[(size_t)(c0 + j) * CN];
    unsigned short h16 = f2bf(v);
    hi[j] = h16;
    lo[j] = f2bf(v - bf2f(h16));
  }
  size_t po = (((size_t)b * 66 + (h + 1)) * 66 + (w + 1)) * 512 + c0;
  *(u16x8*)&Xpad[po] = hi;
  *(u16x8*)&Xpad[XSPLIT + po] = lo;
}

// ---- prep 2: packed A matrix [1536 x 9216] + bias[1536] --------------------
__global__ __launch_bounds__(256) void prep_abig(
    const float* __restrict__ wq, const float* __restrict__ wk,
    const float* __restrict__ wv, const float* __restrict__ bq,
    const float* __restrict__ bk, const float* __restrict__ bv,
    unsigned short* __restrict__ Abig, float* __restrict__ bias) {
  unsigned id = blockIdx.x * 256 + threadIdx.x;   // total 1536*9216
  int m = id / K2;
  int kk = id - m * K2;
  int third = kk / K1;
  int r = kk - third * K1;
  int t = r >> 9;
  int c = r & 511;
  int ky = t / 3;
  int kx = t - ky * 3;
  unsigned short oval;
  if (m < 1024) {
    const float* wp = (m < 512) ? wq : wk;
    int mm = (m < 512) ? m : m - 512;
    float wval = wp[(((size_t)mm * 512 + c) * 3 + ky) * 3 + kx];
    unsigned short h16 = f2bf(wval);
    oval = (third == 0) ? h16 : f2bf(wval - bf2f(h16));
  } else {
    oval = 0;
    if (third == 0) oval = f2bf(wv[(((size_t)(m - 1024) * 512 + c) * 3 + ky) * 3 + kx]);
  }
  Abig[id] = oval;
  if (id < 1536) {
    int mm = (int)id;
    bias[mm] = (mm < 512) ? bq[mm] : (mm < 1024) ? bk[mm - 512] : bv[mm - 1024];
  }
}

// ---- conv GEMM: 256x256 tile, BK=32, 3-slot LDS ring, counted vmcnt --------
// 8 waves (2M x 4N), per-wave 128x64 = 8x4 frags of 16x16x32.
// ROUND-7 FIX: round 6's linear [row][32] layout was an 8-WAY bank conflict on
// ds_read_b128 (bank = (row*16+slot*4)&31 -> 8 lanes per 4-bank set; 4.96e7
// conflicts measured). Both-sides swizzle with f(row)=(row>>1)&3:
//   stage: thread (srow,scu) loads global chunk (scu ^ f(srow))  [per-thread CONST]
//   read:  byte = row*64 + (kq ^ (f(row)<<4));  f const across mf/nf -> folds
//          into a per-thread base. 16-lane group now spreads all 8 bank-quads,
//          2 lanes/bank = free (m136).
__global__ __launch_bounds__(512, 2) void conv_k(
    const unsigned short* __restrict__ Abig,
    const unsigned short* __restrict__ Xpad,
    const float* __restrict__ bias,
    unsigned short* __restrict__ Qhi, unsigned short* __restrict__ Qlo,
    unsigned short* __restrict__ Khi, unsigned short* __restrict__ Klo,
    unsigned short* __restrict__ Vt)
{
  __shared__ __align__(16) unsigned char smem[3 * 32768];
  const int tid = threadIdx.x;
  const int lane = tid & 63;
  const int wid = tid >> 6;           // 0..7
  const int wr = wid >> 2;            // 0..1 (M)
  const int wc = wid & 3;             // 0..3 (N)

  // bijective XCD swizzle (nwg=384, %8==0)
  constexpr int nwg = 6 * (BCH * CN / 256);   // 384
  int orig = blockIdx.x;
  int swz = (orig & 7) * (nwg >> 3) + (orig >> 3);
  int mb = swz % 6;
  int nb = swz / 6;
  const int m0 = mb * 256;
  const int n0 = nb * 256;
  const int bidx = n0 >> 12;
  const int nl0 = n0 & (CN - 1);
  const int h0 = nl0 >> 6;
  const int NT = (m0 >= 1024) ? 144 : 432;    // BK=32 ktiles (v: s=0 only)

  // per-thread staging bases (once); source chunk pre-swizzled by f(srow)
  const int srow = tid >> 2;          // 0..127
  const int scu = tid & 3;
  const int scuS = scu ^ ((srow >> 1) & 3);   // pre-swizzled source chunk
  const unsigned short* gA0 = Abig + (size_t)(m0 + srow) * K2 + scuS * 8;
  const unsigned short* gA1 = gA0 + (size_t)128 * K2;
  const unsigned short* gB0 = Xpad +
      (((size_t)(bidx * 66 + h0 + (srow >> 6))) * 66 + (srow & 63)) * 512 + scuS * 8;
  const unsigned short* gB1 = gB0 + (size_t)2 * 66 * 512;
  const int wofs = wid * 1024;        // wave-uniform LDS byte base within half

  // stage cursor (block-uniform scalars): K order = s / tap(ky,kx) / c0
  int c0S = 0, tapS = 0, kxS = 0, sS = 0, aT = 0;
  size_t sh = 0, tapOfs = 0;

  auto stageS = [&](int slot) {
    int aOfs = aT + tapS * 512 + c0S;
    size_t bOfs = sh + tapOfs + (size_t)c0S;
    unsigned char* lA = smem + slot * 32768 + wofs;
    unsigned char* lB = smem + slot * 32768 + 16384 + wofs;
    g2lds16(gA0 + aOfs, lA);
    g2lds16(gA1 + aOfs, lA + 8192);
    g2lds16(gB0 + bOfs, lB);
    g2lds16(gB1 + bOfs, lB + 8192);
    c0S += 32;
    if (c0S == 512) {
      c0S = 0;
      ++tapS;
      if (tapS == 9) {
        tapS = 0; kxS = 0; tapOfs = 0;
        ++sS;
        aT = (sS == 2) ? K1 : 0;
        sh = (sS == 1) ? XSPLIT : 0;
      } else if (kxS == 2) { kxS = 0; tapOfs += (size_t)64 * 512; }  // ky++
      else { ++kxS; tapOfs += 512; }
    }
  };

  f32x4 acc[8][4];
  const f32x4 fz = {0.f, 0.f, 0.f, 0.f};
#pragma unroll
  for (int i = 0; i < 8; ++i)
#pragma unroll
    for (int j = 0; j < 4; ++j) acc[i][j] = fz;

  const int rA = wr * 128 + (lane & 15);
  const int rB = wc * 64 + (lane & 15);
  const int kq = (lane >> 4) * 16;    // byte offset in 64B LDS row
  // f(row) is invariant under row += multiples of 16 -> fold XOR per thread
  const int kqA = kq ^ (((rA >> 1) & 3) << 4);
  const int kqB = kq ^ (((rB >> 1) & 3) << 4);

  stageS(0);
  stageS(1);
  int slotC = 0, slotS = 2;

  for (int t = 0; t < NT; ++t) {
    if (t + 2 < NT) {
      stageS(slotS);
      slotS = (slotS == 2) ? 0 : slotS + 1;
      asm volatile("s_waitcnt vmcnt(8)" ::: "memory");
    } else if (t + 2 == NT) {
      asm volatile("s_waitcnt vmcnt(4)" ::: "memory");
    } else {
      asm volatile("s_waitcnt vmcnt(0)" ::: "memory");
    }
    SCHED();
    SBAR();                           // slot slotC fully staged, all waves
    SCHED();

    const unsigned char* lA = smem + slotC * 32768;
    const unsigned char* lB = lA + 16384;
    bf16x8 af0[4], af1[4], bfr[4];
#pragma unroll
    for (int mf = 0; mf < 4; ++mf)
      af0[mf] = *(const bf16x8*)(lA + (rA + mf * 16) * 64 + kqA);
#pragma unroll
    for (int nf = 0; nf < 4; ++nf)
      bfr[nf] = *(const bf16x8*)(lB + (rB + nf * 16) * 64 + kqB);
#pragma unroll
    for (int mf = 0; mf < 4; ++mf)
      af1[mf] = *(const bf16x8*)(lA + (rA + 64 + mf * 16) * 64 + kqA);

    __builtin_amdgcn_s_setprio(1);
#pragma unroll
    for (int mf = 0; mf < 4; ++mf)
#pragma unroll
      for (int nf = 0; nf < 4; ++nf)
        acc[mf][nf] = __builtin_amdgcn_mfma_f32_16x16x32_bf16(
            af0[mf], bfr[nf], acc[mf][nf], 0, 0, 0);
    __builtin_amdgcn_s_setprio(0);
    __builtin_amdgcn_s_setprio(1);
#pragma unroll
    for (int mf = 0; mf < 4; ++mf)
#pragma unroll
      for (int nf = 0; nf < 4; ++nf)
        acc[mf + 4][nf] = __builtin_amdgcn_mfma_f32_16x16x32_bf16(
            af1[mf], bfr[nf], acc[mf + 4][nf], 0, 0, 0);
    __builtin_amdgcn_s_setprio(0);

    slotC = (slotC == 2) ? 0 : slotC + 1;
    SCHED();
    SBAR();                           // slot slotC reads done -> reusable
    SCHED();
  }

  // ---- epilogue: C/D layout col=lane&15, row=(lane>>4)*4+j ----
#pragma unroll
  for (int mf = 0; mf < 8; ++mf) {
#pragma unroll
    for (int nf = 0; nf < 4; ++nf) {
      f32x4 a = acc[mf][nf];
      int mrow = m0 + wr * 128 + mf * 16 + ((lane >> 4) << 2);
      int ncol = nl0 + wc * 64 + nf * 16 + (lane & 15);
      if (m0 < 512) {
#pragma unroll
        for (int j = 0; j < 4; ++j) {
          float v = a[j] + bias[mrow + j];
          unsigned short h16 = f2bf(v);
          size_t o = ((size_t)bidx * CC + (mrow + j)) * CN + ncol;
          Qhi[o] = h16;
          Qlo[o] = f2bf(v - bf2f(h16));
        }
      } else if (m0 < 1024) {
#pragma unroll
        for (int j = 0; j < 4; ++j) {
          float v = a[j] + bias[mrow + j];
          unsigned short h16 = f2bf(v);
          size_t o = ((size_t)bidx * CC + (mrow + j - 512)) * CN + ncol;
          Khi[o] = h16;
          Klo[o] = f2bf(v - bf2f(h16));
        }
      } else {
        u16x4 vs;                     // V written transposed: Vt[b][n][d]
#pragma unroll
        for (int j = 0; j < 4; ++j) vs[j] = f2bf(a[j] + bias[mrow + j]);
        *(u16x4*)&Vt[((size_t)bidx * CN + ncol) * CC + (mrow - 1024)] = vs;
      }
    }
  }
}

// ---- MFMA GEMM: MODE 1=QK^T (3-phase hi/lo, split-K), 2=PV -----------------
// (round-5 verified structure: 128x128, 4 waves, gload_lds + XOR-swizzled LDS)
DI int sofs(int row, int kb) { return row * 128 + (kb ^ ((row & 7) << 4)); }

template<int MODE>
__global__ __launch_bounds__(256) void gemm_k(
    const unsigned short* __restrict__ Qhi, const unsigned short* __restrict__ Qlo,
    const unsigned short* __restrict__ Khi, const unsigned short* __restrict__ Klo,
    const unsigned short* __restrict__ Vt,
    float* __restrict__ attn,
    const unsigned short* __restrict__ P,
    const float* __restrict__ xin,
    const float* __restrict__ gamma,
    float* __restrict__ out)
{
  __shared__ __align__(16) unsigned char sA[16384];
  __shared__ __align__(16) unsigned char sB[16384];
  const int tid = threadIdx.x;
  const int lane = tid & 63;
  const int wav = tid >> 6;
  const int wr = wav >> 1, wc = wav & 1;

  int m0, n0, bidx, Kbeg = 0, Kend, ks = 0;
  if constexpr (MODE == 1) {
    int tile = blockIdx.x & 15;
    ks = blockIdx.x >> 4;
    m0 = (tile & 3) * 128;
    n0 = (tile >> 2) * 128;
    bidx = blockIdx.z;
    Kbeg = ks * (3 * CN / KSPL);
    Kend = Kbeg + (3 * CN / KSPL);
  } else {
    m0 = (blockIdx.x & 3) * 128;
    n0 = (blockIdx.x >> 2) * 128;
    bidx = blockIdx.z;
    Kend = CC;
  }

  auto stage = [&](int k0) {
#pragma unroll
    for (int q = 0; q < 4; ++q) {
      int ci = q * 256 + tid;
      int row = ci >> 3;
      int ke = ((ci & 7) ^ (row & 7)) * 8;
      const unsigned short* ap;
      const unsigned short* bp;
      if constexpr (MODE == 1) {
        int ph = k0 >> 12;
        int kin = k0 & (CN - 1);
        const unsigned short* Aq = (ph == 2) ? Qlo : Qhi;
        const unsigned short* Bk = (ph == 1) ? Klo : Khi;
        ap = Aq + ((size_t)bidx * CC + (m0 + row)) * CN + (kin + ke);
        bp = Bk + ((size_t)bidx * CC + (n0 + row)) * CN + (kin + ke);
      } else {
        ap = P + ((size_t)bidx * CC + (m0 + row)) * CC + (k0 + ke);
        bp = Vt + ((size_t)bidx * CN + (n0 + row)) * CC + (k0 + ke);
      }
      int wbase = (q * 256 + wav * 64) * 16;
      g2lds16(ap, sA + wbase);
      g2lds16(bp, sB + wbase);
    }
  };

  f32x4 acc[4][4];
  const f32x4 fz = {0.f, 0.f, 0.f, 0.f};
#pragma unroll
  for (int i = 0; i < 4; ++i)
#pragma unroll
    for (int j = 0; j < 4; ++j) acc[i][j] = fz;

  for (int k0 = Kbeg; k0 < Kend; k0 += 64) {
    stage(k0);
    __syncthreads();
#pragma unroll
    for (int kkp = 0; kkp < 2; ++kkp) {
      bf16x8 af[4], bfv[4];
#pragma unroll
      for (int mf = 0; mf < 4; ++mf)
        af[mf] = *(const bf16x8*)&sA[sofs(wr * 64 + mf * 16 + (lane & 15),
                                          kkp * 64 + (lane >> 4) * 16)];
#pragma unroll
      for (int nf = 0; nf < 4; ++nf)
        bfv[nf] = *(const bf16x8*)&sB[sofs(wc * 64 + nf * 16 + (lane & 15),
                                           kkp * 64 + (lane >> 4) * 16)];
#pragma unroll
      for (int mf = 0; mf < 4; ++mf)
#pragma unroll
        for (int nf = 0; nf < 4; ++nf)
          acc[mf][nf] = __builtin_amdgcn_mfma_f32_16x16x32_bf16(
              af[mf], bfv[nf], acc[mf][nf], 0, 0, 0);
    }
    __syncthreads();
  }

  float g = 0.f;
  if constexpr (MODE == 2) g = gamma[0];
#pragma unroll
  for (int mf = 0; mf < 4; ++mf) {
#pragma unroll
    for (int nf = 0; nf < 4; ++nf) {
      f32x4 a = acc[mf][nf];
      int mrow = m0 + wr * 64 + mf * 16 + ((lane >> 4) << 2);
      int ncol = n0 + wc * 64 + nf * 16 + (lane & 15);
      if constexpr (MODE == 1) {
        size_t pbase = (size_t)ks * ((size_t)BCH * CC * CC);
#pragma unroll
        for (int j = 0; j < 4; ++j)
          attn[pbase + ((size_t)bidx * CC + (mrow + j)) * CC + ncol] = a[j];
      } else {
#pragma unroll
        for (int j = 0; j < 4; ++j) {
          size_t o = ((size_t)bidx * CC + (mrow + j)) * CN + ncol;
          out[o] = g * a[j] + xin[o];
        }
      }
    }
  }
}

// ---- softmax over d (512): sum KSPL split-K partials, one wave per row -----
__global__ __launch_bounds__(256) void softmax_k(const float* __restrict__ attn,
                                                 unsigned short* __restrict__ P) {
  int row = blockIdx.x * 4 + (threadIdx.x >> 6);
  int lane = threadIdx.x & 63;
  constexpr size_t PS = (size_t)BCH * CC * CC;
  const float* rp = attn + (size_t)row * 512 + lane * 8;
  f32x4 a = {0.f, 0.f, 0.f, 0.f};
  f32x4 b = {0.f, 0.f, 0.f, 0.f};
#pragma unroll
  for (int ksp = 0; ksp < KSPL; ++ksp) {
    a += *(const f32x4*)(rp + (size_t)ksp * PS);
    b += *(const f32x4*)(rp + (size_t)ksp * PS + 4);
  }
  float mx = fmaxf(fmaxf(fmaxf(a[0], a[1]), fmaxf(a[2], a[3])),
                   fmaxf(fmaxf(b[0], b[1]), fmaxf(b[2], b[3])));
#pragma unroll
  for (int s = 32; s > 0; s >>= 1) mx = fmaxf(mx, __shfl_xor(mx, s, 64));
  float e[8];
  float sum = 0.f;
#pragma unroll
  for (int j = 0; j < 4; ++j) { e[j] = __expf(a[j] - mx); sum += e[j]; }
#pragma unroll
  for (int j = 0; j < 4; ++j) { e[4 + j] = __expf(b[j] - mx); sum += e[4 + j]; }
#pragma unroll
  for (int s = 32; s > 0; s >>= 1) sum += __shfl_xor(sum, s, 64);
  float inv = 1.0f / sum;
  u16x8 o;
#pragma unroll
  for (int j = 0; j < 8; ++j) o[j] = f2bf(e[j] * inv);
  *(u16x8*)&P[(size_t)row * 512 + lane * 8] = o;
}

// ---- diagnostic: fill out with sentinel if workspace is too small ----------
__global__ __launch_bounds__(256) void fill_sentinel(float* __restrict__ out, int n) {
  int i = blockIdx.x * 256 + threadIdx.x;
  if (i < n) out[i] = 1.0e4f;
}

// ---------------------------------------------------------------------------
extern "C" void kernel_launch(void* const* d_in, const int* in_sizes, int n_in,
                              void* d_out, int out_size, void* d_ws, size_t ws_size,
                              hipStream_t stream) {
  (void)in_sizes; (void)n_in;
  const float* x  = (const float*)d_in[0];
  const float* wq = (const float*)d_in[1];
  const float* bq = (const float*)d_in[2];
  const float* wk = (const float*)d_in[3];
  const float* bk = (const float*)d_in[4];
  const float* wv = (const float*)d_in[5];
  const float* bv = (const float*)d_in[6];
  const float* gm = (const float*)d_in[7];
  float* out = (float*)d_out;

  uint8_t* wsp = (uint8_t*)d_ws;
  auto take = [&](size_t bytes) {
    uint8_t* p = wsp;
    wsp += (bytes + 255) & ~(size_t)255;
    return p;
  };
  unsigned short* Xpad = (unsigned short*)take(2 * XSPLIT * sizeof(unsigned short)); // 35.7 MB
  unsigned short* Abig = (unsigned short*)take((size_t)MR * K2 * 2);                 // 28.3 MB
  float* bias          = (float*)take((size_t)MR * 4);
  unsigned short* Khi  = (unsigned short*)take((size_t)BCH * CC * CN * 2);           // 16.8 MB
  unsigned short* Klo  = (unsigned short*)take((size_t)BCH * CC * CN * 2);           // 16.8 MB
  unsigned short* Vt   = (unsigned short*)take((size_t)BCH * CN * CC * 2);           // 16.8 MB
  float* attn          = (float*)Xpad;   // aliases Xpad (dead after conv)
  unsigned short* P    = (unsigned short*)((uint8_t*)Xpad +
                           (size_t)KSPL * BCH * CC * CC * 4 + 256);

  size_t needed = (size_t)(wsp - (uint8_t*)d_ws);   // ~114.5 MB
  if (ws_size < needed) {
    fill_sentinel<<<(out_size + 255) / 256, 256, 0, stream>>>(out, out_size);
    return;
  }

  for (int ch = 0; ch < CB / BCH; ++ch) {
    const float* xch = x + (size_t)ch * BCH * CC * CN;
    float* outch = out + (size_t)ch * BCH * CC * CN;
    unsigned short* Qhi = (unsigned short*)outch;   // Q pair lives in d_out
    unsigned short* Qlo = Qhi + (size_t)BCH * CC * CN;

    hipMemsetAsync(Xpad, 0, 2 * XSPLIT * sizeof(unsigned short), stream);
    prep_xpad<<<BCH * 16 * 64, 256, 0, stream>>>(xch, Xpad);
    if (ch == 0)
      prep_abig<<<(MR * K2) / 256, 256, 0, stream>>>(wq, wk, wv, bq, bk, bv, Abig, bias);
    conv_k<<<dim3(6 * BCH * 16), 512, 0, stream>>>(Abig, Xpad, bias, Qhi, Qlo,
                                                   Khi, Klo, Vt);
    gemm_k<1><<<dim3(16 * KSPL, 1, BCH), 256, 0, stream>>>(Qhi, Qlo, Khi, Klo, Vt,
                                                           attn, P, xch, gm, outch);
    softmax_k<<<BCH * 128, 256, 0, stream>>>(attn, P);
    gemm_k<2><<<dim3(128, 1, BCH), 256, 0, stream>>>(Qhi, Qlo, Khi, Klo, Vt,
                                                     attn, P, xch, gm, outch);
  }
}

// Round 8
// 1275.658 us; speedup vs baseline: 1.3567x; 1.2414x over previous
//
#include <hip/hip_runtime.h>
#include <stdint.h>

typedef __attribute__((ext_vector_type(8))) short bf16x8;
typedef __attribute__((ext_vector_type(4))) float f32x4;
typedef __attribute__((ext_vector_type(8))) unsigned short u16x8;
typedef __attribute__((ext_vector_type(4))) unsigned short u16x4;

#define DI static __device__ __forceinline__

constexpr int CB = 8;          // batch (total)
constexpr int BCH = 4;         // batches per chunk (2 chunks)
constexpr int CC = 512;        // channels
constexpr int CN = 4096;       // H*W
constexpr int K1 = CC * 9;     // 4608
constexpr int K2 = 2 * K1;     // 9216: packed A = [W_hi | W_lo]
constexpr int MR = 3 * CC;     // 1536 output rows (q|k|v)
constexpr int KSPL = 4;        // QK^T split-K factor
constexpr size_t XSPLIT = (size_t)BCH * 66 * 66 * 512;

DI unsigned short f2bf(float f) {
  union { float f; uint32_t u; } v; v.f = f;
  uint32_t r = (v.u + 0x7FFFu + ((v.u >> 16) & 1u)) >> 16;  // RNE
  return (unsigned short)r;
}
DI float bf2f(unsigned short h) {
  union { uint32_t u; float f; } v; v.u = ((uint32_t)h) << 16;
  return v.f;
}

DI void g2lds16(const void* g, void* l) {
  __builtin_amdgcn_global_load_lds((const __attribute__((address_space(1))) void*)g,
                                   (__attribute__((address_space(3))) void*)l, 16, 0, 0);
}
#define SBAR()  __builtin_amdgcn_s_barrier()
#define SCHED() __builtin_amdgcn_sched_barrier(0)

// ---- prep 1: padded channels-last hi/lo copies of x (one chunk) ------------
__global__ __launch_bounds__(256) void prep_xpad(const float* __restrict__ x,
                                                 unsigned short* __restrict__ Xpad) {
  int tid = threadIdx.x;
  int w = tid & 63;
  int ccl = tid >> 6;
  int blk = blockIdx.x;               // 4096 = b(4) * ccg(16) * h(64)
  int h = blk & 63;
  int ccg = (blk >> 6) & 15;
  int b = blk >> 10;
  int c0 = (ccg * 4 + ccl) * 8;
  const float* xp = x + ((size_t)b * CC) * CN + h * 64 + w;
  u16x8 hi, lo;
#pragma unroll
  for (int j = 0; j < 8; ++j) {
    float v = xp[(size_t)(c0 + j) * CN];
    unsigned short h16 = f2bf(v);
    hi[j] = h16;
    lo[j] = f2bf(v - bf2f(h16));
  }
  size_t po = (((size_t)b * 66 + (h + 1)) * 66 + (w + 1)) * 512 + c0;
  *(u16x8*)&Xpad[po] = hi;
  *(u16x8*)&Xpad[XSPLIT + po] = lo;
}

// ---- prep 2: packed A matrix [1536 x 9216] + bias[1536] --------------------
__global__ __launch_bounds__(256) void prep_abig(
    const float* __restrict__ wq, const float* __restrict__ wk,
    const float* __restrict__ wv, const float* __restrict__ bq,
    const float* __restrict__ bk, const float* __restrict__ bv,
    unsigned short* __restrict__ Abig, float* __restrict__ bias) {
  unsigned id = blockIdx.x * 256 + threadIdx.x;   // total 1536*9216
  int m = id / K2;
  int kk = id - m * K2;
  int third = kk / K1;
  int r = kk - third * K1;
  int t = r >> 9;
  int c = r & 511;
  int ky = t / 3;
  int kx = t - ky * 3;
  unsigned short oval;
  if (m < 1024) {
    const float* wp = (m < 512) ? wq : wk;
    int mm = (m < 512) ? m : m - 512;
    float wval = wp[(((size_t)mm * 512 + c) * 3 + ky) * 3 + kx];
    unsigned short h16 = f2bf(wval);
    oval = (third == 0) ? h16 : f2bf(wval - bf2f(h16));
  } else {
    oval = 0;
    if (third == 0) oval = f2bf(wv[(((size_t)(m - 1024) * 512 + c) * 3 + ky) * 3 + kx]);
  }
  Abig[id] = oval;
  if (id < 1536) {
    int mm = (int)id;
    bias[mm] = (mm < 512) ? bq[mm] : (mm < 1024) ? bk[mm - 512] : bv[mm - 1024];
  }
}

// ---- conv GEMM: 256x256, BK=32, 3-slot ring, frag-level pipeline -----------
// 8 waves (2M x 4N), per-wave 128x64 = 8x4 frags of 16x16x32.
// Per ktile: {read A-half2(t) || MFMA half1(t)} then {read frags(t+1) from the
// already-staged next slot || MFMA half2(t)}. Next-frags ping-pong between two
// static register sets (macro-expanded). Race-free slot reuse: lgkmcnt(0)+SBAR
// at ktile end -> all waves' reads of a slot complete >=1 barrier before the
// stage that overwrites it. Bank swizzle (r7, verified 0-conflict) unchanged.
__global__ __launch_bounds__(512, 2) void conv_k(
    const unsigned short* __restrict__ Abig,
    const unsigned short* __restrict__ Xpad,
    const float* __restrict__ bias,
    unsigned short* __restrict__ Qhi, unsigned short* __restrict__ Qlo,
    unsigned short* __restrict__ Khi, unsigned short* __restrict__ Klo,
    unsigned short* __restrict__ Vt)
{
  __shared__ __align__(16) unsigned char smem[3 * 32768];
  const int tid = threadIdx.x;
  const int lane = tid & 63;
  const int wid = tid >> 6;           // 0..7
  const int wr = wid >> 2;            // 0..1 (M)
  const int wc = wid & 3;             // 0..3 (N)

  // Balanced + XCD-local mapping: heavy q/k blocks (NT=432) are exactly 256 =
  // orig 0..255 -> dispatched first, one per CU; 128 light v blocks (NT=144)
  // backfill. XCD x (orig&7) owns nb panels [8x, 8x+8) for both -> L2 reuse.
  int orig = blockIdx.x;
  int x, nbl, mb;
  if (orig < 256) { x = orig & 7; int j = orig >> 3; nbl = j >> 2; mb = j & 3; }
  else { int o = orig - 256; x = o & 7; int j = o >> 3; nbl = j >> 1; mb = 4 + (j & 1); }
  const int nb = x * 8 + nbl;
  const int m0 = mb * 256;
  const int n0 = nb * 256;
  const int bidx = n0 >> 12;
  const int nl0 = n0 & (CN - 1);
  const int h0 = nl0 >> 6;
  const int NT = (m0 >= 1024) ? 144 : 432;    // BK=32 ktiles (v: s=0 only)

  // per-thread staging bases (once); source chunk pre-swizzled by f(srow)
  const int srow = tid >> 2;          // 0..127
  const int scu = tid & 3;
  const int scuS = scu ^ ((srow >> 1) & 3);
  const unsigned short* gA0 = Abig + (size_t)(m0 + srow) * K2 + scuS * 8;
  const unsigned short* gA1 = gA0 + (size_t)128 * K2;
  const unsigned short* gB0 = Xpad +
      (((size_t)(bidx * 66 + h0 + (srow >> 6))) * 66 + (srow & 63)) * 512 + scuS * 8;
  const unsigned short* gB1 = gB0 + (size_t)2 * 66 * 512;
  const int wofs = wid * 1024;

  // stage cursor (block-uniform): K order = s / tap(ky,kx) / c0
  int c0S = 0, tapS = 0, kxS = 0, sS = 0, aT = 0;
  size_t sh = 0, tapOfs = 0;

  auto stageS = [&](int slot) {
    int aOfs = aT + tapS * 512 + c0S;
    size_t bOfs = sh + tapOfs + (size_t)c0S;
    unsigned char* lA = smem + slot * 32768 + wofs;
    unsigned char* lB = smem + slot * 32768 + 16384 + wofs;
    g2lds16(gA0 + aOfs, lA);
    g2lds16(gA1 + aOfs, lA + 8192);
    g2lds16(gB0 + bOfs, lB);
    g2lds16(gB1 + bOfs, lB + 8192);
    c0S += 32;
    if (c0S == 512) {
      c0S = 0;
      ++tapS;
      if (tapS == 9) {
        tapS = 0; kxS = 0; tapOfs = 0;
        ++sS;
        aT = (sS == 2) ? K1 : 0;
        sh = (sS == 1) ? XSPLIT : 0;
      } else if (kxS == 2) { kxS = 0; tapOfs += (size_t)64 * 512; }  // ky++
      else { ++kxS; tapOfs += 512; }
    }
  };

  f32x4 acc[8][4];
  const f32x4 fz = {0.f, 0.f, 0.f, 0.f};
#pragma unroll
  for (int i = 0; i < 8; ++i)
#pragma unroll
    for (int j = 0; j < 4; ++j) acc[i][j] = fz;

  const int rA = wr * 128 + (lane & 15);
  const int rB = wc * 64 + (lane & 15);
  const int kq = (lane >> 4) * 16;
  const int kqA = kq ^ (((rA >> 1) & 3) << 4);   // r7 swizzle (0-conflict)
  const int kqB = kq ^ (((rB >> 1) & 3) << 4);

  stageS(0);
  stageS(1);
  asm volatile("s_waitcnt vmcnt(4)" ::: "memory");   // stage(0) landed
  SCHED(); SBAR(); SCHED();

  bf16x8 afA[4], bfA[4], afB[4], bfB[4], af1[4];
#pragma unroll
  for (int mf = 0; mf < 4; ++mf)
    afA[mf] = *(const bf16x8*)(smem + (rA + mf * 16) * 64 + kqA);
#pragma unroll
  for (int nf = 0; nf < 4; ++nf)
    bfA[nf] = *(const bf16x8*)(smem + 16384 + (rB + nf * 16) * 64 + kqB);

  int slotC = 0, slotS = 2, t2 = 2;

#define CONV_BODY(CURA, CURB, NXTA, NXTB)                                     \
  {                                                                           \
    if (t2 < NT) {                                                            \
      stageS(slotS); slotS = (slotS == 2) ? 0 : slotS + 1;                    \
      asm volatile("s_waitcnt vmcnt(4)" ::: "memory");                        \
    } else {                                                                  \
      asm volatile("s_waitcnt vmcnt(0)" ::: "memory");                        \
    }                                                                         \
    SCHED(); SBAR(); SCHED();                                                 \
    const unsigned char* lA = smem + slotC * 32768;                           \
    const int slotN = (slotC == 2) ? 0 : slotC + 1;                           \
    const unsigned char* lAn = smem + slotN * 32768;                          \
    _Pragma("unroll")                                                         \
    for (int mf = 0; mf < 4; ++mf)                                            \
      af1[mf] = *(const bf16x8*)(lA + (rA + 64 + mf * 16) * 64 + kqA);        \
    __builtin_amdgcn_s_setprio(1);                                            \
    _Pragma("unroll")                                                         \
    for (int mf = 0; mf < 4; ++mf) {                                          \
      _Pragma("unroll")                                                       \
      for (int nf = 0; nf < 4; ++nf)                                          \
        acc[mf][nf] = __builtin_amdgcn_mfma_f32_16x16x32_bf16(                \
            CURA[mf], CURB[nf], acc[mf][nf], 0, 0, 0);                        \
    }                                                                         \
    __builtin_amdgcn_s_setprio(0);                                            \
    _Pragma("unroll")                                                         \
    for (int mf = 0; mf < 4; ++mf)                                            \
      NXTA[mf] = *(const bf16x8*)(lAn + (rA + mf * 16) * 64 + kqA);           \
    _Pragma("unroll")                                                         \
    for (int nf = 0; nf < 4; ++nf)                                            \
      NXTB[nf] = *(const bf16x8*)(lAn + 16384 + (rB + nf * 16) * 64 + kqB);   \
    __builtin_amdgcn_s_setprio(1);                                            \
    _Pragma("unroll")                                                         \
    for (int mf = 0; mf < 4; ++mf) {                                          \
      _Pragma("unroll")                                                       \
      for (int nf = 0; nf < 4; ++nf)                                          \
        acc[mf + 4][nf] = __builtin_amdgcn_mfma_f32_16x16x32_bf16(            \
            af1[mf], CURB[nf], acc[mf + 4][nf], 0, 0, 0);                     \
    }                                                                         \
    __builtin_amdgcn_s_setprio(0);                                            \
    asm volatile("s_waitcnt lgkmcnt(0)" ::: "memory");                        \
    SCHED(); SBAR(); SCHED();                                                 \
    slotC = slotN;                                                            \
    ++t2;                                                                     \
  }

  for (int t = 0; t < NT; t += 2) {     // NT always even (432 / 144)
    CONV_BODY(afA, bfA, afB, bfB)
    CONV_BODY(afB, bfB, afA, bfA)
  }
#undef CONV_BODY

  // ---- epilogue: C/D layout col=lane&15, row=(lane>>4)*4+j ----
#pragma unroll
  for (int mf = 0; mf < 8; ++mf) {
#pragma unroll
    for (int nf = 0; nf < 4; ++nf) {
      f32x4 a = acc[mf][nf];
      int mrow = m0 + wr * 128 + mf * 16 + ((lane >> 4) << 2);
      int ncol = nl0 + wc * 64 + nf * 16 + (lane & 15);
      if (m0 < 512) {
#pragma unroll
        for (int j = 0; j < 4; ++j) {
          float v = a[j] + bias[mrow + j];
          unsigned short h16 = f2bf(v);
          size_t o = ((size_t)bidx * CC + (mrow + j)) * CN + ncol;
          Qhi[o] = h16;
          Qlo[o] = f2bf(v - bf2f(h16));
        }
      } else if (m0 < 1024) {
#pragma unroll
        for (int j = 0; j < 4; ++j) {
          float v = a[j] + bias[mrow + j];
          unsigned short h16 = f2bf(v);
          size_t o = ((size_t)bidx * CC + (mrow + j - 512)) * CN + ncol;
          Khi[o] = h16;
          Klo[o] = f2bf(v - bf2f(h16));
        }
      } else {
        u16x4 vs;                     // V written transposed: Vt[b][n][d]
#pragma unroll
        for (int j = 0; j < 4; ++j) vs[j] = f2bf(a[j] + bias[mrow + j]);
        *(u16x4*)&Vt[((size_t)bidx * CN + ncol) * CC + (mrow - 1024)] = vs;
      }
    }
  }
}

// ---- MFMA GEMM: MODE 1=QK^T (3-phase hi/lo, split-K), 2=PV -----------------
DI int sofs(int row, int kb) { return row * 128 + (kb ^ ((row & 7) << 4)); }

template<int MODE>
__global__ __launch_bounds__(256) void gemm_k(
    const unsigned short* __restrict__ Qhi, const unsigned short* __restrict__ Qlo,
    const unsigned short* __restrict__ Khi, const unsigned short* __restrict__ Klo,
    const unsigned short* __restrict__ Vt,
    float* __restrict__ attn,
    const unsigned short* __restrict__ P,
    const float* __restrict__ xin,
    const float* __restrict__ gamma,
    float* __restrict__ out)
{
  __shared__ __align__(16) unsigned char sA[16384];
  __shared__ __align__(16) unsigned char sB[16384];
  const int tid = threadIdx.x;
  const int lane = tid & 63;
  const int wav = tid >> 6;
  const int wr = wav >> 1, wc = wav & 1;

  int m0, n0, bidx, Kbeg = 0, Kend, ks = 0;
  if constexpr (MODE == 1) {
    int tile = blockIdx.x & 15;
    ks = blockIdx.x >> 4;
    m0 = (tile & 3) * 128;
    n0 = (tile >> 2) * 128;
    bidx = blockIdx.z;
    Kbeg = ks * (3 * CN / KSPL);
    Kend = Kbeg + (3 * CN / KSPL);
  } else {
    m0 = (blockIdx.x & 3) * 128;
    n0 = (blockIdx.x >> 2) * 128;
    bidx = blockIdx.z;
    Kend = CC;
  }

  auto stage = [&](int k0) {
#pragma unroll
    for (int q = 0; q < 4; ++q) {
      int ci = q * 256 + tid;
      int row = ci >> 3;
      int ke = ((ci & 7) ^ (row & 7)) * 8;
      const unsigned short* ap;
      const unsigned short* bp;
      if constexpr (MODE == 1) {
        int ph = k0 >> 12;
        int kin = k0 & (CN - 1);
        const unsigned short* Aq = (ph == 2) ? Qlo : Qhi;
        const unsigned short* Bk = (ph == 1) ? Klo : Khi;
        ap = Aq + ((size_t)bidx * CC + (m0 + row)) * CN + (kin + ke);
        bp = Bk + ((size_t)bidx * CC + (n0 + row)) * CN + (kin + ke);
      } else {
        ap = P + ((size_t)bidx * CC + (m0 + row)) * CC + (k0 + ke);
        bp = Vt + ((size_t)bidx * CN + (n0 + row)) * CC + (k0 + ke);
      }
      int wbase = (q * 256 + wav * 64) * 16;
      g2lds16(ap, sA + wbase);
      g2lds16(bp, sB + wbase);
    }
  };

  f32x4 acc[4][4];
  const f32x4 fz = {0.f, 0.f, 0.f, 0.f};
#pragma unroll
  for (int i = 0; i < 4; ++i)
#pragma unroll
    for (int j = 0; j < 4; ++j) acc[i][j] = fz;

  for (int k0 = Kbeg; k0 < Kend; k0 += 64) {
    stage(k0);
    __syncthreads();
#pragma unroll
    for (int kkp = 0; kkp < 2; ++kkp) {
      bf16x8 af[4], bfv[4];
#pragma unroll
      for (int mf = 0; mf < 4; ++mf)
        af[mf] = *(const bf16x8*)&sA[sofs(wr * 64 + mf * 16 + (lane & 15),
                                          kkp * 64 + (lane >> 4) * 16)];
#pragma unroll
      for (int nf = 0; nf < 4; ++nf)
        bfv[nf] = *(const bf16x8*)&sB[sofs(wc * 64 + nf * 16 + (lane & 15),
                                           kkp * 64 + (lane >> 4) * 16)];
#pragma unroll
      for (int mf = 0; mf < 4; ++mf)
#pragma unroll
        for (int nf = 0; nf < 4; ++nf)
          acc[mf][nf] = __builtin_amdgcn_mfma_f32_16x16x32_bf16(
              af[mf], bfv[nf], acc[mf][nf], 0, 0, 0);
    }
    __syncthreads();
  }

  float g = 0.f;
  if constexpr (MODE == 2) g = gamma[0];
#pragma unroll
  for (int mf = 0; mf < 4; ++mf) {
#pragma unroll
    for (int nf = 0; nf < 4; ++nf) {
      f32x4 a = acc[mf][nf];
      int mrow = m0 + wr * 64 + mf * 16 + ((lane >> 4) << 2);
      int ncol = n0 + wc * 64 + nf * 16 + (lane & 15);
      if constexpr (MODE == 1) {
        size_t pbase = (size_t)ks * ((size_t)BCH * CC * CC);
#pragma unroll
        for (int j = 0; j < 4; ++j)
          attn[pbase + ((size_t)bidx * CC + (mrow + j)) * CC + ncol] = a[j];
      } else {
#pragma unroll
        for (int j = 0; j < 4; ++j) {
          size_t o = ((size_t)bidx * CC + (mrow + j)) * CN + ncol;
          out[o] = g * a[j] + xin[o];
        }
      }
    }
  }
}

// ---- softmax over d (512): sum KSPL split-K partials, one wave per row -----
__global__ __launch_bounds__(256) void softmax_k(const float* __restrict__ attn,
                                                 unsigned short* __restrict__ P) {
  int row = blockIdx.x * 4 + (threadIdx.x >> 6);
  int lane = threadIdx.x & 63;
  constexpr size_t PS = (size_t)BCH * CC * CC;
  const float* rp = attn + (size_t)row * 512 + lane * 8;
  f32x4 a = {0.f, 0.f, 0.f, 0.f};
  f32x4 b = {0.f, 0.f, 0.f, 0.f};
#pragma unroll
  for (int ksp = 0; ksp < KSPL; ++ksp) {
    a += *(const f32x4*)(rp + (size_t)ksp * PS);
    b += *(const f32x4*)(rp + (size_t)ksp * PS + 4);
  }
  float mx = fmaxf(fmaxf(fmaxf(a[0], a[1]), fmaxf(a[2], a[3])),
                   fmaxf(fmaxf(b[0], b[1]), fmaxf(b[2], b[3])));
#pragma unroll
  for (int s = 32; s > 0; s >>= 1) mx = fmaxf(mx, __shfl_xor(mx, s, 64));
  float e[8];
  float sum = 0.f;
#pragma unroll
  for (int j = 0; j < 4; ++j) { e[j] = __expf(a[j] - mx); sum += e[j]; }
#pragma unroll
  for (int j = 0; j < 4; ++j) { e[4 + j] = __expf(b[j] - mx); sum += e[4 + j]; }
#pragma unroll
  for (int s = 32; s > 0; s >>= 1) sum += __shfl_xor(sum, s, 64);
  float inv = 1.0f / sum;
  u16x8 o;
#pragma unroll
  for (int j = 0; j < 8; ++j) o[j] = f2bf(e[j] * inv);
  *(u16x8*)&P[(size_t)row * 512 + lane * 8] = o;
}

// ---- diagnostic: fill out with sentinel if workspace is too small ----------
__global__ __launch_bounds__(256) void fill_sentinel(float* __restrict__ out, int n) {
  int i = blockIdx.x * 256 + threadIdx.x;
  if (i < n) out[i] = 1.0e4f;
}

// ---------------------------------------------------------------------------
extern "C" void kernel_launch(void* const* d_in, const int* in_sizes, int n_in,
                              void* d_out, int out_size, void* d_ws, size_t ws_size,
                              hipStream_t stream) {
  (void)in_sizes; (void)n_in;
  const float* x  = (const float*)d_in[0];
  const float* wq = (const float*)d_in[1];
  const float* bq = (const float*)d_in[2];
  const float* wk = (const float*)d_in[3];
  const float* bk = (const float*)d_in[4];
  const float* wv = (const float*)d_in[5];
  const float* bv = (const float*)d_in[6];
  const float* gm = (const float*)d_in[7];
  float* out = (float*)d_out;

  uint8_t* wsp = (uint8_t*)d_ws;
  auto take = [&](size_t bytes) {
    uint8_t* p = wsp;
    wsp += (bytes + 255) & ~(size_t)255;
    return p;
  };
  unsigned short* Xpad = (unsigned short*)take(2 * XSPLIT * sizeof(unsigned short)); // 35.7 MB
  unsigned short* Abig = (unsigned short*)take((size_t)MR * K2 * 2);                 // 28.3 MB
  float* bias          = (float*)take((size_t)MR * 4);
  unsigned short* Khi  = (unsigned short*)take((size_t)BCH * CC * CN * 2);           // 16.8 MB
  unsigned short* Klo  = (unsigned short*)take((size_t)BCH * CC * CN * 2);           // 16.8 MB
  unsigned short* Vt   = (unsigned short*)take((size_t)BCH * CN * CC * 2);           // 16.8 MB
  float* attn          = (float*)Xpad;   // aliases Xpad (dead after conv)
  unsigned short* P    = (unsigned short*)((uint8_t*)Xpad +
                           (size_t)KSPL * BCH * CC * CC * 4 + 256);

  size_t needed = (size_t)(wsp - (uint8_t*)d_ws);   // ~114.5 MB
  if (ws_size < needed) {
    fill_sentinel<<<(out_size + 255) / 256, 256, 0, stream>>>(out, out_size);
    return;
  }

  for (int ch = 0; ch < CB / BCH; ++ch) {
    const float* xch = x + (size_t)ch * BCH * CC * CN;
    float* outch = out + (size_t)ch * BCH * CC * CN;
    unsigned short* Qhi = (unsigned short*)outch;   // Q pair lives in d_out
    unsigned short* Qlo = Qhi + (size_t)BCH * CC * CN;

    hipMemsetAsync(Xpad, 0, 2 * XSPLIT * sizeof(unsigned short), stream);
    prep_xpad<<<BCH * 16 * 64, 256, 0, stream>>>(xch, Xpad);
    if (ch == 0)
      prep_abig<<<(MR * K2) / 256, 256, 0, stream>>>(wq, wk, wv, bq, bk, bv, Abig, bias);
    conv_k<<<dim3(6 * BCH * 16), 512, 0, stream>>>(Abig, Xpad, bias, Qhi, Qlo,
                                                   Khi, Klo, Vt);
    gemm_k<1><<<dim3(16 * KSPL, 1, BCH), 256, 0, stream>>>(Qhi, Qlo, Khi, Klo, Vt,
                                                           attn, P, xch, gm, outch);
    softmax_k<<<BCH * 128, 256, 0, stream>>>(attn, P);
    gemm_k<2><<<dim3(128, 1, BCH), 256, 0, stream>>>(Qhi, Qlo, Khi, Klo, Vt,
                                                     attn, P, xch, gm, outch);
  }
}

// Round 9
// 1141.008 us; speedup vs baseline: 1.5168x; 1.1180x over previous
//
#include <hip/hip_runtime.h>
#include <stdint.h>

typedef __attribute__((ext_vector_type(8))) short bf16x8;
typedef __attribute__((ext_vector_type(4))) float f32x4;
typedef __attribute__((ext_vector_type(2))) long i64x2;
typedef __attribute__((ext_vector_type(8))) unsigned short u16x8;
typedef __attribute__((ext_vector_type(4))) unsigned short u16x4;

#define DI static __device__ __forceinline__

constexpr int CB = 8;          // batch (total)
constexpr int BCH = 4;         // batches per chunk (2 chunks)
constexpr int CC = 512;        // channels
constexpr int CN = 4096;       // H*W
constexpr int K1 = CC * 9;     // 4608
constexpr int MR = 3 * CC;     // 1536 output rows (q|k|v)
constexpr int KSPL = 4;        // QK^T split-K factor
constexpr size_t XSPLIT = (size_t)BCH * 66 * 66 * 512;

DI unsigned short f2bf(float f) {
  union { float f; uint32_t u; } v; v.f = f;
  uint32_t r = (v.u + 0x7FFFu + ((v.u >> 16) & 1u)) >> 16;  // RNE
  return (unsigned short)r;
}
DI float bf2f(unsigned short h) {
  union { uint32_t u; float f; } v; v.u = ((uint32_t)h) << 16;
  return v.f;
}
// manual OCP e4m3fn convert (RNE on mantissa; sat to 448); input |x| << 448 here
DI unsigned char f2e4m3(float x) {
  union { float f; uint32_t u; } v; v.f = x;
  uint32_t sgn = (v.u >> 24) & 0x80u;
  float a = fabsf(x);
  if (a < 0.015625f) {                       // subnormal: quantum 2^-9
    int qi = (int)rintf(a * 512.f);          // 0..8 (8 -> min normal 0x08)
    return (unsigned char)(sgn | (uint32_t)qi);
  }
  int e = (int)((v.u >> 23) & 0xff) - 127;
  uint32_t m3 = (v.u >> 20) & 7u;
  uint32_t rest = v.u & 0xFFFFFu;
  if (rest > 0x80000u || (rest == 0x80000u && (m3 & 1u))) {
    if (++m3 == 8u) { m3 = 0; ++e; }
  }
  if (e > 8 || (e == 8 && m3 == 7u)) return (unsigned char)(sgn | 0x7Eu);
  return (unsigned char)(sgn | ((uint32_t)(e + 7) << 3) | m3);
}
// byte position of k (0..63) inside a 64B pair-interleaved fp8 row:
// b128 at byte q*16 yields (k=q*8..+7) as long[0], (k=32+q*8..+7) as long[1]
DI int perm64(int k) { return (k & 7) + (((k >> 5) & 1) << 3) + (((k >> 3) & 3) << 4); }

DI void g2lds16(const void* g, void* l) {
  __builtin_amdgcn_global_load_lds((const __attribute__((address_space(1))) void*)g,
                                   (__attribute__((address_space(3))) void*)l, 16, 0, 0);
}
#define SBAR()  __builtin_amdgcn_s_barrier()
#define SCHED() __builtin_amdgcn_sched_barrier(0)

// ---- prep 1: Xhi (bf16, x2^7), X8 split0=Xlo8 (x2^8), split1=Xhi8 (x1) -----
// all [b][66][66][512], pads zeroed per chunk; fp8 c-interleaved per 64-group.
__global__ __launch_bounds__(256) void prep_xpad(const float* __restrict__ x,
                                                 unsigned short* __restrict__ Xhi,
                                                 unsigned char* __restrict__ X8) {
  int tid = threadIdx.x;
  int w = tid & 63;
  int ccl = tid >> 6;
  int blk = blockIdx.x;               // 4096 = b(4) * ccg(16) * h(64)
  int h = blk & 63;
  int ccg = (blk >> 6) & 15;
  int b = blk >> 10;
  int c0 = (ccg * 4 + ccl) * 8;
  const float* xp = x + ((size_t)b * CC) * CN + h * 64 + w;
  u16x8 hi;
  unsigned long long lo8 = 0, hi8 = 0;
#pragma unroll
  for (int j = 0; j < 8; ++j) {
    float v = xp[(size_t)(c0 + j) * CN];
    unsigned short h16 = f2bf(v);
    float vhi = bf2f(h16);
    hi[j] = f2bf(vhi * 128.f);                    // exact shift
    lo8 |= (unsigned long long)f2e4m3((v - vhi) * 256.f) << (8 * j);
    hi8 |= (unsigned long long)f2e4m3(vhi) << (8 * j);
  }
  size_t pix = (((size_t)b * 66 + (h + 1)) * 66 + (w + 1)) * 512;
  *(u16x8*)&Xhi[pix + c0] = hi;
  size_t p8 = pix + (size_t)(c0 & ~63) + perm64(c0 & 63);   // c0 8-aligned
  *(unsigned long long*)&X8[p8] = lo8;
  *(unsigned long long*)&X8[XSPLIT + p8] = hi8;
}

// ---- prep 2: Ahi [1536][4608] bf16 (x2^7), A8 [1536][9216] fp8 -------------
// A8 third0 = fp8(Whi*2^6) (s1), third1 = fp8(Wlo*2^14) (s2); v rows zero.
__global__ __launch_bounds__(256) void prep_abig(
    const float* __restrict__ wq, const float* __restrict__ wk,
    const float* __restrict__ wv, const float* __restrict__ bq,
    const float* __restrict__ bk, const float* __restrict__ bv,
    unsigned short* __restrict__ Ahi, unsigned char* __restrict__ A8,
    float* __restrict__ bias) {
  unsigned id = blockIdx.x * 256 + threadIdx.x;   // total 1536*4608
  int m = id / K1;
  int r = id - m * K1;
  int t = r >> 9;
  int c = r & 511;
  int ky = t / 3;
  int kx = t - ky * 3;
  size_t ip = (size_t)m * 9216 + (size_t)(r & ~63) + perm64(r & 63);
  if (m < 1024) {
    const float* wp = (m < 512) ? wq : wk;
    int mm = (m < 512) ? m : m - 512;
    float wval = wp[(((size_t)mm * 512 + c) * 3 + ky) * 3 + kx];
    float whi = bf2f(f2bf(wval));
    Ahi[id] = f2bf(whi * 128.f);
    A8[ip] = f2e4m3(whi * 64.f);
    A8[ip + 4608] = f2e4m3((wval - whi) * 16384.f);
  } else {
    float wval = wv[(((size_t)(m - 1024) * 512 + c) * 3 + ky) * 3 + kx];
    Ahi[id] = f2bf(wval * 128.f);
    A8[ip] = 0;
    A8[ip + 4608] = 0;
  }
  if (id < 1536) {
    int mm = (int)id;
    bias[mm] = (mm < 512) ? bq[mm] : (mm < 1024) ? bk[mm - 512] : bv[mm - 1024];
  }
}

// ---- conv GEMM: 256x256, 3-slot ring, frag pipeline, bf16 + fp8 phases -----
// Phase 1 (all blocks): s0 = (Whi*2^7)(Xhi*2^7) bf16, BK=32, 144 ktiles.
// Phase 2 (q/k blocks): s1+s2 fp8 K=64/ktile, 144 ktiles (pair-interleaved
// rows: one ds_read_b128 = both K-half operands). All products at scale 2^14;
// epilogue * 2^-14. Slot geometry/swizzle identical in both phases (64B rows).
__global__ __launch_bounds__(512, 2) void conv_k(
    const unsigned short* __restrict__ Ahi,
    const unsigned char* __restrict__ A8,
    const unsigned short* __restrict__ Xhi,
    const unsigned char* __restrict__ X8,
    const float* __restrict__ bias,
    unsigned short* __restrict__ Qhi, unsigned short* __restrict__ Qlo,
    unsigned short* __restrict__ Khi, unsigned short* __restrict__ Klo,
    unsigned short* __restrict__ Vt)
{
  __shared__ __align__(16) unsigned char smem[3 * 32768];
  const int tid = threadIdx.x;
  const int lane = tid & 63;
  const int wid = tid >> 6;
  const int wr = wid >> 2;            // 0..1 (M)
  const int wc = wid & 3;             // 0..3 (N)

  // Balanced + XCD-local: heavy q/k blocks = orig 0..255 (one per CU first),
  // 128 light v blocks backfill; XCD x owns nb panels [8x, 8x+8).
  int orig = blockIdx.x;
  int xcd, nbl, mb;
  if (orig < 256) { xcd = orig & 7; int j = orig >> 3; nbl = j >> 2; mb = j & 3; }
  else { int o = orig - 256; xcd = o & 7; int j = o >> 3; nbl = j >> 1; mb = 4 + (j & 1); }
  const int nb = xcd * 8 + nbl;
  const int m0 = mb * 256;
  const int n0 = nb * 256;
  const int bidx = n0 >> 12;
  const int nl0 = n0 & (CN - 1);
  const int h0 = nl0 >> 6;

  // per-thread staging bases; source chunk pre-swizzled by f(srow)
  const int srow = tid >> 2;          // 0..127
  const int scu = tid & 3;
  const int scuS = scu ^ ((srow >> 1) & 3);
  const size_t pixOfs = (((size_t)(bidx * 66 + h0 + (srow >> 6))) * 66 + (srow & 63)) * 512;
  const unsigned short* gAh0 = Ahi + (size_t)(m0 + srow) * K1 + scuS * 8;
  const unsigned short* gAh1 = gAh0 + (size_t)128 * K1;
  const unsigned short* gBh0 = Xhi + pixOfs + scuS * 8;
  const unsigned short* gBh1 = gBh0 + (size_t)2 * 66 * 512;
  const unsigned char* gA80 = A8 + (size_t)(m0 + srow) * 9216 + scuS * 16;
  const unsigned char* gA81 = gA80 + (size_t)128 * 9216;
  const unsigned char* gB80 = X8 + pixOfs + scuS * 16;
  const unsigned char* gB81 = gB80 + (size_t)2 * 66 * 512;
  const int wofs = wid * 1024;

  // phase-1 cursor (s0: tap 0..8 x c0 step 32 -> 144 ktiles)
  int c0S = 0, kxS = 0, tapS = 0;
  size_t tapOfs = 0;
  auto stage1 = [&](int slot) {
    int aOfs = tapS * 512 + c0S;
    size_t bOfs = tapOfs + (size_t)c0S;
    unsigned char* lA = smem + slot * 32768 + wofs;
    unsigned char* lB = smem + slot * 32768 + 16384 + wofs;
    g2lds16(gAh0 + aOfs, lA);
    g2lds16(gAh1 + aOfs, lA + 8192);
    g2lds16(gBh0 + bOfs, lB);
    g2lds16(gBh1 + bOfs, lB + 8192);
    c0S += 32;
    if (c0S == 512) {
      c0S = 0; ++tapS;
      if (kxS == 2) { kxS = 0; tapOfs += (size_t)64 * 512; }
      else { ++kxS; tapOfs += 512; }
    }
  };
  // phase-2 cursor (s'=0:Whi8*Xlo8, s'=1:Wlo8*Xhi8; tap 0..8 x c0 step 64)
  int c8 = 0, kx8 = 0, tap8 = 0, s8 = 0;
  size_t tapOfs8 = 0;
  auto stage2 = [&](int slot) {
    int aOfs = s8 * 4608 + tap8 * 512 + c8;
    size_t bOfs = (size_t)s8 * XSPLIT + tapOfs8 + (size_t)c8;
    unsigned char* lA = smem + slot * 32768 + wofs;
    unsigned char* lB = smem + slot * 32768 + 16384 + wofs;
    g2lds16(gA80 + aOfs, lA);
    g2lds16(gA81 + aOfs, lA + 8192);
    g2lds16(gB80 + bOfs, lB);
    g2lds16(gB81 + bOfs, lB + 8192);
    c8 += 64;
    if (c8 == 512) {
      c8 = 0; ++tap8;
      if (tap8 == 9) { tap8 = 0; kx8 = 0; tapOfs8 = 0; ++s8; }
      else if (kx8 == 2) { kx8 = 0; tapOfs8 += (size_t)64 * 512; }
      else { ++kx8; tapOfs8 += 512; }
    }
  };

  f32x4 acc[8][4];
  const f32x4 fz = {0.f, 0.f, 0.f, 0.f};
#pragma unroll
  for (int i = 0; i < 8; ++i)
#pragma unroll
    for (int j = 0; j < 4; ++j) acc[i][j] = fz;

  const int rA = wr * 128 + (lane & 15);
  const int rB = wc * 64 + (lane & 15);
  const int kq = (lane >> 4) * 16;
  const int kqA = kq ^ (((rA >> 1) & 3) << 4);   // r7 swizzle (0-conflict)
  const int kqB = kq ^ (((rB >> 1) & 3) << 4);

  int slotC, slotS, t2;

  // ================= phase 1: bf16 s0, 144 ktiles =================
  stage1(0);
  stage1(1);
  asm volatile("s_waitcnt vmcnt(4)" ::: "memory");
  SCHED(); SBAR(); SCHED();
  {
    bf16x8 afA[4], bfA[4], afB[4], bfB[4], af1[4];
#pragma unroll
    for (int mf = 0; mf < 4; ++mf)
      afA[mf] = *(const bf16x8*)(smem + (rA + mf * 16) * 64 + kqA);
#pragma unroll
    for (int nf = 0; nf < 4; ++nf)
      bfA[nf] = *(const bf16x8*)(smem + 16384 + (rB + nf * 16) * 64 + kqB);
    slotC = 0; slotS = 2; t2 = 2;

#define CONV_BF(CURA, CURB, NXTA, NXTB)                                       \
  {                                                                           \
    if (t2 < 144) {                                                           \
      stage1(slotS); slotS = (slotS == 2) ? 0 : slotS + 1;                    \
      asm volatile("s_waitcnt vmcnt(4)" ::: "memory");                        \
    } else {                                                                  \
      asm volatile("s_waitcnt vmcnt(0)" ::: "memory");                        \
    }                                                                         \
    SCHED(); SBAR(); SCHED();                                                 \
    const unsigned char* lA = smem + slotC * 32768;                           \
    const int slotN = (slotC == 2) ? 0 : slotC + 1;                           \
    const unsigned char* lAn = smem + slotN * 32768;                          \
    _Pragma("unroll")                                                         \
    for (int mf = 0; mf < 4; ++mf)                                            \
      af1[mf] = *(const bf16x8*)(lA + (rA + 64 + mf * 16) * 64 + kqA);        \
    __builtin_amdgcn_s_setprio(1);                                            \
    _Pragma("unroll")                                                         \
    for (int mf = 0; mf < 4; ++mf) {                                          \
      _Pragma("unroll")                                                       \
      for (int nf = 0; nf < 4; ++nf)                                          \
        acc[mf][nf] = __builtin_amdgcn_mfma_f32_16x16x32_bf16(                \
            CURA[mf], CURB[nf], acc[mf][nf], 0, 0, 0);                        \
    }                                                                         \
    __builtin_amdgcn_s_setprio(0);                                            \
    _Pragma("unroll")                                                         \
    for (int mf = 0; mf < 4; ++mf)                                            \
      NXTA[mf] = *(const bf16x8*)(lAn + (rA + mf * 16) * 64 + kqA);           \
    _Pragma("unroll")                                                         \
    for (int nf = 0; nf < 4; ++nf)                                            \
      NXTB[nf] = *(const bf16x8*)(lAn + 16384 + (rB + nf * 16) * 64 + kqB);   \
    __builtin_amdgcn_s_setprio(1);                                            \
    _Pragma("unroll")                                                         \
    for (int mf = 0; mf < 4; ++mf) {                                          \
      _Pragma("unroll")                                                       \
      for (int nf = 0; nf < 4; ++nf)                                          \
        acc[mf + 4][nf] = __builtin_amdgcn_mfma_f32_16x16x32_bf16(            \
            af1[mf], CURB[nf], acc[mf + 4][nf], 0, 0, 0);                     \
    }                                                                         \
    __builtin_amdgcn_s_setprio(0);                                            \
    asm volatile("s_waitcnt lgkmcnt(0)" ::: "memory");                        \
    SCHED(); SBAR(); SCHED();                                                 \
    slotC = slotN;                                                            \
    ++t2;                                                                     \
  }

    for (int t = 0; t < 144; t += 2) {
      CONV_BF(afA, bfA, afB, bfB)
      CONV_BF(afB, bfB, afA, bfA)
    }
#undef CONV_BF
  }

  // ================= phase 2 (q/k only): fp8 s1+s2, 144 ktiles of K=64 =====
  if (m0 < 1024) {
    stage2(0);
    stage2(1);
    asm volatile("s_waitcnt vmcnt(4)" ::: "memory");
    SCHED(); SBAR(); SCHED();
    i64x2 a8A[4], b8A[4], a8B[4], b8B[4], a18[4];
#pragma unroll
    for (int mf = 0; mf < 4; ++mf)
      a8A[mf] = *(const i64x2*)(smem + (rA + mf * 16) * 64 + kqA);
#pragma unroll
    for (int nf = 0; nf < 4; ++nf)
      b8A[nf] = *(const i64x2*)(smem + 16384 + (rB + nf * 16) * 64 + kqB);
    slotC = 0; slotS = 2; t2 = 2;

#define CONV_F8(CURA, CURB, NXTA, NXTB)                                       \
  {                                                                           \
    if (t2 < 144) {                                                           \
      stage2(slotS); slotS = (slotS == 2) ? 0 : slotS + 1;                    \
      asm volatile("s_waitcnt vmcnt(4)" ::: "memory");                        \
    } else {                                                                  \
      asm volatile("s_waitcnt vmcnt(0)" ::: "memory");                        \
    }                                                                         \
    SCHED(); SBAR(); SCHED();                                                 \
    const unsigned char* lA = smem + slotC * 32768;                           \
    const int slotN = (slotC == 2) ? 0 : slotC + 1;                           \
    const unsigned char* lAn = smem + slotN * 32768;                          \
    _Pragma("unroll")                                                         \
    for (int mf = 0; mf < 4; ++mf)                                            \
      a18[mf] = *(const i64x2*)(lA + (rA + 64 + mf * 16) * 64 + kqA);         \
    __builtin_amdgcn_s_setprio(1);                                            \
    _Pragma("unroll")                                                         \
    for (int mf = 0; mf < 4; ++mf) {                                          \
      _Pragma("unroll")                                                       \
      for (int nf = 0; nf < 4; ++nf) {                                        \
        acc[mf][nf] = __builtin_amdgcn_mfma_f32_16x16x32_fp8_fp8(             \
            CURA[mf][0], CURB[nf][0], acc[mf][nf], 0, 0, 0);                  \
        acc[mf][nf] = __builtin_amdgcn_mfma_f32_16x16x32_fp8_fp8(             \
            CURA[mf][1], CURB[nf][1], acc[mf][nf], 0, 0, 0);                  \
      }                                                                       \
    }                                                                         \
    __builtin_amdgcn_s_setprio(0);                                            \
    _Pragma("unroll")                                                         \
    for (int mf = 0; mf < 4; ++mf)                                            \
      NXTA[mf] = *(const i64x2*)(lAn + (rA + mf * 16) * 64 + kqA);            \
    _Pragma("unroll")                                                         \
    for (int nf = 0; nf < 4; ++nf)                                            \
      NXTB[nf] = *(const i64x2*)(lAn + 16384 + (rB + nf * 16) * 64 + kqB);    \
    __builtin_amdgcn_s_setprio(1);                                            \
    _Pragma("unroll")                                                         \
    for (int mf = 0; mf < 4; ++mf) {                                          \
      _Pragma("unroll")                                                       \
      for (int nf = 0; nf < 4; ++nf) {                                        \
        acc[mf + 4][nf] = __builtin_amdgcn_mfma_f32_16x16x32_fp8_fp8(         \
            a18[mf][0], CURB[nf][0], acc[mf + 4][nf], 0, 0, 0);               \
        acc[mf + 4][nf] = __builtin_amdgcn_mfma_f32_16x16x32_fp8_fp8(         \
            a18[mf][1], CURB[nf][1], acc[mf + 4][nf], 0, 0, 0);               \
      }                                                                       \
    }                                                                         \
    __builtin_amdgcn_s_setprio(0);                                            \
    asm volatile("s_waitcnt lgkmcnt(0)" ::: "memory");                        \
    SCHED(); SBAR(); SCHED();                                                 \
    slotC = slotN;                                                            \
    ++t2;                                                                     \
  }

    for (int t = 0; t < 144; t += 2) {
      CONV_F8(a8A, b8A, a8B, b8B)
      CONV_F8(a8B, b8B, a8A, b8A)
    }
#undef CONV_F8
  }

  // ---- epilogue: all products at scale 2^14 -> * 2^-14 ----
  constexpr float SC = 1.f / 16384.f;
#pragma unroll
  for (int mf = 0; mf < 8; ++mf) {
#pragma unroll
    for (int nf = 0; nf < 4; ++nf) {
      f32x4 a = acc[mf][nf];
      int mrow = m0 + wr * 128 + mf * 16 + ((lane >> 4) << 2);
      int ncol = nl0 + wc * 64 + nf * 16 + (lane & 15);
      if (m0 < 512) {
#pragma unroll
        for (int j = 0; j < 4; ++j) {
          float v = a[j] * SC + bias[mrow + j];
          unsigned short h16 = f2bf(v);
          size_t o = ((size_t)bidx * CC + (mrow + j)) * CN + ncol;
          Qhi[o] = h16;
          Qlo[o] = f2bf(v - bf2f(h16));
        }
      } else if (m0 < 1024) {
#pragma unroll
        for (int j = 0; j < 4; ++j) {
          float v = a[j] * SC + bias[mrow + j];
          unsigned short h16 = f2bf(v);
          size_t o = ((size_t)bidx * CC + (mrow + j - 512)) * CN + ncol;
          Khi[o] = h16;
          Klo[o] = f2bf(v - bf2f(h16));
        }
      } else {
        u16x4 vs;                     // V written transposed: Vt[b][n][d]
#pragma unroll
        for (int j = 0; j < 4; ++j) vs[j] = f2bf(a[j] * SC + bias[mrow + j]);
        *(u16x4*)&Vt[((size_t)bidx * CN + ncol) * CC + (mrow - 1024)] = vs;
      }
    }
  }
}

// ---- MFMA GEMM: MODE 1=QK^T (3-phase hi/lo, split-K), 2=PV -----------------
DI int sofs(int row, int kb) { return row * 128 + (kb ^ ((row & 7) << 4)); }

template<int MODE>
__global__ __launch_bounds__(256) void gemm_k(
    const unsigned short* __restrict__ Qhi, const unsigned short* __restrict__ Qlo,
    const unsigned short* __restrict__ Khi, const unsigned short* __restrict__ Klo,
    const unsigned short* __restrict__ Vt,
    float* __restrict__ attn,
    const unsigned short* __restrict__ P,
    const float* __restrict__ xin,
    const float* __restrict__ gamma,
    float* __restrict__ out)
{
  __shared__ __align__(16) unsigned char sA[16384];
  __shared__ __align__(16) unsigned char sB[16384];
  const int tid = threadIdx.x;
  const int lane = tid & 63;
  const int wav = tid >> 6;
  const int wr = wav >> 1, wc = wav & 1;

  int m0, n0, bidx, Kbeg = 0, Kend, ks = 0;
  if constexpr (MODE == 1) {
    int tile = blockIdx.x & 15;
    ks = blockIdx.x >> 4;
    m0 = (tile & 3) * 128;
    n0 = (tile >> 2) * 128;
    bidx = blockIdx.z;
    Kbeg = ks * (3 * CN / KSPL);
    Kend = Kbeg + (3 * CN / KSPL);
  } else {
    m0 = (blockIdx.x & 3) * 128;
    n0 = (blockIdx.x >> 2) * 128;
    bidx = blockIdx.z;
    Kend = CC;
  }

  auto stage = [&](int k0) {
#pragma unroll
    for (int q = 0; q < 4; ++q) {
      int ci = q * 256 + tid;
      int row = ci >> 3;
      int ke = ((ci & 7) ^ (row & 7)) * 8;
      const unsigned short* ap;
      const unsigned short* bp;
      if constexpr (MODE == 1) {
        int ph = k0 >> 12;
        int kin = k0 & (CN - 1);
        const unsigned short* Aq = (ph == 2) ? Qlo : Qhi;
        const unsigned short* Bk = (ph == 1) ? Klo : Khi;
        ap = Aq + ((size_t)bidx * CC + (m0 + row)) * CN + (kin + ke);
        bp = Bk + ((size_t)bidx * CC + (n0 + row)) * CN + (kin + ke);
      } else {
        ap = P + ((size_t)bidx * CC + (m0 + row)) * CC + (k0 + ke);
        bp = Vt + ((size_t)bidx * CN + (n0 + row)) * CC + (k0 + ke);
      }
      int wbase = (q * 256 + wav * 64) * 16;
      g2lds16(ap, sA + wbase);
      g2lds16(bp, sB + wbase);
    }
  };

  f32x4 acc[4][4];
  const f32x4 fz = {0.f, 0.f, 0.f, 0.f};
#pragma unroll
  for (int i = 0; i < 4; ++i)
#pragma unroll
    for (int j = 0; j < 4; ++j) acc[i][j] = fz;

  for (int k0 = Kbeg; k0 < Kend; k0 += 64) {
    stage(k0);
    __syncthreads();
#pragma unroll
    for (int kkp = 0; kkp < 2; ++kkp) {
      bf16x8 af[4], bfv[4];
#pragma unroll
      for (int mf = 0; mf < 4; ++mf)
        af[mf] = *(const bf16x8*)&sA[sofs(wr * 64 + mf * 16 + (lane & 15),
                                          kkp * 64 + (lane >> 4) * 16)];
#pragma unroll
      for (int nf = 0; nf < 4; ++nf)
        bfv[nf] = *(const bf16x8*)&sB[sofs(wc * 64 + nf * 16 + (lane & 15),
                                           kkp * 64 + (lane >> 4) * 16)];
#pragma unroll
      for (int mf = 0; mf < 4; ++mf)
#pragma unroll
        for (int nf = 0; nf < 4; ++nf)
          acc[mf][nf] = __builtin_amdgcn_mfma_f32_16x16x32_bf16(
              af[mf], bfv[nf], acc[mf][nf], 0, 0, 0);
    }
    __syncthreads();
  }

  float g = 0.f;
  if constexpr (MODE == 2) g = gamma[0];
#pragma unroll
  for (int mf = 0; mf < 4; ++mf) {
#pragma unroll
    for (int nf = 0; nf < 4; ++nf) {
      f32x4 a = acc[mf][nf];
      int mrow = m0 + wr * 64 + mf * 16 + ((lane >> 4) << 2);
      int ncol = n0 + wc * 64 + nf * 16 + (lane & 15);
      if constexpr (MODE == 1) {
        size_t pbase = (size_t)ks * ((size_t)BCH * CC * CC);
#pragma unroll
        for (int j = 0; j < 4; ++j)
          attn[pbase + ((size_t)bidx * CC + (mrow + j)) * CC + ncol] = a[j];
      } else {
#pragma unroll
        for (int j = 0; j < 4; ++j) {
          size_t o = ((size_t)bidx * CC + (mrow + j)) * CN + ncol;
          out[o] = g * a[j] + xin[o];
        }
      }
    }
  }
}

// ---- softmax over d (512): sum KSPL split-K partials, one wave per row -----
__global__ __launch_bounds__(256) void softmax_k(const float* __restrict__ attn,
                                                 unsigned short* __restrict__ P) {
  int row = blockIdx.x * 4 + (threadIdx.x >> 6);
  int lane = threadIdx.x & 63;
  constexpr size_t PS = (size_t)BCH * CC * CC;
  const float* rp = attn + (size_t)row * 512 + lane * 8;
  f32x4 a = {0.f, 0.f, 0.f, 0.f};
  f32x4 b = {0.f, 0.f, 0.f, 0.f};
#pragma unroll
  for (int ksp = 0; ksp < KSPL; ++ksp) {
    a += *(const f32x4*)(rp + (size_t)ksp * PS);
    b += *(const f32x4*)(rp + (size_t)ksp * PS + 4);
  }
  float mx = fmaxf(fmaxf(fmaxf(a[0], a[1]), fmaxf(a[2], a[3])),
                   fmaxf(fmaxf(b[0], b[1]), fmaxf(b[2], b[3])));
#pragma unroll
  for (int s = 32; s > 0; s >>= 1) mx = fmaxf(mx, __shfl_xor(mx, s, 64));
  float e[8];
  float sum = 0.f;
#pragma unroll
  for (int j = 0; j < 4; ++j) { e[j] = __expf(a[j] - mx); sum += e[j]; }
#pragma unroll
  for (int j = 0; j < 4; ++j) { e[4 + j] = __expf(b[j] - mx); sum += e[4 + j]; }
#pragma unroll
  for (int s = 32; s > 0; s >>= 1) sum += __shfl_xor(sum, s, 64);
  float inv = 1.0f / sum;
  u16x8 o;
#pragma unroll
  for (int j = 0; j < 8; ++j) o[j] = f2bf(e[j] * inv);
  *(u16x8*)&P[(size_t)row * 512 + lane * 8] = o;
}

// ---- diagnostic: fill out with sentinel if workspace is too small ----------
__global__ __launch_bounds__(256) void fill_sentinel(float* __restrict__ out, int n) {
  int i = blockIdx.x * 256 + threadIdx.x;
  if (i < n) out[i] = 1.0e4f;
}

// ---------------------------------------------------------------------------
extern "C" void kernel_launch(void* const* d_in, const int* in_sizes, int n_in,
                              void* d_out, int out_size, void* d_ws, size_t ws_size,
                              hipStream_t stream) {
  (void)in_sizes; (void)n_in;
  const float* x  = (const float*)d_in[0];
  const float* wq = (const float*)d_in[1];
  const float* bq = (const float*)d_in[2];
  const float* wk = (const float*)d_in[3];
  const float* bk = (const float*)d_in[4];
  const float* wv = (const float*)d_in[5];
  const float* bv = (const float*)d_in[6];
  const float* gm = (const float*)d_in[7];
  float* out = (float*)d_out;

  uint8_t* wsp = (uint8_t*)d_ws;
  auto take = [&](size_t bytes) {
    uint8_t* p = wsp;
    wsp += (bytes + 255) & ~(size_t)255;
    return p;
  };
  unsigned short* Xhi = (unsigned short*)take(XSPLIT * 2);          // 17.8 MB
  unsigned char*  X8  = (unsigned char*)take(2 * XSPLIT);           // 17.8 MB (contiguous after Xhi)
  unsigned short* Ahi = (unsigned short*)take((size_t)MR * K1 * 2); // 13.5 MB
  unsigned char*  A8  = (unsigned char*)take((size_t)MR * 2 * K1);  // 13.5 MB
  float* bias         = (float*)take((size_t)MR * 4);
  unsigned short* Khi = (unsigned short*)take((size_t)BCH * CC * CN * 2);  // 16.8 MB
  unsigned short* Klo = (unsigned short*)take((size_t)BCH * CC * CN * 2);  // 16.8 MB
  unsigned short* Vt  = (unsigned short*)take((size_t)BCH * CN * CC * 2);  // 16.8 MB
  // attn (16.8MB) + P (2.1MB) alias the Xhi+X8 region (35.7MB, dead after conv)
  float* attn         = (float*)Xhi;
  unsigned short* P   = (unsigned short*)((uint8_t*)Xhi +
                          (size_t)KSPL * BCH * CC * CC * 4 + 256);

  size_t needed = (size_t)(wsp - (uint8_t*)d_ws);   // ~113 MB
  if (ws_size < needed) {
    fill_sentinel<<<(out_size + 255) / 256, 256, 0, stream>>>(out, out_size);
    return;
  }

  for (int ch = 0; ch < CB / BCH; ++ch) {
    const float* xch = x + (size_t)ch * BCH * CC * CN;
    float* outch = out + (size_t)ch * BCH * CC * CN;
    unsigned short* Qhi = (unsigned short*)outch;   // Q pair lives in d_out
    unsigned short* Qlo = Qhi + (size_t)BCH * CC * CN;

    // re-zero Xhi+X8 every chunk (pads + heal attn/P aliasing corruption)
    hipMemsetAsync(Xhi, 0, XSPLIT * 2 + 2 * XSPLIT, stream);
    prep_xpad<<<BCH * 16 * 64, 256, 0, stream>>>(xch, Xhi, X8);
    if (ch == 0)
      prep_abig<<<(MR * K1) / 256, 256, 0, stream>>>(wq, wk, wv, bq, bk, bv,
                                                     Ahi, A8, bias);
    conv_k<<<dim3(6 * BCH * 16), 512, 0, stream>>>(Ahi, A8, Xhi, X8, bias,
                                                   Qhi, Qlo, Khi, Klo, Vt);
    gemm_k<1><<<dim3(16 * KSPL, 1, BCH), 256, 0, stream>>>(Qhi, Qlo, Khi, Klo, Vt,
                                                           attn, P, xch, gm, outch);
    softmax_k<<<BCH * 128, 256, 0, stream>>>(attn, P);
    gemm_k<2><<<dim3(128, 1, BCH), 256, 0, stream>>>(Qhi, Qlo, Khi, Klo, Vt,
                                                     attn, P, xch, gm, outch);
  }
}

// Round 10
// 1111.692 us; speedup vs baseline: 1.5568x; 1.0264x over previous
//
#include <hip/hip_runtime.h>
#include <stdint.h>

typedef __attribute__((ext_vector_type(8))) short bf16x8;
typedef __attribute__((ext_vector_type(4))) float f32x4;
typedef __attribute__((ext_vector_type(2))) long i64x2;
typedef __attribute__((ext_vector_type(8))) unsigned short u16x8;
typedef __attribute__((ext_vector_type(4))) unsigned short u16x4;

#define DI static __device__ __forceinline__

constexpr int CB = 8;          // batch (total)
constexpr int BCH = 4;         // batches per chunk (2 chunks)
constexpr int CC = 512;        // channels
constexpr int CN = 4096;       // H*W
constexpr int K1 = CC * 9;     // 4608
constexpr int MR = 3 * CC;     // 1536 output rows (q|k|v)
constexpr int KSPL = 4;        // QK^T split-K factor
constexpr size_t XSPLIT = (size_t)BCH * 66 * 66 * 512;

DI unsigned short f2bf(float f) {
  union { float f; uint32_t u; } v; v.f = f;
  uint32_t r = (v.u + 0x7FFFu + ((v.u >> 16) & 1u)) >> 16;  // RNE
  return (unsigned short)r;
}
DI float bf2f(unsigned short h) {
  union { uint32_t u; float f; } v; v.u = ((uint32_t)h) << 16;
  return v.f;
}
// manual OCP e4m3fn convert (RNE on mantissa; sat to 448); input |x| << 448 here
DI unsigned char f2e4m3(float x) {
  union { float f; uint32_t u; } v; v.f = x;
  uint32_t sgn = (v.u >> 24) & 0x80u;
  float a = fabsf(x);
  if (a < 0.015625f) {                       // subnormal: quantum 2^-9
    int qi = (int)rintf(a * 512.f);          // 0..8 (8 -> min normal 0x08)
    return (unsigned char)(sgn | (uint32_t)qi);
  }
  int e = (int)((v.u >> 23) & 0xff) - 127;
  uint32_t m3 = (v.u >> 20) & 7u;
  uint32_t rest = v.u & 0xFFFFFu;
  if (rest > 0x80000u || (rest == 0x80000u && (m3 & 1u))) {
    if (++m3 == 8u) { m3 = 0; ++e; }
  }
  if (e > 8 || (e == 8 && m3 == 7u)) return (unsigned char)(sgn | 0x7Eu);
  return (unsigned char)(sgn | ((uint32_t)(e + 7) << 3) | m3);
}
// byte position of k (0..63) inside a 64B pair-interleaved fp8 row:
// b128 at byte q*16 yields (k=q*8..+7) as long[0], (k=32+q*8..+7) as long[1]
DI int perm64(int k) { return (k & 7) + (((k >> 5) & 1) << 3) + (((k >> 3) & 3) << 4); }

DI void g2lds16(const void* g, void* l) {
  __builtin_amdgcn_global_load_lds((const __attribute__((address_space(1))) void*)g,
                                   (__attribute__((address_space(3))) void*)l, 16, 0, 0);
}
#define SBAR()  __builtin_amdgcn_s_barrier()
#define SCHED() __builtin_amdgcn_sched_barrier(0)

// ---- prep 1: Xhi (bf16, x2^7), X8 split0=Xlo8 (x2^8), split1=Xhi8 (x1) -----
__global__ __launch_bounds__(256) void prep_xpad(const float* __restrict__ x,
                                                 unsigned short* __restrict__ Xhi,
                                                 unsigned char* __restrict__ X8) {
  int tid = threadIdx.x;
  int w = tid & 63;
  int ccl = tid >> 6;
  int blk = blockIdx.x;               // 4096 = b(4) * ccg(16) * h(64)
  int h = blk & 63;
  int ccg = (blk >> 6) & 15;
  int b = blk >> 10;
  int c0 = (ccg * 4 + ccl) * 8;
  const float* xp = x + ((size_t)b * CC) * CN + h * 64 + w;
  u16x8 hi;
  unsigned long long lo8 = 0, hi8 = 0;
#pragma unroll
  for (int j = 0; j < 8; ++j) {
    float v = xp[(size_t)(c0 + j) * CN];
    unsigned short h16 = f2bf(v);
    float vhi = bf2f(h16);
    hi[j] = f2bf(vhi * 128.f);                    // exact shift
    lo8 |= (unsigned long long)f2e4m3((v - vhi) * 256.f) << (8 * j);
    hi8 |= (unsigned long long)f2e4m3(vhi) << (8 * j);
  }
  size_t pix = (((size_t)b * 66 + (h + 1)) * 66 + (w + 1)) * 512;
  *(u16x8*)&Xhi[pix + c0] = hi;
  size_t p8 = pix + (size_t)(c0 & ~63) + perm64(c0 & 63);   // c0 8-aligned
  *(unsigned long long*)&X8[p8] = lo8;
  *(unsigned long long*)&X8[XSPLIT + p8] = hi8;
}

// ---- prep 2: Ahi [1536][4608] bf16 (x2^7), A8 [1536][9216] fp8 -------------
__global__ __launch_bounds__(256) void prep_abig(
    const float* __restrict__ wq, const float* __restrict__ wk,
    const float* __restrict__ wv, const float* __restrict__ bq,
    const float* __restrict__ bk, const float* __restrict__ bv,
    unsigned short* __restrict__ Ahi, unsigned char* __restrict__ A8,
    float* __restrict__ bias) {
  unsigned id = blockIdx.x * 256 + threadIdx.x;   // total 1536*4608
  int m = id / K1;
  int r = id - m * K1;
  int t = r >> 9;
  int c = r & 511;
  int ky = t / 3;
  int kx = t - ky * 3;
  size_t ip = (size_t)m * 9216 + (size_t)(r & ~63) + perm64(r & 63);
  if (m < 1024) {
    const float* wp = (m < 512) ? wq : wk;
    int mm = (m < 512) ? m : m - 512;
    float wval = wp[(((size_t)mm * 512 + c) * 3 + ky) * 3 + kx];
    float whi = bf2f(f2bf(wval));
    Ahi[id] = f2bf(whi * 128.f);
    A8[ip] = f2e4m3(whi * 64.f);
    A8[ip + 4608] = f2e4m3((wval - whi) * 16384.f);
  } else {
    float wval = wv[(((size_t)(m - 1024) * 512 + c) * 3 + ky) * 3 + kx];
    Ahi[id] = f2bf(wval * 128.f);
    A8[ip] = 0;
    A8[ip + 4608] = 0;
  }
  if (id < 1536) {
    int mm = (int)id;
    bias[mm] = (mm < 512) ? bq[mm] : (mm < 1024) ? bk[mm - 512] : bv[mm - 1024];
  }
}

// ---- conv GEMM: 256x256, 4-slot ring, ONE barrier/ktile, bf16+fp8 phases ---
// ROUND-10: 3-slot ring needed the end-of-ktile lgkmcnt(0)+barrier (stage at
// body t hits slot t+2 = t-1 mod 3, racing slow readers). With 4 slots the
// stage target (t+2)%4 is disjoint from every slot readable within one-barrier
// wave drift (reads of slot s issue only in bodies s-1, s) -> end barrier and
// drain DELETED; 288 barrier+drain pairs removed per heavy block. The head
// vmcnt(4) invariant "stage(t+1) landed" (NXT-read safety) is unchanged.
__global__ __launch_bounds__(512, 2) void conv_k(
    const unsigned short* __restrict__ Ahi,
    const unsigned char* __restrict__ A8,
    const unsigned short* __restrict__ Xhi,
    const unsigned char* __restrict__ X8,
    const float* __restrict__ bias,
    unsigned short* __restrict__ Qhi, unsigned short* __restrict__ Qlo,
    unsigned short* __restrict__ Khi, unsigned short* __restrict__ Klo,
    unsigned short* __restrict__ Vt)
{
  __shared__ __align__(16) unsigned char smem[4 * 32768];
  const int tid = threadIdx.x;
  const int lane = tid & 63;
  const int wid = tid >> 6;
  const int wr = wid >> 2;            // 0..1 (M)
  const int wc = wid & 3;             // 0..3 (N)

  // Balanced + XCD-local: heavy q/k blocks = orig 0..255 (one per CU first),
  // 128 light v blocks backfill; XCD x owns nb panels [8x, 8x+8).
  int orig = blockIdx.x;
  int xcd, nbl, mb;
  if (orig < 256) { xcd = orig & 7; int j = orig >> 3; nbl = j >> 2; mb = j & 3; }
  else { int o = orig - 256; xcd = o & 7; int j = o >> 3; nbl = j >> 1; mb = 4 + (j & 1); }
  const int nb = xcd * 8 + nbl;
  const int m0 = mb * 256;
  const int n0 = nb * 256;
  const int bidx = n0 >> 12;
  const int nl0 = n0 & (CN - 1);
  const int h0 = nl0 >> 6;

  // per-thread staging bases; source chunk pre-swizzled by f(srow)
  const int srow = tid >> 2;          // 0..127
  const int scu = tid & 3;
  const int scuS = scu ^ ((srow >> 1) & 3);
  const size_t pixOfs = (((size_t)(bidx * 66 + h0 + (srow >> 6))) * 66 + (srow & 63)) * 512;
  const unsigned short* gAh0 = Ahi + (size_t)(m0 + srow) * K1 + scuS * 8;
  const unsigned short* gAh1 = gAh0 + (size_t)128 * K1;
  const unsigned short* gBh0 = Xhi + pixOfs + scuS * 8;
  const unsigned short* gBh1 = gBh0 + (size_t)2 * 66 * 512;
  const unsigned char* gA80 = A8 + (size_t)(m0 + srow) * 9216 + scuS * 16;
  const unsigned char* gA81 = gA80 + (size_t)128 * 9216;
  const unsigned char* gB80 = X8 + pixOfs + scuS * 16;
  const unsigned char* gB81 = gB80 + (size_t)2 * 66 * 512;
  const int wofs = wid * 1024;

  // phase-1 cursor (s0: tap 0..8 x c0 step 32 -> 144 ktiles)
  int c0S = 0, kxS = 0, tapS = 0;
  size_t tapOfs = 0;
  auto stage1 = [&](int slot) {
    int aOfs = tapS * 512 + c0S;
    size_t bOfs = tapOfs + (size_t)c0S;
    unsigned char* lA = smem + slot * 32768 + wofs;
    unsigned char* lB = smem + slot * 32768 + 16384 + wofs;
    g2lds16(gAh0 + aOfs, lA);
    g2lds16(gAh1 + aOfs, lA + 8192);
    g2lds16(gBh0 + bOfs, lB);
    g2lds16(gBh1 + bOfs, lB + 8192);
    c0S += 32;
    if (c0S == 512) {
      c0S = 0; ++tapS;
      if (kxS == 2) { kxS = 0; tapOfs += (size_t)64 * 512; }
      else { ++kxS; tapOfs += 512; }
    }
  };
  // phase-2 cursor (s'=0:Whi8*Xlo8, s'=1:Wlo8*Xhi8; tap 0..8 x c0 step 64)
  int c8 = 0, kx8 = 0, tap8 = 0, s8 = 0;
  size_t tapOfs8 = 0;
  auto stage2 = [&](int slot) {
    int aOfs = s8 * 4608 + tap8 * 512 + c8;
    size_t bOfs = (size_t)s8 * XSPLIT + tapOfs8 + (size_t)c8;
    unsigned char* lA = smem + slot * 32768 + wofs;
    unsigned char* lB = smem + slot * 32768 + 16384 + wofs;
    g2lds16(gA80 + aOfs, lA);
    g2lds16(gA81 + aOfs, lA + 8192);
    g2lds16(gB80 + bOfs, lB);
    g2lds16(gB81 + bOfs, lB + 8192);
    c8 += 64;
    if (c8 == 512) {
      c8 = 0; ++tap8;
      if (tap8 == 9) { tap8 = 0; kx8 = 0; tapOfs8 = 0; ++s8; }
      else if (kx8 == 2) { kx8 = 0; tapOfs8 += (size_t)64 * 512; }
      else { ++kx8; tapOfs8 += 512; }
    }
  };

  f32x4 acc[8][4];
  const f32x4 fz = {0.f, 0.f, 0.f, 0.f};
#pragma unroll
  for (int i = 0; i < 8; ++i)
#pragma unroll
    for (int j = 0; j < 4; ++j) acc[i][j] = fz;

  const int rA = wr * 128 + (lane & 15);
  const int rB = wc * 64 + (lane & 15);
  const int kq = (lane >> 4) * 16;
  const int kqA = kq ^ (((rA >> 1) & 3) << 4);   // r7 swizzle (0-conflict)
  const int kqB = kq ^ (((rB >> 1) & 3) << 4);

  int slotC, slotS, t2;

  // ================= phase 1: bf16 s0, 144 ktiles =================
  stage1(0);
  stage1(1);
  asm volatile("s_waitcnt vmcnt(4)" ::: "memory");
  SCHED(); SBAR(); SCHED();
  {
    bf16x8 afA[4], bfA[4], afB[4], bfB[4], af1[4];
#pragma unroll
    for (int mf = 0; mf < 4; ++mf)
      afA[mf] = *(const bf16x8*)(smem + (rA + mf * 16) * 64 + kqA);
#pragma unroll
    for (int nf = 0; nf < 4; ++nf)
      bfA[nf] = *(const bf16x8*)(smem + 16384 + (rB + nf * 16) * 64 + kqB);
    slotC = 0; slotS = 2; t2 = 2;

#define CONV_BF(CURA, CURB, NXTA, NXTB)                                       \
  {                                                                           \
    if (t2 < 144) {                                                           \
      stage1(slotS); slotS = (slotS + 1) & 3;                                 \
      asm volatile("s_waitcnt vmcnt(4)" ::: "memory");                        \
    } else {                                                                  \
      asm volatile("s_waitcnt vmcnt(0)" ::: "memory");                        \
    }                                                                         \
    SCHED(); SBAR(); SCHED();                                                 \
    const unsigned char* lA = smem + slotC * 32768;                           \
    const int slotN = (slotC + 1) & 3;                                        \
    const unsigned char* lAn = smem + slotN * 32768;                          \
    _Pragma("unroll")                                                         \
    for (int mf = 0; mf < 4; ++mf)                                            \
      af1[mf] = *(const bf16x8*)(lA + (rA + 64 + mf * 16) * 64 + kqA);        \
    __builtin_amdgcn_s_setprio(1);                                            \
    _Pragma("unroll")                                                         \
    for (int mf = 0; mf < 4; ++mf) {                                          \
      _Pragma("unroll")                                                       \
      for (int nf = 0; nf < 4; ++nf)                                          \
        acc[mf][nf] = __builtin_amdgcn_mfma_f32_16x16x32_bf16(                \
            CURA[mf], CURB[nf], acc[mf][nf], 0, 0, 0);                        \
    }                                                                         \
    __builtin_amdgcn_s_setprio(0);                                            \
    _Pragma("unroll")                                                         \
    for (int mf = 0; mf < 4; ++mf)                                            \
      NXTA[mf] = *(const bf16x8*)(lAn + (rA + mf * 16) * 64 + kqA);           \
    _Pragma("unroll")                                                         \
    for (int nf = 0; nf < 4; ++nf)                                            \
      NXTB[nf] = *(const bf16x8*)(lAn + 16384 + (rB + nf * 16) * 64 + kqB);   \
    __builtin_amdgcn_s_setprio(1);                                            \
    _Pragma("unroll")                                                         \
    for (int mf = 0; mf < 4; ++mf) {                                          \
      _Pragma("unroll")                                                       \
      for (int nf = 0; nf < 4; ++nf)                                          \
        acc[mf + 4][nf] = __builtin_amdgcn_mfma_f32_16x16x32_bf16(            \
            af1[mf], CURB[nf], acc[mf + 4][nf], 0, 0, 0);                     \
    }                                                                         \
    __builtin_amdgcn_s_setprio(0);                                            \
    slotC = slotN;                                                            \
    ++t2;                                                                     \
  }

    for (int t = 0; t < 144; t += 2) {
      CONV_BF(afA, bfA, afB, bfB)
      CONV_BF(afB, bfB, afA, bfA)
    }
#undef CONV_BF
  }

  // ================= phase 2 (q/k only): fp8 s1+s2, 144 ktiles of K=64 =====
  if (m0 < 1024) {
    stage2(0);
    stage2(1);
    asm volatile("s_waitcnt vmcnt(4)" ::: "memory");
    SCHED(); SBAR(); SCHED();
    i64x2 a8A[4], b8A[4], a8B[4], b8B[4], a18[4];
#pragma unroll
    for (int mf = 0; mf < 4; ++mf)
      a8A[mf] = *(const i64x2*)(smem + (rA + mf * 16) * 64 + kqA);
#pragma unroll
    for (int nf = 0; nf < 4; ++nf)
      b8A[nf] = *(const i64x2*)(smem + 16384 + (rB + nf * 16) * 64 + kqB);
    slotC = 0; slotS = 2; t2 = 2;

#define CONV_F8(CURA, CURB, NXTA, NXTB)                                       \
  {                                                                           \
    if (t2 < 144) {                                                           \
      stage2(slotS); slotS = (slotS + 1) & 3;                                 \
      asm volatile("s_waitcnt vmcnt(4)" ::: "memory");                        \
    } else {                                                                  \
      asm volatile("s_waitcnt vmcnt(0)" ::: "memory");                        \
    }                                                                         \
    SCHED(); SBAR(); SCHED();                                                 \
    const unsigned char* lA = smem + slotC * 32768;                           \
    const int slotN = (slotC + 1) & 3;                                        \
    const unsigned char* lAn = smem + slotN * 32768;                          \
    _Pragma("unroll")                                                         \
    for (int mf = 0; mf < 4; ++mf)                                            \
      a18[mf] = *(const i64x2*)(lA + (rA + 64 + mf * 16) * 64 + kqA);         \
    __builtin_amdgcn_s_setprio(1);                                            \
    _Pragma("unroll")                                                         \
    for (int mf = 0; mf < 4; ++mf) {                                          \
      _Pragma("unroll")                                                       \
      for (int nf = 0; nf < 4; ++nf) {                                        \
        acc[mf][nf] = __builtin_amdgcn_mfma_f32_16x16x32_fp8_fp8(             \
            CURA[mf][0], CURB[nf][0], acc[mf][nf], 0, 0, 0);                  \
        acc[mf][nf] = __builtin_amdgcn_mfma_f32_16x16x32_fp8_fp8(             \
            CURA[mf][1], CURB[nf][1], acc[mf][nf], 0, 0, 0);                  \
      }                                                                       \
    }                                                                         \
    __builtin_amdgcn_s_setprio(0);                                            \
    _Pragma("unroll")                                                         \
    for (int mf = 0; mf < 4; ++mf)                                            \
      NXTA[mf] = *(const i64x2*)(lAn + (rA + mf * 16) * 64 + kqA);            \
    _Pragma("unroll")                                                         \
    for (int nf = 0; nf < 4; ++nf)                                            \
      NXTB[nf] = *(const i64x2*)(lAn + 16384 + (rB + nf * 16) * 64 + kqB);    \
    __builtin_amdgcn_s_setprio(1);                                            \
    _Pragma("unroll")                                                         \
    for (int mf = 0; mf < 4; ++mf) {                                          \
      _Pragma("unroll")                                                       \
      for (int nf = 0; nf < 4; ++nf) {                                        \
        acc[mf + 4][nf] = __builtin_amdgcn_mfma_f32_16x16x32_fp8_fp8(         \
            a18[mf][0], CURB[nf][0], acc[mf + 4][nf], 0, 0, 0);               \
        acc[mf + 4][nf] = __builtin_amdgcn_mfma_f32_16x16x32_fp8_fp8(         \
            a18[mf][1], CURB[nf][1], acc[mf + 4][nf], 0, 0, 0);               \
      }                                                                       \
    }                                                                         \
    __builtin_amdgcn_s_setprio(0);                                            \
    slotC = slotN;                                                            \
    ++t2;                                                                     \
  }

    for (int t = 0; t < 144; t += 2) {
      CONV_F8(a8A, b8A, a8B, b8B)
      CONV_F8(a8B, b8B, a8A, b8A)
    }
#undef CONV_F8
  }

  // ---- epilogue: all products at scale 2^14 -> * 2^-14 ----
  constexpr float SC = 1.f / 16384.f;
#pragma unroll
  for (int mf = 0; mf < 8; ++mf) {
#pragma unroll
    for (int nf = 0; nf < 4; ++nf) {
      f32x4 a = acc[mf][nf];
      int mrow = m0 + wr * 128 + mf * 16 + ((lane >> 4) << 2);
      int ncol = nl0 + wc * 64 + nf * 16 + (lane & 15);
      if (m0 < 512) {
#pragma unroll
        for (int j = 0; j < 4; ++j) {
          float v = a[j] * SC + bias[mrow + j];
          unsigned short h16 = f2bf(v);
          size_t o = ((size_t)bidx * CC + (mrow + j)) * CN + ncol;
          Qhi[o] = h16;
          Qlo[o] = f2bf(v - bf2f(h16));
        }
      } else if (m0 < 1024) {
#pragma unroll
        for (int j = 0; j < 4; ++j) {
          float v = a[j] * SC + bias[mrow + j];
          unsigned short h16 = f2bf(v);
          size_t o = ((size_t)bidx * CC + (mrow + j - 512)) * CN + ncol;
          Khi[o] = h16;
          Klo[o] = f2bf(v - bf2f(h16));
        }
      } else {
        u16x4 vs;                     // V written transposed: Vt[b][n][d]
#pragma unroll
        for (int j = 0; j < 4; ++j) vs[j] = f2bf(a[j] * SC + bias[mrow + j]);
        *(u16x4*)&Vt[((size_t)bidx * CN + ncol) * CC + (mrow - 1024)] = vs;
      }
    }
  }
}

// ---- MFMA GEMM: MODE 1=QK^T (3-phase hi/lo, split-K), 2=PV -----------------
DI int sofs(int row, int kb) { return row * 128 + (kb ^ ((row & 7) << 4)); }

template<int MODE>
__global__ __launch_bounds__(256) void gemm_k(
    const unsigned short* __restrict__ Qhi, const unsigned short* __restrict__ Qlo,
    const unsigned short* __restrict__ Khi, const unsigned short* __restrict__ Klo,
    const unsigned short* __restrict__ Vt,
    float* __restrict__ attn,
    const unsigned short* __restrict__ P,
    const float* __restrict__ xin,
    const float* __restrict__ gamma,
    float* __restrict__ out)
{
  __shared__ __align__(16) unsigned char sA[16384];
  __shared__ __align__(16) unsigned char sB[16384];
  const int tid = threadIdx.x;
  const int lane = tid & 63;
  const int wav = tid >> 6;
  const int wr = wav >> 1, wc = wav & 1;

  int m0, n0, bidx, Kbeg = 0, Kend, ks = 0;
  if constexpr (MODE == 1) {
    int tile = blockIdx.x & 15;
    ks = blockIdx.x >> 4;
    m0 = (tile & 3) * 128;
    n0 = (tile >> 2) * 128;
    bidx = blockIdx.z;
    Kbeg = ks * (3 * CN / KSPL);
    Kend = Kbeg + (3 * CN / KSPL);
  } else {
    m0 = (blockIdx.x & 3) * 128;
    n0 = (blockIdx.x >> 2) * 128;
    bidx = blockIdx.z;
    Kend = CC;
  }

  auto stage = [&](int k0) {
#pragma unroll
    for (int q = 0; q < 4; ++q) {
      int ci = q * 256 + tid;
      int row = ci >> 3;
      int ke = ((ci & 7) ^ (row & 7)) * 8;
      const unsigned short* ap;
      const unsigned short* bp;
      if constexpr (MODE == 1) {
        int ph = k0 >> 12;
        int kin = k0 & (CN - 1);
        const unsigned short* Aq = (ph == 2) ? Qlo : Qhi;
        const unsigned short* Bk = (ph == 1) ? Klo : Khi;
        ap = Aq + ((size_t)bidx * CC + (m0 + row)) * CN + (kin + ke);
        bp = Bk + ((size_t)bidx * CC + (n0 + row)) * CN + (kin + ke);
      } else {
        ap = P + ((size_t)bidx * CC + (m0 + row)) * CC + (k0 + ke);
        bp = Vt + ((size_t)bidx * CN + (n0 + row)) * CC + (k0 + ke);
      }
      int wbase = (q * 256 + wav * 64) * 16;
      g2lds16(ap, sA + wbase);
      g2lds16(bp, sB + wbase);
    }
  };

  f32x4 acc[4][4];
  const f32x4 fz = {0.f, 0.f, 0.f, 0.f};
#pragma unroll
  for (int i = 0; i < 4; ++i)
#pragma unroll
    for (int j = 0; j < 4; ++j) acc[i][j] = fz;

  for (int k0 = Kbeg; k0 < Kend; k0 += 64) {
    stage(k0);
    __syncthreads();
#pragma unroll
    for (int kkp = 0; kkp < 2; ++kkp) {
      bf16x8 af[4], bfv[4];
#pragma unroll
      for (int mf = 0; mf < 4; ++mf)
        af[mf] = *(const bf16x8*)&sA[sofs(wr * 64 + mf * 16 + (lane & 15),
                                          kkp * 64 + (lane >> 4) * 16)];
#pragma unroll
      for (int nf = 0; nf < 4; ++nf)
        bfv[nf] = *(const bf16x8*)&sB[sofs(wc * 64 + nf * 16 + (lane & 15),
                                           kkp * 64 + (lane >> 4) * 16)];
#pragma unroll
      for (int mf = 0; mf < 4; ++mf)
#pragma unroll
        for (int nf = 0; nf < 4; ++nf)
          acc[mf][nf] = __builtin_amdgcn_mfma_f32_16x16x32_bf16(
              af[mf], bfv[nf], acc[mf][nf], 0, 0, 0);
    }
    __syncthreads();
  }

  float g = 0.f;
  if constexpr (MODE == 2) g = gamma[0];
#pragma unroll
  for (int mf = 0; mf < 4; ++mf) {
#pragma unroll
    for (int nf = 0; nf < 4; ++nf) {
      f32x4 a = acc[mf][nf];
      int mrow = m0 + wr * 64 + mf * 16 + ((lane >> 4) << 2);
      int ncol = n0 + wc * 64 + nf * 16 + (lane & 15);
      if constexpr (MODE == 1) {
        size_t pbase = (size_t)ks * ((size_t)BCH * CC * CC);
#pragma unroll
        for (int j = 0; j < 4; ++j)
          attn[pbase + ((size_t)bidx * CC + (mrow + j)) * CC + ncol] = a[j];
      } else {
#pragma unroll
        for (int j = 0; j < 4; ++j) {
          size_t o = ((size_t)bidx * CC + (mrow + j)) * CN + ncol;
          out[o] = g * a[j] + xin[o];
        }
      }
    }
  }
}

// ---- softmax over d (512): sum KSPL split-K partials, one wave per row -----
__global__ __launch_bounds__(256) void softmax_k(const float* __restrict__ attn,
                                                 unsigned short* __restrict__ P) {
  int row = blockIdx.x * 4 + (threadIdx.x >> 6);
  int lane = threadIdx.x & 63;
  constexpr size_t PS = (size_t)BCH * CC * CC;
  const float* rp = attn + (size_t)row * 512 + lane * 8;
  f32x4 a = {0.f, 0.f, 0.f, 0.f};
  f32x4 b = {0.f, 0.f, 0.f, 0.f};
#pragma unroll
  for (int ksp = 0; ksp < KSPL; ++ksp) {
    a += *(const f32x4*)(rp + (size_t)ksp * PS);
    b += *(const f32x4*)(rp + (size_t)ksp * PS + 4);
  }
  float mx = fmaxf(fmaxf(fmaxf(a[0], a[1]), fmaxf(a[2], a[3])),
                   fmaxf(fmaxf(b[0], b[1]), fmaxf(b[2], b[3])));
#pragma unroll
  for (int s = 32; s > 0; s >>= 1) mx = fmaxf(mx, __shfl_xor(mx, s, 64));
  float e[8];
  float sum = 0.f;
#pragma unroll
  for (int j = 0; j < 4; ++j) { e[j] = __expf(a[j] - mx); sum += e[j]; }
#pragma unroll
  for (int j = 0; j < 4; ++j) { e[4 + j] = __expf(b[j] - mx); sum += e[4 + j]; }
#pragma unroll
  for (int s = 32; s > 0; s >>= 1) sum += __shfl_xor(sum, s, 64);
  float inv = 1.0f / sum;
  u16x8 o;
#pragma unroll
  for (int j = 0; j < 8; ++j) o[j] = f2bf(e[j] * inv);
  *(u16x8*)&P[(size_t)row * 512 + lane * 8] = o;
}

// ---- diagnostic: fill out with sentinel if workspace is too small ----------
__global__ __launch_bounds__(256) void fill_sentinel(float* __restrict__ out, int n) {
  int i = blockIdx.x * 256 + threadIdx.x;
  if (i < n) out[i] = 1.0e4f;
}

// ---------------------------------------------------------------------------
extern "C" void kernel_launch(void* const* d_in, const int* in_sizes, int n_in,
                              void* d_out, int out_size, void* d_ws, size_t ws_size,
                              hipStream_t stream) {
  (void)in_sizes; (void)n_in;
  const float* x  = (const float*)d_in[0];
  const float* wq = (const float*)d_in[1];
  const float* bq = (const float*)d_in[2];
  const float* wk = (const float*)d_in[3];
  const float* bk = (const float*)d_in[4];
  const float* wv = (const float*)d_in[5];
  const float* bv = (const float*)d_in[6];
  const float* gm = (const float*)d_in[7];
  float* out = (float*)d_out;

  uint8_t* wsp = (uint8_t*)d_ws;
  auto take = [&](size_t bytes) {
    uint8_t* p = wsp;
    wsp += (bytes + 255) & ~(size_t)255;
    return p;
  };
  unsigned short* Xhi = (unsigned short*)take(XSPLIT * 2);          // 17.8 MB
  unsigned char*  X8  = (unsigned char*)take(2 * XSPLIT);           // 17.8 MB
  unsigned short* Ahi = (unsigned short*)take((size_t)MR * K1 * 2); // 13.5 MB
  unsigned char*  A8  = (unsigned char*)take((size_t)MR * 2 * K1);  // 13.5 MB
  float* bias         = (float*)take((size_t)MR * 4);
  unsigned short* Khi = (unsigned short*)take((size_t)BCH * CC * CN * 2);  // 16.8 MB
  unsigned short* Klo = (unsigned short*)take((size_t)BCH * CC * CN * 2);  // 16.8 MB
  unsigned short* Vt  = (unsigned short*)take((size_t)BCH * CN * CC * 2);  // 16.8 MB
  // attn (16.8MB) + P (2.1MB) alias the Xhi+X8 region (35.7MB, dead after conv)
  float* attn         = (float*)Xhi;
  unsigned short* P   = (unsigned short*)((uint8_t*)Xhi +
                          (size_t)KSPL * BCH * CC * CC * 4 + 256);

  size_t needed = (size_t)(wsp - (uint8_t*)d_ws);   // ~113 MB
  if (ws_size < needed) {
    fill_sentinel<<<(out_size + 255) / 256, 256, 0, stream>>>(out, out_size);
    return;
  }

  for (int ch = 0; ch < CB / BCH; ++ch) {
    const float* xch = x + (size_t)ch * BCH * CC * CN;
    float* outch = out + (size_t)ch * BCH * CC * CN;
    unsigned short* Qhi = (unsigned short*)outch;   // Q pair lives in d_out
    unsigned short* Qlo = Qhi + (size_t)BCH * CC * CN;

    // re-zero Xhi+X8 every chunk (pads + heal attn/P aliasing corruption)
    hipMemsetAsync(Xhi, 0, XSPLIT * 2 + 2 * XSPLIT, stream);
    prep_xpad<<<BCH * 16 * 64, 256, 0, stream>>>(xch, Xhi, X8);
    if (ch == 0)
      prep_abig<<<(MR * K1) / 256, 256, 0, stream>>>(wq, wk, wv, bq, bk, bv,
                                                     Ahi, A8, bias);
    conv_k<<<dim3(6 * BCH * 16), 512, 0, stream>>>(Ahi, A8, Xhi, X8, bias,
                                                   Qhi, Qlo, Khi, Klo, Vt);
    gemm_k<1><<<dim3(16 * KSPL, 1, BCH), 256, 0, stream>>>(Qhi, Qlo, Khi, Klo, Vt,
                                                           attn, P, xch, gm, outch);
    softmax_k<<<BCH * 128, 256, 0, stream>>>(attn, P);
    gemm_k<2><<<dim3(128, 1, BCH), 256, 0, stream>>>(Qhi, Qlo, Khi, Klo, Vt,
                                                     attn, P, xch, gm, outch);
  }
}

// Round 11
// 1053.503 us; speedup vs baseline: 1.6428x; 1.0552x over previous
//
#include <hip/hip_runtime.h>
#include <stdint.h>

typedef __attribute__((ext_vector_type(8))) short bf16x8;
typedef __attribute__((ext_vector_type(4))) float f32x4;
typedef __attribute__((ext_vector_type(2))) long i64x2;
typedef __attribute__((ext_vector_type(8))) unsigned short u16x8;
typedef __attribute__((ext_vector_type(4))) unsigned short u16x4;

#define DI static __device__ __forceinline__

constexpr int CB = 8;          // batch (total)
constexpr int BCH = 4;         // batches per chunk (2 chunks)
constexpr int CC = 512;        // channels
constexpr int CN = 4096;       // H*W
constexpr int K1 = CC * 9;     // 4608
constexpr int MR = 3 * CC;     // 1536 output rows (q|k|v)
constexpr int KSPL = 4;        // QK^T split-K factor
constexpr size_t XSPLIT = (size_t)BCH * 66 * 66 * 512;

DI unsigned short f2bf(float f) {
  union { float f; uint32_t u; } v; v.f = f;
  uint32_t r = (v.u + 0x7FFFu + ((v.u >> 16) & 1u)) >> 16;  // RNE
  return (unsigned short)r;
}
DI float bf2f(unsigned short h) {
  union { uint32_t u; float f; } v; v.u = ((uint32_t)h) << 16;
  return v.f;
}
// manual OCP e4m3fn convert (RNE on mantissa; sat to 448); input |x| << 448 here
DI unsigned char f2e4m3(float x) {
  union { float f; uint32_t u; } v; v.f = x;
  uint32_t sgn = (v.u >> 24) & 0x80u;
  float a = fabsf(x);
  if (a < 0.015625f) {                       // subnormal: quantum 2^-9
    int qi = (int)rintf(a * 512.f);          // 0..8 (8 -> min normal 0x08)
    return (unsigned char)(sgn | (uint32_t)qi);
  }
  int e = (int)((v.u >> 23) & 0xff) - 127;
  uint32_t m3 = (v.u >> 20) & 7u;
  uint32_t rest = v.u & 0xFFFFFu;
  if (rest > 0x80000u || (rest == 0x80000u && (m3 & 1u))) {
    if (++m3 == 8u) { m3 = 0; ++e; }
  }
  if (e > 8 || (e == 8 && m3 == 7u)) return (unsigned char)(sgn | 0x7Eu);
  return (unsigned char)(sgn | ((uint32_t)(e + 7) << 3) | m3);
}
// byte position of k (0..63) inside a 64B pair-interleaved fp8 row:
// b128 at byte q*16 yields (k=q*8..+7) as long[0], (k=32+q*8..+7) as long[1]
DI int perm64(int k) { return (k & 7) + (((k >> 5) & 1) << 3) + (((k >> 3) & 3) << 4); }

DI void g2lds16(const void* g, void* l) {
  __builtin_amdgcn_global_load_lds((const __attribute__((address_space(1))) void*)g,
                                   (__attribute__((address_space(3))) void*)l, 16, 0, 0);
}
#define SBAR()  __builtin_amdgcn_s_barrier()
#define SCHED() __builtin_amdgcn_sched_barrier(0)

// ---- prep 1: Xhi (bf16, x2^7), X8 split0=Xlo8 (x2^8), split1=Xhi8 (x1) -----
__global__ __launch_bounds__(256) void prep_xpad(const float* __restrict__ x,
                                                 unsigned short* __restrict__ Xhi,
                                                 unsigned char* __restrict__ X8) {
  int tid = threadIdx.x;
  int w = tid & 63;
  int ccl = tid >> 6;
  int blk = blockIdx.x;               // 4096 = b(4) * ccg(16) * h(64)
  int h = blk & 63;
  int ccg = (blk >> 6) & 15;
  int b = blk >> 10;
  int c0 = (ccg * 4 + ccl) * 8;
  const float* xp = x + ((size_t)b * CC) * CN + h * 64 + w;
  u16x8 hi;
  unsigned long long lo8 = 0, hi8 = 0;
#pragma unroll
  for (int j = 0; j < 8; ++j) {
    float v = xp[(size_t)(c0 + j) * CN];
    unsigned short h16 = f2bf(v);
    float vhi = bf2f(h16);
    hi[j] = f2bf(vhi * 128.f);                    // exact shift
    lo8 |= (unsigned long long)f2e4m3((v - vhi) * 256.f) << (8 * j);
    hi8 |= (unsigned long long)f2e4m3(vhi) << (8 * j);
  }
  size_t pix = (((size_t)b * 66 + (h + 1)) * 66 + (w + 1)) * 512;
  *(u16x8*)&Xhi[pix + c0] = hi;
  size_t p8 = pix + (size_t)(c0 & ~63) + perm64(c0 & 63);   // c0 8-aligned
  *(unsigned long long*)&X8[p8] = lo8;
  *(unsigned long long*)&X8[XSPLIT + p8] = hi8;
}

// ---- prep 2: Ahi [1536][4608] bf16 (x2^7), A8 [1536][9216] fp8 -------------
__global__ __launch_bounds__(256) void prep_abig(
    const float* __restrict__ wq, const float* __restrict__ wk,
    const float* __restrict__ wv, const float* __restrict__ bq,
    const float* __restrict__ bk, const float* __restrict__ bv,
    unsigned short* __restrict__ Ahi, unsigned char* __restrict__ A8,
    float* __restrict__ bias) {
  unsigned id = blockIdx.x * 256 + threadIdx.x;   // total 1536*4608
  int m = id / K1;
  int r = id - m * K1;
  int t = r >> 9;
  int c = r & 511;
  int ky = t / 3;
  int kx = t - ky * 3;
  size_t ip = (size_t)m * 9216 + (size_t)(r & ~63) + perm64(r & 63);
  if (m < 1024) {
    const float* wp = (m < 512) ? wq : wk;
    int mm = (m < 512) ? m : m - 512;
    float wval = wp[(((size_t)mm * 512 + c) * 3 + ky) * 3 + kx];
    float whi = bf2f(f2bf(wval));
    Ahi[id] = f2bf(whi * 128.f);
    A8[ip] = f2e4m3(whi * 64.f);
    A8[ip + 4608] = f2e4m3((wval - whi) * 16384.f);
  } else {
    float wval = wv[(((size_t)(m - 1024) * 512 + c) * 3 + ky) * 3 + kx];
    Ahi[id] = f2bf(wval * 128.f);
    A8[ip] = 0;
    A8[ip + 4608] = 0;
  }
  if (id < 1536) {
    int mm = (int)id;
    bias[mm] = (mm < 512) ? bq[mm] : (mm < 1024) ? bk[mm - 512] : bv[mm - 1024];
  }
}

// ---- conv GEMM: 4-slot ring, one barrier/ktile, bf16+fp8 phases ------------
// ROUND-11: heavy q/k blocks (256x256, 288 ktiles) = ids 0..255 as before.
// v is re-tiled 128(M)x256(N) -> 256 light blocks (ids 256..511): every CU
// gets 1 heavy + 1 light, killing the half-chip-idle 144-ktile v tail.
// Light loop = heavy phase-1 minus the af1 half: 3 loads/stage -> vmcnt(3)
// (prologue 6->3 = stage(0) landed; body <=6->3 = stage(t+1) landed; same
// 4-slot disjointness proof). NXT reads precede the MFMA cluster.
__global__ __launch_bounds__(512, 2) void conv_k(
    const unsigned short* __restrict__ Ahi,
    const unsigned char* __restrict__ A8,
    const unsigned short* __restrict__ Xhi,
    const unsigned char* __restrict__ X8,
    const float* __restrict__ bias,
    unsigned short* __restrict__ Qhi, unsigned short* __restrict__ Qlo,
    unsigned short* __restrict__ Khi, unsigned short* __restrict__ Klo,
    unsigned short* __restrict__ Vt)
{
  __shared__ __align__(16) unsigned char smem[4 * 32768];
  const int tid = threadIdx.x;
  const int lane = tid & 63;
  const int wid = tid >> 6;
  const int wr = wid >> 2;            // 0..1 (M)
  const int wc = wid & 3;             // 0..3 (N)

  // XCD-local mapping: xcd = id&7 owns nb panels [8x, 8x+8) for heavy+light.
  int orig = blockIdx.x;
  int xcd, nbl, m0;
  if (orig < 256) {                   // heavy q/k: 256x256
    xcd = orig & 7; int j = orig >> 3;
    nbl = j >> 2;
    m0 = (j & 3) * 256;               // 0..768
  } else {                            // light v: 128x256
    int o = orig - 256;
    xcd = o & 7; int j = o >> 3;      // 0..31
    nbl = j >> 2;
    m0 = 1024 + (j & 3) * 128;        // 1024..1408
  }
  const int nb = xcd * 8 + nbl;
  const int n0 = nb * 256;
  const int bidx = n0 >> 12;
  const int nl0 = n0 & (CN - 1);
  const int h0 = nl0 >> 6;

  // per-thread staging bases; source chunk pre-swizzled by f(srow)
  const int srow = tid >> 2;          // 0..127
  const int scu = tid & 3;
  const int scuS = scu ^ ((srow >> 1) & 3);
  const size_t pixOfs = (((size_t)(bidx * 66 + h0 + (srow >> 6))) * 66 + (srow & 63)) * 512;
  const unsigned short* gAh0 = Ahi + (size_t)(m0 + srow) * K1 + scuS * 8;
  const unsigned short* gAh1 = gAh0 + (size_t)128 * K1;
  const unsigned short* gBh0 = Xhi + pixOfs + scuS * 8;
  const unsigned short* gBh1 = gBh0 + (size_t)2 * 66 * 512;
  const unsigned char* gA80 = A8 + (size_t)(m0 + srow) * 9216 + scuS * 16;
  const unsigned char* gA81 = gA80 + (size_t)128 * 9216;
  const unsigned char* gB80 = X8 + pixOfs + scuS * 16;
  const unsigned char* gB81 = gB80 + (size_t)2 * 66 * 512;
  const int wofs = wid * 1024;

  // phase-1 cursor (s0: tap 0..8 x c0 step 32 -> 144 ktiles)
  int c0S = 0, kxS = 0, tapS = 0;
  size_t tapOfs = 0;
  auto stage1 = [&](int slot) {       // heavy: 4 loads
    int aOfs = tapS * 512 + c0S;
    size_t bOfs = tapOfs + (size_t)c0S;
    unsigned char* lA = smem + slot * 32768 + wofs;
    unsigned char* lB = smem + slot * 32768 + 16384 + wofs;
    g2lds16(gAh0 + aOfs, lA);
    g2lds16(gAh1 + aOfs, lA + 8192);
    g2lds16(gBh0 + bOfs, lB);
    g2lds16(gBh1 + bOfs, lB + 8192);
    c0S += 32;
    if (c0S == 512) {
      c0S = 0; ++tapS;
      if (kxS == 2) { kxS = 0; tapOfs += (size_t)64 * 512; }
      else { ++kxS; tapOfs += 512; }
    }
  };
  auto stage1v = [&](int slot) {      // light: 3 loads (A is 128 rows)
    int aOfs = tapS * 512 + c0S;
    size_t bOfs = tapOfs + (size_t)c0S;
    unsigned char* lA = smem + slot * 32768 + wofs;
    unsigned char* lB = smem + slot * 32768 + 16384 + wofs;
    g2lds16(gAh0 + aOfs, lA);
    g2lds16(gBh0 + bOfs, lB);
    g2lds16(gBh1 + bOfs, lB + 8192);
    c0S += 32;
    if (c0S == 512) {
      c0S = 0; ++tapS;
      if (kxS == 2) { kxS = 0; tapOfs += (size_t)64 * 512; }
      else { ++kxS; tapOfs += 512; }
    }
  };
  // phase-2 cursor (s'=0:Whi8*Xlo8, s'=1:Wlo8*Xhi8; tap 0..8 x c0 step 64)
  int c8 = 0, kx8 = 0, tap8 = 0, s8 = 0;
  size_t tapOfs8 = 0;
  auto stage2 = [&](int slot) {
    int aOfs = s8 * 4608 + tap8 * 512 + c8;
    size_t bOfs = (size_t)s8 * XSPLIT + tapOfs8 + (size_t)c8;
    unsigned char* lA = smem + slot * 32768 + wofs;
    unsigned char* lB = smem + slot * 32768 + 16384 + wofs;
    g2lds16(gA80 + aOfs, lA);
    g2lds16(gA81 + aOfs, lA + 8192);
    g2lds16(gB80 + bOfs, lB);
    g2lds16(gB81 + bOfs, lB + 8192);
    c8 += 64;
    if (c8 == 512) {
      c8 = 0; ++tap8;
      if (tap8 == 9) { tap8 = 0; kx8 = 0; tapOfs8 = 0; ++s8; }
      else if (kx8 == 2) { kx8 = 0; tapOfs8 += (size_t)64 * 512; }
      else { ++kx8; tapOfs8 += 512; }
    }
  };

  f32x4 acc[8][4];
  const f32x4 fz = {0.f, 0.f, 0.f, 0.f};
#pragma unroll
  for (int i = 0; i < 8; ++i)
#pragma unroll
    for (int j = 0; j < 4; ++j) acc[i][j] = fz;

  const int kq = (lane >> 4) * 16;
  int slotC, slotS, t2;

  if (m0 < 1024) {
    // =================== HEAVY: 256x256, bf16 s0 + fp8 s1,s2 ===============
    const int rA = wr * 128 + (lane & 15);
    const int rB = wc * 64 + (lane & 15);
    const int kqA = kq ^ (((rA >> 1) & 3) << 4);   // r7 swizzle (0-conflict)
    const int kqB = kq ^ (((rB >> 1) & 3) << 4);

    // ---- phase 1: bf16 s0, 144 ktiles ----
    stage1(0);
    stage1(1);
    asm volatile("s_waitcnt vmcnt(4)" ::: "memory");
    SCHED(); SBAR(); SCHED();
    {
      bf16x8 afA[4], bfA[4], afB[4], bfB[4], af1[4];
#pragma unroll
      for (int mf = 0; mf < 4; ++mf)
        afA[mf] = *(const bf16x8*)(smem + (rA + mf * 16) * 64 + kqA);
#pragma unroll
      for (int nf = 0; nf < 4; ++nf)
        bfA[nf] = *(const bf16x8*)(smem + 16384 + (rB + nf * 16) * 64 + kqB);
      slotC = 0; slotS = 2; t2 = 2;

#define CONV_BF(CURA, CURB, NXTA, NXTB)                                       \
  {                                                                           \
    if (t2 < 144) {                                                           \
      stage1(slotS); slotS = (slotS + 1) & 3;                                 \
      asm volatile("s_waitcnt vmcnt(4)" ::: "memory");                        \
    } else {                                                                  \
      asm volatile("s_waitcnt vmcnt(0)" ::: "memory");                        \
    }                                                                         \
    SCHED(); SBAR(); SCHED();                                                 \
    const unsigned char* lA = smem + slotC * 32768;                           \
    const int slotN = (slotC + 1) & 3;                                        \
    const unsigned char* lAn = smem + slotN * 32768;                          \
    _Pragma("unroll")                                                         \
    for (int mf = 0; mf < 4; ++mf)                                            \
      af1[mf] = *(const bf16x8*)(lA + (rA + 64 + mf * 16) * 64 + kqA);        \
    __builtin_amdgcn_s_setprio(1);                                            \
    _Pragma("unroll")                                                         \
    for (int mf = 0; mf < 4; ++mf) {                                          \
      _Pragma("unroll")                                                       \
      for (int nf = 0; nf < 4; ++nf)                                          \
        acc[mf][nf] = __builtin_amdgcn_mfma_f32_16x16x32_bf16(                \
            CURA[mf], CURB[nf], acc[mf][nf], 0, 0, 0);                        \
    }                                                                         \
    __builtin_amdgcn_s_setprio(0);                                            \
    _Pragma("unroll")                                                         \
    for (int mf = 0; mf < 4; ++mf)                                            \
      NXTA[mf] = *(const bf16x8*)(lAn + (rA + mf * 16) * 64 + kqA);           \
    _Pragma("unroll")                                                         \
    for (int nf = 0; nf < 4; ++nf)                                            \
      NXTB[nf] = *(const bf16x8*)(lAn + 16384 + (rB + nf * 16) * 64 + kqB);   \
    __builtin_amdgcn_s_setprio(1);                                            \
    _Pragma("unroll")                                                         \
    for (int mf = 0; mf < 4; ++mf) {                                          \
      _Pragma("unroll")                                                       \
      for (int nf = 0; nf < 4; ++nf)                                          \
        acc[mf + 4][nf] = __builtin_amdgcn_mfma_f32_16x16x32_bf16(            \
            af1[mf], CURB[nf], acc[mf + 4][nf], 0, 0, 0);                     \
    }                                                                         \
    __builtin_amdgcn_s_setprio(0);                                            \
    slotC = slotN;                                                            \
    ++t2;                                                                     \
  }

      for (int t = 0; t < 144; t += 2) {
        CONV_BF(afA, bfA, afB, bfB)
        CONV_BF(afB, bfB, afA, bfA)
      }
#undef CONV_BF
    }

    // ---- phase 2: fp8 s1+s2, 144 ktiles of K=64 ----
    {
      stage2(0);
      stage2(1);
      asm volatile("s_waitcnt vmcnt(4)" ::: "memory");
      SCHED(); SBAR(); SCHED();
      i64x2 a8A[4], b8A[4], a8B[4], b8B[4], a18[4];
#pragma unroll
      for (int mf = 0; mf < 4; ++mf)
        a8A[mf] = *(const i64x2*)(smem + (rA + mf * 16) * 64 + kqA);
#pragma unroll
      for (int nf = 0; nf < 4; ++nf)
        b8A[nf] = *(const i64x2*)(smem + 16384 + (rB + nf * 16) * 64 + kqB);
      slotC = 0; slotS = 2; t2 = 2;

#define CONV_F8(CURA, CURB, NXTA, NXTB)                                       \
  {                                                                           \
    if (t2 < 144) {                                                           \
      stage2(slotS); slotS = (slotS + 1) & 3;                                 \
      asm volatile("s_waitcnt vmcnt(4)" ::: "memory");                        \
    } else {                                                                  \
      asm volatile("s_waitcnt vmcnt(0)" ::: "memory");                        \
    }                                                                         \
    SCHED(); SBAR(); SCHED();                                                 \
    const unsigned char* lA = smem + slotC * 32768;                           \
    const int slotN = (slotC + 1) & 3;                                        \
    const unsigned char* lAn = smem + slotN * 32768;                          \
    _Pragma("unroll")                                                         \
    for (int mf = 0; mf < 4; ++mf)                                            \
      a18[mf] = *(const i64x2*)(lA + (rA + 64 + mf * 16) * 64 + kqA);         \
    __builtin_amdgcn_s_setprio(1);                                            \
    _Pragma("unroll")                                                         \
    for (int mf = 0; mf < 4; ++mf) {                                          \
      _Pragma("unroll")                                                       \
      for (int nf = 0; nf < 4; ++nf) {                                        \
        acc[mf][nf] = __builtin_amdgcn_mfma_f32_16x16x32_fp8_fp8(             \
            CURA[mf][0], CURB[nf][0], acc[mf][nf], 0, 0, 0);                  \
        acc[mf][nf] = __builtin_amdgcn_mfma_f32_16x16x32_fp8_fp8(             \
            CURA[mf][1], CURB[nf][1], acc[mf][nf], 0, 0, 0);                  \
      }                                                                       \
    }                                                                         \
    __builtin_amdgcn_s_setprio(0);                                            \
    _Pragma("unroll")                                                         \
    for (int mf = 0; mf < 4; ++mf)                                            \
      NXTA[mf] = *(const i64x2*)(lAn + (rA + mf * 16) * 64 + kqA);            \
    _Pragma("unroll")                                                         \
    for (int nf = 0; nf < 4; ++nf)                                            \
      NXTB[nf] = *(const i64x2*)(lAn + 16384 + (rB + nf * 16) * 64 + kqB);    \
    __builtin_amdgcn_s_setprio(1);                                            \
    _Pragma("unroll")                                                         \
    for (int mf = 0; mf < 4; ++mf) {                                          \
      _Pragma("unroll")                                                       \
      for (int nf = 0; nf < 4; ++nf) {                                        \
        acc[mf + 4][nf] = __builtin_amdgcn_mfma_f32_16x16x32_fp8_fp8(         \
            a18[mf][0], CURB[nf][0], acc[mf + 4][nf], 0, 0, 0);               \
        acc[mf + 4][nf] = __builtin_amdgcn_mfma_f32_16x16x32_fp8_fp8(         \
            a18[mf][1], CURB[nf][1], acc[mf + 4][nf], 0, 0, 0);               \
      }                                                                       \
    }                                                                         \
    __builtin_amdgcn_s_setprio(0);                                            \
    slotC = slotN;                                                            \
    ++t2;                                                                     \
  }

      for (int t = 0; t < 144; t += 2) {
        CONV_F8(a8A, b8A, a8B, b8B)
        CONV_F8(a8B, b8B, a8A, b8A)
      }
#undef CONV_F8
    }
  } else {
    // =================== LIGHT v: 128x256, bf16 s0 only ====================
    const int rAv = wr * 64 + (lane & 15);         // rows 0..127
    const int rB = wc * 64 + (lane & 15);
    const int kqA = kq ^ (((rAv >> 1) & 3) << 4);
    const int kqB = kq ^ (((rB >> 1) & 3) << 4);

    stage1v(0);
    stage1v(1);
    asm volatile("s_waitcnt vmcnt(3)" ::: "memory");
    SCHED(); SBAR(); SCHED();
    bf16x8 afA[4], bfA[4], afB[4], bfB[4];
#pragma unroll
    for (int mf = 0; mf < 4; ++mf)
      afA[mf] = *(const bf16x8*)(smem + (rAv + mf * 16) * 64 + kqA);
#pragma unroll
    for (int nf = 0; nf < 4; ++nf)
      bfA[nf] = *(const bf16x8*)(smem + 16384 + (rB + nf * 16) * 64 + kqB);
    slotC = 0; slotS = 2; t2 = 2;

#define CONV_LV(CURA, CURB, NXTA, NXTB)                                       \
  {                                                                           \
    if (t2 < 144) {                                                           \
      stage1v(slotS); slotS = (slotS + 1) & 3;                                \
      asm volatile("s_waitcnt vmcnt(3)" ::: "memory");                        \
    } else {                                                                  \
      asm volatile("s_waitcnt vmcnt(0)" ::: "memory");                        \
    }                                                                         \
    SCHED(); SBAR(); SCHED();                                                 \
    const int slotN = (slotC + 1) & 3;                                        \
    const unsigned char* lAn = smem + slotN * 32768;                          \
    _Pragma("unroll")                                                         \
    for (int mf = 0; mf < 4; ++mf)                                            \
      NXTA[mf] = *(const bf16x8*)(lAn + (rAv + mf * 16) * 64 + kqA);          \
    _Pragma("unroll")                                                         \
    for (int nf = 0; nf < 4; ++nf)                                            \
      NXTB[nf] = *(const bf16x8*)(lAn + 16384 + (rB + nf * 16) * 64 + kqB);   \
    __builtin_amdgcn_s_setprio(1);                                            \
    _Pragma("unroll")                                                         \
    for (int mf = 0; mf < 4; ++mf) {                                          \
      _Pragma("unroll")                                                       \
      for (int nf = 0; nf < 4; ++nf)                                          \
        acc[mf][nf] = __builtin_amdgcn_mfma_f32_16x16x32_bf16(                \
            CURA[mf], CURB[nf], acc[mf][nf], 0, 0, 0);                        \
    }                                                                         \
    __builtin_amdgcn_s_setprio(0);                                            \
    slotC = slotN;                                                            \
    ++t2;                                                                     \
  }

    for (int t = 0; t < 144; t += 2) {
      CONV_LV(afA, bfA, afB, bfB)
      CONV_LV(afB, bfB, afA, bfA)
    }
#undef CONV_LV
  }

  // ---- epilogue: all products at scale 2^14 -> * 2^-14 ----
  constexpr float SC = 1.f / 16384.f;
  if (m0 < 1024) {
#pragma unroll
    for (int mf = 0; mf < 8; ++mf) {
#pragma unroll
      for (int nf = 0; nf < 4; ++nf) {
        f32x4 a = acc[mf][nf];
        int mrow = m0 + wr * 128 + mf * 16 + ((lane >> 4) << 2);
        int ncol = nl0 + wc * 64 + nf * 16 + (lane & 15);
        if (m0 < 512) {
#pragma unroll
          for (int j = 0; j < 4; ++j) {
            float v = a[j] * SC + bias[mrow + j];
            unsigned short h16 = f2bf(v);
            size_t o = ((size_t)bidx * CC + (mrow + j)) * CN + ncol;
            Qhi[o] = h16;
            Qlo[o] = f2bf(v - bf2f(h16));
          }
        } else {
#pragma unroll
          for (int j = 0; j < 4; ++j) {
            float v = a[j] * SC + bias[mrow + j];
            unsigned short h16 = f2bf(v);
            size_t o = ((size_t)bidx * CC + (mrow + j - 512)) * CN + ncol;
            Khi[o] = h16;
            Klo[o] = f2bf(v - bf2f(h16));
          }
        }
      }
    }
  } else {
#pragma unroll
    for (int mf = 0; mf < 4; ++mf) {
#pragma unroll
      for (int nf = 0; nf < 4; ++nf) {
        f32x4 a = acc[mf][nf];
        int mrow = m0 + wr * 64 + mf * 16 + ((lane >> 4) << 2);
        int ncol = nl0 + wc * 64 + nf * 16 + (lane & 15);
        u16x4 vs;                     // V written transposed: Vt[b][n][d]
#pragma unroll
        for (int j = 0; j < 4; ++j) vs[j] = f2bf(a[j] * SC + bias[mrow + j]);
        *(u16x4*)&Vt[((size_t)bidx * CN + ncol) * CC + (mrow - 1024)] = vs;
      }
    }
  }
}

// ---- MFMA GEMM: MODE 1=QK^T (3-phase hi/lo, split-K), 2=PV -----------------
DI int sofs(int row, int kb) { return row * 128 + (kb ^ ((row & 7) << 4)); }

template<int MODE>
__global__ __launch_bounds__(256) void gemm_k(
    const unsigned short* __restrict__ Qhi, const unsigned short* __restrict__ Qlo,
    const unsigned short* __restrict__ Khi, const unsigned short* __restrict__ Klo,
    const unsigned short* __restrict__ Vt,
    float* __restrict__ attn,
    const unsigned short* __restrict__ P,
    const float* __restrict__ xin,
    const float* __restrict__ gamma,
    float* __restrict__ out)
{
  __shared__ __align__(16) unsigned char sA[16384];
  __shared__ __align__(16) unsigned char sB[16384];
  const int tid = threadIdx.x;
  const int lane = tid & 63;
  const int wav = tid >> 6;
  const int wr = wav >> 1, wc = wav & 1;

  int m0, n0, bidx, Kbeg = 0, Kend, ks = 0;
  if constexpr (MODE == 1) {
    int tile = blockIdx.x & 15;
    ks = blockIdx.x >> 4;
    m0 = (tile & 3) * 128;
    n0 = (tile >> 2) * 128;
    bidx = blockIdx.z;
    Kbeg = ks * (3 * CN / KSPL);
    Kend = Kbeg + (3 * CN / KSPL);
  } else {
    m0 = (blockIdx.x & 3) * 128;
    n0 = (blockIdx.x >> 2) * 128;
    bidx = blockIdx.z;
    Kend = CC;
  }

  auto stage = [&](int k0) {
#pragma unroll
    for (int q = 0; q < 4; ++q) {
      int ci = q * 256 + tid;
      int row = ci >> 3;
      int ke = ((ci & 7) ^ (row & 7)) * 8;
      const unsigned short* ap;
      const unsigned short* bp;
      if constexpr (MODE == 1) {
        int ph = k0 >> 12;
        int kin = k0 & (CN - 1);
        const unsigned short* Aq = (ph == 2) ? Qlo : Qhi;
        const unsigned short* Bk = (ph == 1) ? Klo : Khi;
        ap = Aq + ((size_t)bidx * CC + (m0 + row)) * CN + (kin + ke);
        bp = Bk + ((size_t)bidx * CC + (n0 + row)) * CN + (kin + ke);
      } else {
        ap = P + ((size_t)bidx * CC + (m0 + row)) * CC + (k0 + ke);
        bp = Vt + ((size_t)bidx * CN + (n0 + row)) * CC + (k0 + ke);
      }
      int wbase = (q * 256 + wav * 64) * 16;
      g2lds16(ap, sA + wbase);
      g2lds16(bp, sB + wbase);
    }
  };

  f32x4 acc[4][4];
  const f32x4 fz = {0.f, 0.f, 0.f, 0.f};
#pragma unroll
  for (int i = 0; i < 4; ++i)
#pragma unroll
    for (int j = 0; j < 4; ++j) acc[i][j] = fz;

  for (int k0 = Kbeg; k0 < Kend; k0 += 64) {
    stage(k0);
    __syncthreads();
#pragma unroll
    for (int kkp = 0; kkp < 2; ++kkp) {
      bf16x8 af[4], bfv[4];
#pragma unroll
      for (int mf = 0; mf < 4; ++mf)
        af[mf] = *(const bf16x8*)&sA[sofs(wr * 64 + mf * 16 + (lane & 15),
                                          kkp * 64 + (lane >> 4) * 16)];
#pragma unroll
      for (int nf = 0; nf < 4; ++nf)
        bfv[nf] = *(const bf16x8*)&sB[sofs(wc * 64 + nf * 16 + (lane & 15),
                                           kkp * 64 + (lane >> 4) * 16)];
#pragma unroll
      for (int mf = 0; mf < 4; ++mf)
#pragma unroll
        for (int nf = 0; nf < 4; ++nf)
          acc[mf][nf] = __builtin_amdgcn_mfma_f32_16x16x32_bf16(
              af[mf], bfv[nf], acc[mf][nf], 0, 0, 0);
    }
    __syncthreads();
  }

  float g = 0.f;
  if constexpr (MODE == 2) g = gamma[0];
#pragma unroll
  for (int mf = 0; mf < 4; ++mf) {
#pragma unroll
    for (int nf = 0; nf < 4; ++nf) {
      f32x4 a = acc[mf][nf];
      int mrow = m0 + wr * 64 + mf * 16 + ((lane >> 4) << 2);
      int ncol = n0 + wc * 64 + nf * 16 + (lane & 15);
      if constexpr (MODE == 1) {
        size_t pbase = (size_t)ks * ((size_t)BCH * CC * CC);
#pragma unroll
        for (int j = 0; j < 4; ++j)
          attn[pbase + ((size_t)bidx * CC + (mrow + j)) * CC + ncol] = a[j];
      } else {
#pragma unroll
        for (int j = 0; j < 4; ++j) {
          size_t o = ((size_t)bidx * CC + (mrow + j)) * CN + ncol;
          out[o] = g * a[j] + xin[o];
        }
      }
    }
  }
}

// ---- softmax over d (512): sum KSPL split-K partials, one wave per row -----
__global__ __launch_bounds__(256) void softmax_k(const float* __restrict__ attn,
                                                 unsigned short* __restrict__ P) {
  int row = blockIdx.x * 4 + (threadIdx.x >> 6);
  int lane = threadIdx.x & 63;
  constexpr size_t PS = (size_t)BCH * CC * CC;
  const float* rp = attn + (size_t)row * 512 + lane * 8;
  f32x4 a = {0.f, 0.f, 0.f, 0.f};
  f32x4 b = {0.f, 0.f, 0.f, 0.f};
#pragma unroll
  for (int ksp = 0; ksp < KSPL; ++ksp) {
    a += *(const f32x4*)(rp + (size_t)ksp * PS);
    b += *(const f32x4*)(rp + (size_t)ksp * PS + 4);
  }
  float mx = fmaxf(fmaxf(fmaxf(a[0], a[1]), fmaxf(a[2], a[3])),
                   fmaxf(fmaxf(b[0], b[1]), fmaxf(b[2], b[3])));
#pragma unroll
  for (int s = 32; s > 0; s >>= 1) mx = fmaxf(mx, __shfl_xor(mx, s, 64));
  float e[8];
  float sum = 0.f;
#pragma unroll
  for (int j = 0; j < 4; ++j) { e[j] = __expf(a[j] - mx); sum += e[j]; }
#pragma unroll
  for (int j = 0; j < 4; ++j) { e[4 + j] = __expf(b[j] - mx); sum += e[4 + j]; }
#pragma unroll
  for (int s = 32; s > 0; s >>= 1) sum += __shfl_xor(sum, s, 64);
  float inv = 1.0f / sum;
  u16x8 o;
#pragma unroll
  for (int j = 0; j < 8; ++j) o[j] = f2bf(e[j] * inv);
  *(u16x8*)&P[(size_t)row * 512 + lane * 8] = o;
}

// ---- diagnostic: fill out with sentinel if workspace is too small ----------
__global__ __launch_bounds__(256) void fill_sentinel(float* __restrict__ out, int n) {
  int i = blockIdx.x * 256 + threadIdx.x;
  if (i < n) out[i] = 1.0e4f;
}

// ---------------------------------------------------------------------------
extern "C" void kernel_launch(void* const* d_in, const int* in_sizes, int n_in,
                              void* d_out, int out_size, void* d_ws, size_t ws_size,
                              hipStream_t stream) {
  (void)in_sizes; (void)n_in;
  const float* x  = (const float*)d_in[0];
  const float* wq = (const float*)d_in[1];
  const float* bq = (const float*)d_in[2];
  const float* wk = (const float*)d_in[3];
  const float* bk = (const float*)d_in[4];
  const float* wv = (const float*)d_in[5];
  const float* bv = (const float*)d_in[6];
  const float* gm = (const float*)d_in[7];
  float* out = (float*)d_out;

  uint8_t* wsp = (uint8_t*)d_ws;
  auto take = [&](size_t bytes) {
    uint8_t* p = wsp;
    wsp += (bytes + 255) & ~(size_t)255;
    return p;
  };
  unsigned short* Xhi = (unsigned short*)take(XSPLIT * 2);          // 17.8 MB
  unsigned char*  X8  = (unsigned char*)take(2 * XSPLIT);           // 17.8 MB
  unsigned short* Ahi = (unsigned short*)take((size_t)MR * K1 * 2); // 13.5 MB
  unsigned char*  A8  = (unsigned char*)take((size_t)MR * 2 * K1);  // 13.5 MB
  float* bias         = (float*)take((size_t)MR * 4);
  unsigned short* Khi = (unsigned short*)take((size_t)BCH * CC * CN * 2);  // 16.8 MB
  unsigned short* Klo = (unsigned short*)take((size_t)BCH * CC * CN * 2);  // 16.8 MB
  unsigned short* Vt  = (unsigned short*)take((size_t)BCH * CN * CC * 2);  // 16.8 MB
  // attn (16.8MB) + P (2.1MB) alias the Xhi+X8 region (35.7MB, dead after conv)
  float* attn         = (float*)Xhi;
  unsigned short* P   = (unsigned short*)((uint8_t*)Xhi +
                          (size_t)KSPL * BCH * CC * CC * 4 + 256);

  size_t needed = (size_t)(wsp - (uint8_t*)d_ws);   // ~113 MB
  if (ws_size < needed) {
    fill_sentinel<<<(out_size + 255) / 256, 256, 0, stream>>>(out, out_size);
    return;
  }

  for (int ch = 0; ch < CB / BCH; ++ch) {
    const float* xch = x + (size_t)ch * BCH * CC * CN;
    float* outch = out + (size_t)ch * BCH * CC * CN;
    unsigned short* Qhi = (unsigned short*)outch;   // Q pair lives in d_out
    unsigned short* Qlo = Qhi + (size_t)BCH * CC * CN;

    // re-zero Xhi+X8 every chunk (pads + heal attn/P aliasing corruption)
    hipMemsetAsync(Xhi, 0, XSPLIT * 2 + 2 * XSPLIT, stream);
    prep_xpad<<<BCH * 16 * 64, 256, 0, stream>>>(xch, Xhi, X8);
    if (ch == 0)
      prep_abig<<<(MR * K1) / 256, 256, 0, stream>>>(wq, wk, wv, bq, bk, bv,
                                                     Ahi, A8, bias);
    conv_k<<<dim3(512), 512, 0, stream>>>(Ahi, A8, Xhi, X8, bias,
                                          Qhi, Qlo, Khi, Klo, Vt);
    gemm_k<1><<<dim3(16 * KSPL, 1, BCH), 256, 0, stream>>>(Qhi, Qlo, Khi, Klo, Vt,
                                                           attn, P, xch, gm, outch);
    softmax_k<<<BCH * 128, 256, 0, stream>>>(attn, P);
    gemm_k<2><<<dim3(128, 1, BCH), 256, 0, stream>>>(Qhi, Qlo, Khi, Klo, Vt,
                                                     attn, P, xch, gm, outch);
  }
}

// Round 12
// 1007.367 us; speedup vs baseline: 1.7180x; 1.0458x over previous
//
#include <hip/hip_runtime.h>
#include <stdint.h>

typedef __attribute__((ext_vector_type(8))) short bf16x8;
typedef __attribute__((ext_vector_type(4))) float f32x4;
typedef __attribute__((ext_vector_type(4))) int i32x4;
typedef __attribute__((ext_vector_type(8))) int i32x8;
typedef __attribute__((ext_vector_type(8))) unsigned short u16x8;
typedef __attribute__((ext_vector_type(4))) unsigned short u16x4;

#define DI static __device__ __forceinline__

constexpr int CB = 8;          // batch (total)
constexpr int BCH = 4;         // batches per chunk (2 chunks)
constexpr int CC = 512;        // channels
constexpr int CN = 4096;       // H*W
constexpr int K1 = CC * 9;     // 4608
constexpr int MR = 3 * CC;     // 1536 output rows (q|k|v)
constexpr int KSPL = 4;        // QK^T split-K factor
constexpr size_t XSPLIT = (size_t)BCH * 66 * 66 * 512;

DI unsigned short f2bf(float f) {
  union { float f; uint32_t u; } v; v.f = f;
  uint32_t r = (v.u + 0x7FFFu + ((v.u >> 16) & 1u)) >> 16;  // RNE
  return (unsigned short)r;
}
DI float bf2f(unsigned short h) {
  union { uint32_t u; float f; } v; v.u = ((uint32_t)h) << 16;
  return v.f;
}
// manual OCP e4m3fn convert (RNE on mantissa; sat to 448); input |x| << 448 here
DI unsigned char f2e4m3(float x) {
  union { float f; uint32_t u; } v; v.f = x;
  uint32_t sgn = (v.u >> 24) & 0x80u;
  float a = fabsf(x);
  if (a < 0.015625f) {                       // subnormal: quantum 2^-9
    int qi = (int)rintf(a * 512.f);          // 0..8 (8 -> min normal 0x08)
    return (unsigned char)(sgn | (uint32_t)qi);
  }
  int e = (int)((v.u >> 23) & 0xff) - 127;
  uint32_t m3 = (v.u >> 20) & 7u;
  uint32_t rest = v.u & 0xFFFFFu;
  if (rest > 0x80000u || (rest == 0x80000u && (m3 & 1u))) {
    if (++m3 == 8u) { m3 = 0; ++e; }
  }
  if (e > 8 || (e == 8 && m3 == 7u)) return (unsigned char)(sgn | 0x7Eu);
  return (unsigned char)(sgn | ((uint32_t)(e + 7) << 3) | m3);
}

DI void g2lds16(const void* g, void* l) {
  __builtin_amdgcn_global_load_lds((const __attribute__((address_space(1))) void*)g,
                                   (__attribute__((address_space(3))) void*)l, 16, 0, 0);
}
#define SBAR()  __builtin_amdgcn_s_barrier()
#define SCHED() __builtin_amdgcn_sched_barrier(0)

// ---- prep 1: Xhi (bf16, x2^7), X8 split0=Xlo8 (x2^8), split1=Xhi8 (x1) -----
// fp8 now stored PLAIN contiguous (K=128 scaled MFMA wants 32 consecutive
// bytes per lane; the old perm64 pair-interleave is gone).
__global__ __launch_bounds__(256) void prep_xpad(const float* __restrict__ x,
                                                 unsigned short* __restrict__ Xhi,
                                                 unsigned char* __restrict__ X8) {
  int tid = threadIdx.x;
  int w = tid & 63;
  int ccl = tid >> 6;
  int blk = blockIdx.x;               // 4096 = b(4) * ccg(16) * h(64)
  int h = blk & 63;
  int ccg = (blk >> 6) & 15;
  int b = blk >> 10;
  int c0 = (ccg * 4 + ccl) * 8;
  const float* xp = x + ((size_t)b * CC) * CN + h * 64 + w;
  u16x8 hi;
  unsigned long long lo8 = 0, hi8 = 0;
#pragma unroll
  for (int j = 0; j < 8; ++j) {
    float v = xp[(size_t)(c0 + j) * CN];
    unsigned short h16 = f2bf(v);
    float vhi = bf2f(h16);
    hi[j] = f2bf(vhi * 128.f);                    // exact shift
    lo8 |= (unsigned long long)f2e4m3((v - vhi) * 256.f) << (8 * j);
    hi8 |= (unsigned long long)f2e4m3(vhi) << (8 * j);
  }
  size_t pix = (((size_t)b * 66 + (h + 1)) * 66 + (w + 1)) * 512;
  *(u16x8*)&Xhi[pix + c0] = hi;
  *(unsigned long long*)&X8[pix + c0] = lo8;
  *(unsigned long long*)&X8[XSPLIT + pix + c0] = hi8;
}

// ---- prep 2: Ahi [1536][4608] bf16 (x2^7), A8 [1536][9216] fp8 plain -------
__global__ __launch_bounds__(256) void prep_abig(
    const float* __restrict__ wq, const float* __restrict__ wk,
    const float* __restrict__ wv, const float* __restrict__ bq,
    const float* __restrict__ bk, const float* __restrict__ bv,
    unsigned short* __restrict__ Ahi, unsigned char* __restrict__ A8,
    float* __restrict__ bias) {
  unsigned id = blockIdx.x * 256 + threadIdx.x;   // total 1536*4608
  int m = id / K1;
  int r = id - m * K1;
  int t = r >> 9;
  int c = r & 511;
  int ky = t / 3;
  int kx = t - ky * 3;
  size_t ip = (size_t)m * 9216 + r;
  if (m < 1024) {
    const float* wp = (m < 512) ? wq : wk;
    int mm = (m < 512) ? m : m - 512;
    float wval = wp[(((size_t)mm * 512 + c) * 3 + ky) * 3 + kx];
    float whi = bf2f(f2bf(wval));
    Ahi[id] = f2bf(whi * 128.f);
    A8[ip] = f2e4m3(whi * 64.f);
    A8[ip + 4608] = f2e4m3((wval - whi) * 16384.f);
  } else {
    float wval = wv[(((size_t)(m - 1024) * 512 + c) * 3 + ky) * 3 + kx];
    Ahi[id] = f2bf(wval * 128.f);
    A8[ip] = 0;
    A8[ip + 4608] = 0;
  }
  if (id < 1536) {
    int mm = (int)id;
    bias[mm] = (mm < 512) ? bq[mm] : (mm < 1024) ? bk[mm - 512] : bv[mm - 1024];
  }
}

// ---- conv GEMM: 4-slot ring, bf16 phase1 + MX-scaled fp8 K=128 phase2 ------
// ROUND-12: phase 2 uses mfma_scale_f32_16x16x128_f8f6f4 (scales=0x7F -> x1.0,
// fmt 0 = e4m3): same C/D layout as 16x16x32 (shape-determined) -> shares acc
// and epilogue with phase 1. K=128 spans a SLOT PAIR (2x staged K64): lane l,
// group g=l>>4: slot g>>1, row bytes (g&1)*32..+31 via two b128 with the
// existing chunk-XOR swizzle (per-8-lane-phase audit: conflict-free).
// Pair-body: bar; vmcnt(8)->pair p landed; reads+32 MFMA; bar; stage pair p+2
// (into the just-read buffer -- safe: all reads barrier-complete).
__global__ __launch_bounds__(512, 2) void conv_k(
    const unsigned short* __restrict__ Ahi,
    const unsigned char* __restrict__ A8,
    const unsigned short* __restrict__ Xhi,
    const unsigned char* __restrict__ X8,
    const float* __restrict__ bias,
    unsigned short* __restrict__ Qhi, unsigned short* __restrict__ Qlo,
    unsigned short* __restrict__ Khi, unsigned short* __restrict__ Klo,
    unsigned short* __restrict__ Vt)
{
  __shared__ __align__(16) unsigned char smem[4 * 32768];
  const int tid = threadIdx.x;
  const int lane = tid & 63;
  const int wid = tid >> 6;
  const int wr = wid >> 2;            // 0..1 (M)
  const int wc = wid & 3;             // 0..3 (N)

  // XCD-local mapping: xcd = id&7 owns nb panels [8x, 8x+8) for heavy+light.
  int orig = blockIdx.x;
  int xcd, nbl, m0;
  if (orig < 256) {                   // heavy q/k: 256x256
    xcd = orig & 7; int j = orig >> 3;
    nbl = j >> 2;
    m0 = (j & 3) * 256;               // 0..768
  } else {                            // light v: 128x256
    int o = orig - 256;
    xcd = o & 7; int j = o >> 3;      // 0..31
    nbl = j >> 2;
    m0 = 1024 + (j & 3) * 128;        // 1024..1408
  }
  const int nb = xcd * 8 + nbl;
  const int n0 = nb * 256;
  const int bidx = n0 >> 12;
  const int nl0 = n0 & (CN - 1);
  const int h0 = nl0 >> 6;

  // per-thread staging bases; source chunk pre-swizzled by f(srow)
  const int srow = tid >> 2;          // 0..127
  const int scu = tid & 3;
  const int scuS = scu ^ ((srow >> 1) & 3);
  const size_t pixOfs = (((size_t)(bidx * 66 + h0 + (srow >> 6))) * 66 + (srow & 63)) * 512;
  const unsigned short* gAh0 = Ahi + (size_t)(m0 + srow) * K1 + scuS * 8;
  const unsigned short* gAh1 = gAh0 + (size_t)128 * K1;
  const unsigned short* gBh0 = Xhi + pixOfs + scuS * 8;
  const unsigned short* gBh1 = gBh0 + (size_t)2 * 66 * 512;
  const unsigned char* gA80 = A8 + (size_t)(m0 + srow) * 9216 + scuS * 16;
  const unsigned char* gA81 = gA80 + (size_t)128 * 9216;
  const unsigned char* gB80 = X8 + pixOfs + scuS * 16;
  const unsigned char* gB81 = gB80 + (size_t)2 * 66 * 512;
  const int wofs = wid * 1024;

  // phase-1 cursor (s0: tap 0..8 x c0 step 32 -> 144 ktiles)
  int c0S = 0, kxS = 0, tapS = 0;
  size_t tapOfs = 0;
  auto stage1 = [&](int slot) {       // heavy: 4 loads
    int aOfs = tapS * 512 + c0S;
    size_t bOfs = tapOfs + (size_t)c0S;
    unsigned char* lA = smem + slot * 32768 + wofs;
    unsigned char* lB = smem + slot * 32768 + 16384 + wofs;
    g2lds16(gAh0 + aOfs, lA);
    g2lds16(gAh1 + aOfs, lA + 8192);
    g2lds16(gBh0 + bOfs, lB);
    g2lds16(gBh1 + bOfs, lB + 8192);
    c0S += 32;
    if (c0S == 512) {
      c0S = 0; ++tapS;
      if (kxS == 2) { kxS = 0; tapOfs += (size_t)64 * 512; }
      else { ++kxS; tapOfs += 512; }
    }
  };
  auto stage1v = [&](int slot) {      // light: 3 loads (A is 128 rows)
    int aOfs = tapS * 512 + c0S;
    size_t bOfs = tapOfs + (size_t)c0S;
    unsigned char* lA = smem + slot * 32768 + wofs;
    unsigned char* lB = smem + slot * 32768 + 16384 + wofs;
    g2lds16(gAh0 + aOfs, lA);
    g2lds16(gBh0 + bOfs, lB);
    g2lds16(gBh1 + bOfs, lB + 8192);
    c0S += 32;
    if (c0S == 512) {
      c0S = 0; ++tapS;
      if (kxS == 2) { kxS = 0; tapOfs += (size_t)64 * 512; }
      else { ++kxS; tapOfs += 512; }
    }
  };
  // phase-2 cursor (s'=0:Whi8*Xlo8, s'=1:Wlo8*Xhi8; tap 0..8 x c0 step 64)
  int c8 = 0, kx8 = 0, tap8 = 0, s8 = 0;
  size_t tapOfs8 = 0;
  auto stage2 = [&](int slot) {
    int aOfs = s8 * 4608 + tap8 * 512 + c8;
    size_t bOfs = (size_t)s8 * XSPLIT + tapOfs8 + (size_t)c8;
    unsigned char* lA = smem + slot * 32768 + wofs;
    unsigned char* lB = smem + slot * 32768 + 16384 + wofs;
    g2lds16(gA80 + aOfs, lA);
    g2lds16(gA81 + aOfs, lA + 8192);
    g2lds16(gB80 + bOfs, lB);
    g2lds16(gB81 + bOfs, lB + 8192);
    c8 += 64;
    if (c8 == 512) {
      c8 = 0; ++tap8;
      if (tap8 == 9) { tap8 = 0; kx8 = 0; tapOfs8 = 0; ++s8; }
      else if (kx8 == 2) { kx8 = 0; tapOfs8 += (size_t)64 * 512; }
      else { ++kx8; tapOfs8 += 512; }
    }
  };

  f32x4 acc[8][4];
  const f32x4 fz = {0.f, 0.f, 0.f, 0.f};
#pragma unroll
  for (int i = 0; i < 8; ++i)
#pragma unroll
    for (int j = 0; j < 4; ++j) acc[i][j] = fz;

  const int kq = (lane >> 4) * 16;
  int slotC, slotS, t2;

  if (m0 < 1024) {
    // =================== HEAVY: 256x256, bf16 s0 + scaled-fp8 s1,s2 ========
    const int rA = wr * 128 + (lane & 15);
    const int rB = wc * 64 + (lane & 15);
    const int kqA = kq ^ (((rA >> 1) & 3) << 4);   // r7 swizzle (0-conflict)
    const int kqB = kq ^ (((rB >> 1) & 3) << 4);

    // ---- phase 1: bf16 s0, 144 ktiles (unchanged from r10/r11) ----
    stage1(0);
    stage1(1);
    asm volatile("s_waitcnt vmcnt(4)" ::: "memory");
    SCHED(); SBAR(); SCHED();
    {
      bf16x8 afA[4], bfA[4], afB[4], bfB[4], af1[4];
#pragma unroll
      for (int mf = 0; mf < 4; ++mf)
        afA[mf] = *(const bf16x8*)(smem + (rA + mf * 16) * 64 + kqA);
#pragma unroll
      for (int nf = 0; nf < 4; ++nf)
        bfA[nf] = *(const bf16x8*)(smem + 16384 + (rB + nf * 16) * 64 + kqB);
      slotC = 0; slotS = 2; t2 = 2;

#define CONV_BF(CURA, CURB, NXTA, NXTB)                                       \
  {                                                                           \
    if (t2 < 144) {                                                           \
      stage1(slotS); slotS = (slotS + 1) & 3;                                 \
      asm volatile("s_waitcnt vmcnt(4)" ::: "memory");                        \
    } else {                                                                  \
      asm volatile("s_waitcnt vmcnt(0)" ::: "memory");                        \
    }                                                                         \
    SCHED(); SBAR(); SCHED();                                                 \
    const unsigned char* lA = smem + slotC * 32768;                           \
    const int slotN = (slotC + 1) & 3;                                        \
    const unsigned char* lAn = smem + slotN * 32768;                          \
    _Pragma("unroll")                                                         \
    for (int mf = 0; mf < 4; ++mf)                                            \
      af1[mf] = *(const bf16x8*)(lA + (rA + 64 + mf * 16) * 64 + kqA);        \
    __builtin_amdgcn_s_setprio(1);                                            \
    _Pragma("unroll")                                                         \
    for (int mf = 0; mf < 4; ++mf) {                                          \
      _Pragma("unroll")                                                       \
      for (int nf = 0; nf < 4; ++nf)                                          \
        acc[mf][nf] = __builtin_amdgcn_mfma_f32_16x16x32_bf16(                \
            CURA[mf], CURB[nf], acc[mf][nf], 0, 0, 0);                        \
    }                                                                         \
    __builtin_amdgcn_s_setprio(0);                                            \
    _Pragma("unroll")                                                         \
    for (int mf = 0; mf < 4; ++mf)                                            \
      NXTA[mf] = *(const bf16x8*)(lAn + (rA + mf * 16) * 64 + kqA);           \
    _Pragma("unroll")                                                         \
    for (int nf = 0; nf < 4; ++nf)                                            \
      NXTB[nf] = *(const bf16x8*)(lAn + 16384 + (rB + nf * 16) * 64 + kqB);   \
    __builtin_amdgcn_s_setprio(1);                                            \
    _Pragma("unroll")                                                         \
    for (int mf = 0; mf < 4; ++mf) {                                          \
      _Pragma("unroll")                                                       \
      for (int nf = 0; nf < 4; ++nf)                                          \
        acc[mf + 4][nf] = __builtin_amdgcn_mfma_f32_16x16x32_bf16(            \
            af1[mf], CURB[nf], acc[mf + 4][nf], 0, 0, 0);                     \
    }                                                                         \
    __builtin_amdgcn_s_setprio(0);                                            \
    slotC = slotN;                                                            \
    ++t2;                                                                     \
  }

      for (int t = 0; t < 144; t += 2) {
        CONV_BF(afA, bfA, afB, bfB)
        CONV_BF(afB, bfB, afA, bfA)
      }
#undef CONV_BF
    }

    // ---- phase 2': scaled fp8, 72 pair-bodies of K=128 ----
    stage2(0); stage2(1);
    SCHED(); SBAR(); SCHED();          // phase-1 final slot-2/3 reads complete
    stage2(2); stage2(3);
    {
      const int gq = lane >> 4;                  // 0..3: k-range (gq)*32
      const int slotByte = (gq >> 1) << 15;      // lo/hi slot of the pair
      const int cb2 = (gq & 1) * 2;              // 16B chunk base in 64B row
      const int ff2 = ((lane & 15) >> 1) & 3;    // r7 swizzle f(row)
      const int bo0 = ((cb2 ^ ff2) << 4);
      const int bo1 = (((cb2 + 1) ^ ff2) << 4);
      const int aRow = wr * 128 + (lane & 15);
      const int bRow = wc * 64 + (lane & 15);
      i32x8 aF[4], bF[4];
      for (int p = 0; p < 72; ++p) {
        SCHED(); SBAR(); SCHED();
        if (p < 71) { asm volatile("s_waitcnt vmcnt(8)" ::: "memory"); }
        else        { asm volatile("s_waitcnt vmcnt(0)" ::: "memory"); }
        SCHED();
        const unsigned char* pbA = smem + ((p & 1) << 16) + slotByte + aRow * 64;
        const unsigned char* pbB = smem + ((p & 1) << 16) + slotByte + 16384 + bRow * 64;
#pragma unroll
        for (int t = 0; t < 4; ++t) {
          *(i32x4*)&bF[t] = *(const i32x4*)(pbB + t * 1024 + bo0);
          *((i32x4*)&bF[t] + 1) = *(const i32x4*)(pbB + t * 1024 + bo1);
        }
#pragma unroll
        for (int s = 0; s < 4; ++s) {
          *(i32x4*)&aF[s] = *(const i32x4*)(pbA + s * 1024 + bo0);
          *((i32x4*)&aF[s] + 1) = *(const i32x4*)(pbA + s * 1024 + bo1);
        }
        __builtin_amdgcn_s_setprio(1);
#pragma unroll
        for (int s = 0; s < 4; ++s)
#pragma unroll
          for (int t = 0; t < 4; ++t)
            acc[s][t] = __builtin_amdgcn_mfma_scale_f32_16x16x128_f8f6f4(
                aF[s], bF[t], acc[s][t], 0, 0, 0, 127, 0, 127);
        __builtin_amdgcn_s_setprio(0);
#pragma unroll
        for (int s = 0; s < 4; ++s) {
          *(i32x4*)&aF[s] = *(const i32x4*)(pbA + (4 + s) * 1024 + bo0);
          *((i32x4*)&aF[s] + 1) = *(const i32x4*)(pbA + (4 + s) * 1024 + bo1);
        }
        __builtin_amdgcn_s_setprio(1);
#pragma unroll
        for (int s = 0; s < 4; ++s)
#pragma unroll
          for (int t = 0; t < 4; ++t)
            acc[s + 4][t] = __builtin_amdgcn_mfma_scale_f32_16x16x128_f8f6f4(
                aF[s], bF[t], acc[s + 4][t], 0, 0, 0, 127, 0, 127);
        __builtin_amdgcn_s_setprio(0);
        SCHED(); SBAR(); SCHED();
        if (p + 2 < 72) { stage2(2 * (p & 1)); stage2(2 * (p & 1) + 1); }
      }
    }
  } else {
    // =================== LIGHT v: 128x256, bf16 s0 only (unchanged) ========
    const int rAv = wr * 64 + (lane & 15);         // rows 0..127
    const int rB = wc * 64 + (lane & 15);
    const int kqA = kq ^ (((rAv >> 1) & 3) << 4);
    const int kqB = kq ^ (((rB >> 1) & 3) << 4);

    stage1v(0);
    stage1v(1);
    asm volatile("s_waitcnt vmcnt(3)" ::: "memory");
    SCHED(); SBAR(); SCHED();
    bf16x8 afA[4], bfA[4], afB[4], bfB[4];
#pragma unroll
    for (int mf = 0; mf < 4; ++mf)
      afA[mf] = *(const bf16x8*)(smem + (rAv + mf * 16) * 64 + kqA);
#pragma unroll
    for (int nf = 0; nf < 4; ++nf)
      bfA[nf] = *(const bf16x8*)(smem + 16384 + (rB + nf * 16) * 64 + kqB);
    slotC = 0; slotS = 2; t2 = 2;

#define CONV_LV(CURA, CURB, NXTA, NXTB)                                       \
  {                                                                           \
    if (t2 < 144) {                                                           \
      stage1v(slotS); slotS = (slotS + 1) & 3;                                \
      asm volatile("s_waitcnt vmcnt(3)" ::: "memory");                        \
    } else {                                                                  \
      asm volatile("s_waitcnt vmcnt(0)" ::: "memory");                        \
    }                                                                         \
    SCHED(); SBAR(); SCHED();                                                 \
    const int slotN = (slotC + 1) & 3;                                        \
    const unsigned char* lAn = smem + slotN * 32768;                          \
    _Pragma("unroll")                                                         \
    for (int mf = 0; mf < 4; ++mf)                                            \
      NXTA[mf] = *(const bf16x8*)(lAn + (rAv + mf * 16) * 64 + kqA);          \
    _Pragma("unroll")                                                         \
    for (int nf = 0; nf < 4; ++nf)                                            \
      NXTB[nf] = *(const bf16x8*)(lAn + 16384 + (rB + nf * 16) * 64 + kqB);   \
    __builtin_amdgcn_s_setprio(1);                                            \
    _Pragma("unroll")                                                         \
    for (int mf = 0; mf < 4; ++mf) {                                          \
      _Pragma("unroll")                                                       \
      for (int nf = 0; nf < 4; ++nf)                                          \
        acc[mf][nf] = __builtin_amdgcn_mfma_f32_16x16x32_bf16(                \
            CURA[mf], CURB[nf], acc[mf][nf], 0, 0, 0);                        \
    }                                                                         \
    __builtin_amdgcn_s_setprio(0);                                            \
    slotC = slotN;                                                            \
    ++t2;                                                                     \
  }

    for (int t = 0; t < 144; t += 2) {
      CONV_LV(afA, bfA, afB, bfB)
      CONV_LV(afB, bfB, afA, bfA)
    }
#undef CONV_LV
  }

  // ---- epilogue: all products at scale 2^14 -> * 2^-14 ----
  constexpr float SC = 1.f / 16384.f;
  if (m0 < 1024) {
#pragma unroll
    for (int mf = 0; mf < 8; ++mf) {
#pragma unroll
      for (int nf = 0; nf < 4; ++nf) {
        f32x4 a = acc[mf][nf];
        int mrow = m0 + wr * 128 + mf * 16 + ((lane >> 4) << 2);
        int ncol = nl0 + wc * 64 + nf * 16 + (lane & 15);
        if (m0 < 512) {
#pragma unroll
          for (int j = 0; j < 4; ++j) {
            float v = a[j] * SC + bias[mrow + j];
            unsigned short h16 = f2bf(v);
            size_t o = ((size_t)bidx * CC + (mrow + j)) * CN + ncol;
            Qhi[o] = h16;
            Qlo[o] = f2bf(v - bf2f(h16));
          }
        } else {
#pragma unroll
          for (int j = 0; j < 4; ++j) {
            float v = a[j] * SC + bias[mrow + j];
            unsigned short h16 = f2bf(v);
            size_t o = ((size_t)bidx * CC + (mrow + j - 512)) * CN + ncol;
            Khi[o] = h16;
            Klo[o] = f2bf(v - bf2f(h16));
          }
        }
      }
    }
  } else {
#pragma unroll
    for (int mf = 0; mf < 4; ++mf) {
#pragma unroll
      for (int nf = 0; nf < 4; ++nf) {
        f32x4 a = acc[mf][nf];
        int mrow = m0 + wr * 64 + mf * 16 + ((lane >> 4) << 2);
        int ncol = nl0 + wc * 64 + nf * 16 + (lane & 15);
        u16x4 vs;                     // V written transposed: Vt[b][n][d]
#pragma unroll
        for (int j = 0; j < 4; ++j) vs[j] = f2bf(a[j] * SC + bias[mrow + j]);
        *(u16x4*)&Vt[((size_t)bidx * CN + ncol) * CC + (mrow - 1024)] = vs;
      }
    }
  }
}

// ---- MFMA GEMM: MODE 1=QK^T (3-phase hi/lo, split-K), 2=PV -----------------
DI int sofs(int row, int kb) { return row * 128 + (kb ^ ((row & 7) << 4)); }

template<int MODE>
__global__ __launch_bounds__(256) void gemm_k(
    const unsigned short* __restrict__ Qhi, const unsigned short* __restrict__ Qlo,
    const unsigned short* __restrict__ Khi, const unsigned short* __restrict__ Klo,
    const unsigned short* __restrict__ Vt,
    float* __restrict__ attn,
    const unsigned short* __restrict__ P,
    const float* __restrict__ xin,
    const float* __restrict__ gamma,
    float* __restrict__ out)
{
  __shared__ __align__(16) unsigned char sA[16384];
  __shared__ __align__(16) unsigned char sB[16384];
  const int tid = threadIdx.x;
  const int lane = tid & 63;
  const int wav = tid >> 6;
  const int wr = wav >> 1, wc = wav & 1;

  int m0, n0, bidx, Kbeg = 0, Kend, ks = 0;
  if constexpr (MODE == 1) {
    int tile = blockIdx.x & 15;
    ks = blockIdx.x >> 4;
    m0 = (tile & 3) * 128;
    n0 = (tile >> 2) * 128;
    bidx = blockIdx.z;
    Kbeg = ks * (3 * CN / KSPL);
    Kend = Kbeg + (3 * CN / KSPL);
  } else {
    m0 = (blockIdx.x & 3) * 128;
    n0 = (blockIdx.x >> 2) * 128;
    bidx = blockIdx.z;
    Kend = CC;
  }

  auto stage = [&](int k0) {
#pragma unroll
    for (int q = 0; q < 4; ++q) {
      int ci = q * 256 + tid;
      int row = ci >> 3;
      int ke = ((ci & 7) ^ (row & 7)) * 8;
      const unsigned short* ap;
      const unsigned short* bp;
      if constexpr (MODE == 1) {
        int ph = k0 >> 12;
        int kin = k0 & (CN - 1);
        const unsigned short* Aq = (ph == 2) ? Qlo : Qhi;
        const unsigned short* Bk = (ph == 1) ? Klo : Khi;
        ap = Aq + ((size_t)bidx * CC + (m0 + row)) * CN + (kin + ke);
        bp = Bk + ((size_t)bidx * CC + (n0 + row)) * CN + (kin + ke);
      } else {
        ap = P + ((size_t)bidx * CC + (m0 + row)) * CC + (k0 + ke);
        bp = Vt + ((size_t)bidx * CN + (n0 + row)) * CC + (k0 + ke);
      }
      int wbase = (q * 256 + wav * 64) * 16;
      g2lds16(ap, sA + wbase);
      g2lds16(bp, sB + wbase);
    }
  };

  f32x4 acc[4][4];
  const f32x4 fz = {0.f, 0.f, 0.f, 0.f};
#pragma unroll
  for (int i = 0; i < 4; ++i)
#pragma unroll
    for (int j = 0; j < 4; ++j) acc[i][j] = fz;

  for (int k0 = Kbeg; k0 < Kend; k0 += 64) {
    stage(k0);
    __syncthreads();
#pragma unroll
    for (int kkp = 0; kkp < 2; ++kkp) {
      bf16x8 af[4], bfv[4];
#pragma unroll
      for (int mf = 0; mf < 4; ++mf)
        af[mf] = *(const bf16x8*)&sA[sofs(wr * 64 + mf * 16 + (lane & 15),
                                          kkp * 64 + (lane >> 4) * 16)];
#pragma unroll
      for (int nf = 0; nf < 4; ++nf)
        bfv[nf] = *(const bf16x8*)&sB[sofs(wc * 64 + nf * 16 + (lane & 15),
                                           kkp * 64 + (lane >> 4) * 16)];
#pragma unroll
      for (int mf = 0; mf < 4; ++mf)
#pragma unroll
        for (int nf = 0; nf < 4; ++nf)
          acc[mf][nf] = __builtin_amdgcn_mfma_f32_16x16x32_bf16(
              af[mf], bfv[nf], acc[mf][nf], 0, 0, 0);
    }
    __syncthreads();
  }

  float g = 0.f;
  if constexpr (MODE == 2) g = gamma[0];
#pragma unroll
  for (int mf = 0; mf < 4; ++mf) {
#pragma unroll
    for (int nf = 0; nf < 4; ++nf) {
      f32x4 a = acc[mf][nf];
      int mrow = m0 + wr * 64 + mf * 16 + ((lane >> 4) << 2);
      int ncol = n0 + wc * 64 + nf * 16 + (lane & 15);
      if constexpr (MODE == 1) {
        size_t pbase = (size_t)ks * ((size_t)BCH * CC * CC);
#pragma unroll
        for (int j = 0; j < 4; ++j)
          attn[pbase + ((size_t)bidx * CC + (mrow + j)) * CC + ncol] = a[j];
      } else {
#pragma unroll
        for (int j = 0; j < 4; ++j) {
          size_t o = ((size_t)bidx * CC + (mrow + j)) * CN + ncol;
          out[o] = g * a[j] + xin[o];
        }
      }
    }
  }
}

// ---- softmax over d (512): sum KSPL split-K partials, one wave per row -----
__global__ __launch_bounds__(256) void softmax_k(const float* __restrict__ attn,
                                                 unsigned short* __restrict__ P) {
  int row = blockIdx.x * 4 + (threadIdx.x >> 6);
  int lane = threadIdx.x & 63;
  constexpr size_t PS = (size_t)BCH * CC * CC;
  const float* rp = attn + (size_t)row * 512 + lane * 8;
  f32x4 a = {0.f, 0.f, 0.f, 0.f};
  f32x4 b = {0.f, 0.f, 0.f, 0.f};
#pragma unroll
  for (int ksp = 0; ksp < KSPL; ++ksp) {
    a += *(const f32x4*)(rp + (size_t)ksp * PS);
    b += *(const f32x4*)(rp + (size_t)ksp * PS + 4);
  }
  float mx = fmaxf(fmaxf(fmaxf(a[0], a[1]), fmaxf(a[2], a[3])),
                   fmaxf(fmaxf(b[0], b[1]), fmaxf(b[2], b[3])));
#pragma unroll
  for (int s = 32; s > 0; s >>= 1) mx = fmaxf(mx, __shfl_xor(mx, s, 64));
  float e[8];
  float sum = 0.f;
#pragma unroll
  for (int j = 0; j < 4; ++j) { e[j] = __expf(a[j] - mx); sum += e[j]; }
#pragma unroll
  for (int j = 0; j < 4; ++j) { e[4 + j] = __expf(b[j] - mx); sum += e[4 + j]; }
#pragma unroll
  for (int s = 32; s > 0; s >>= 1) sum += __shfl_xor(sum, s, 64);
  float inv = 1.0f / sum;
  u16x8 o;
#pragma unroll
  for (int j = 0; j < 8; ++j) o[j] = f2bf(e[j] * inv);
  *(u16x8*)&P[(size_t)row * 512 + lane * 8] = o;
}

// ---- diagnostic: fill out with sentinel if workspace is too small ----------
__global__ __launch_bounds__(256) void fill_sentinel(float* __restrict__ out, int n) {
  int i = blockIdx.x * 256 + threadIdx.x;
  if (i < n) out[i] = 1.0e4f;
}

// ---------------------------------------------------------------------------
extern "C" void kernel_launch(void* const* d_in, const int* in_sizes, int n_in,
                              void* d_out, int out_size, void* d_ws, size_t ws_size,
                              hipStream_t stream) {
  (void)in_sizes; (void)n_in;
  const float* x  = (const float*)d_in[0];
  const float* wq = (const float*)d_in[1];
  const float* bq = (const float*)d_in[2];
  const float* wk = (const float*)d_in[3];
  const float* bk = (const float*)d_in[4];
  const float* wv = (const float*)d_in[5];
  const float* bv = (const float*)d_in[6];
  const float* gm = (const float*)d_in[7];
  float* out = (float*)d_out;

  uint8_t* wsp = (uint8_t*)d_ws;
  auto take = [&](size_t bytes) {
    uint8_t* p = wsp;
    wsp += (bytes + 255) & ~(size_t)255;
    return p;
  };
  unsigned short* Xhi = (unsigned short*)take(XSPLIT * 2);          // 17.8 MB
  unsigned char*  X8  = (unsigned char*)take(2 * XSPLIT);           // 17.8 MB
  unsigned short* Ahi = (unsigned short*)take((size_t)MR * K1 * 2); // 13.5 MB
  unsigned char*  A8  = (unsigned char*)take((size_t)MR * 2 * K1);  // 13.5 MB
  float* bias         = (float*)take((size_t)MR * 4);
  unsigned short* Khi = (unsigned short*)take((size_t)BCH * CC * CN * 2);  // 16.8 MB
  unsigned short* Klo = (unsigned short*)take((size_t)BCH * CC * CN * 2);  // 16.8 MB
  unsigned short* Vt  = (unsigned short*)take((size_t)BCH * CN * CC * 2);  // 16.8 MB
  // attn (16.8MB) + P (2.1MB) alias the Xhi+X8 region (35.7MB, dead after conv)
  float* attn         = (float*)Xhi;
  unsigned short* P   = (unsigned short*)((uint8_t*)Xhi +
                          (size_t)KSPL * BCH * CC * CC * 4 + 256);

  size_t needed = (size_t)(wsp - (uint8_t*)d_ws);   // ~113 MB
  if (ws_size < needed) {
    fill_sentinel<<<(out_size + 255) / 256, 256, 0, stream>>>(out, out_size);
    return;
  }

  for (int ch = 0; ch < CB / BCH; ++ch) {
    const float* xch = x + (size_t)ch * BCH * CC * CN;
    float* outch = out + (size_t)ch * BCH * CC * CN;
    unsigned short* Qhi = (unsigned short*)outch;   // Q pair lives in d_out
    unsigned short* Qlo = Qhi + (size_t)BCH * CC * CN;

    // re-zero Xhi+X8 every chunk (pads + heal attn/P aliasing corruption)
    hipMemsetAsync(Xhi, 0, XSPLIT * 2 + 2 * XSPLIT, stream);
    prep_xpad<<<BCH * 16 * 64, 256, 0, stream>>>(xch, Xhi, X8);
    if (ch == 0)
      prep_abig<<<(MR * K1) / 256, 256, 0, stream>>>(wq, wk, wv, bq, bk, bv,
                                                     Ahi, A8, bias);
    conv_k<<<dim3(512), 512, 0, stream>>>(Ahi, A8, Xhi, X8, bias,
                                          Qhi, Qlo, Khi, Klo, Vt);
    gemm_k<1><<<dim3(16 * KSPL, 1, BCH), 256, 0, stream>>>(Qhi, Qlo, Khi, Klo, Vt,
                                                           attn, P, xch, gm, outch);
    softmax_k<<<BCH * 128, 256, 0, stream>>>(attn, P);
    gemm_k<2><<<dim3(128, 1, BCH), 256, 0, stream>>>(Qhi, Qlo, Khi, Klo, Vt,
                                                     attn, P, xch, gm, outch);
  }
}

// Round 13
// 963.242 us; speedup vs baseline: 1.7967x; 1.0458x over previous
//
#include <hip/hip_runtime.h>
#include <stdint.h>

typedef __attribute__((ext_vector_type(8))) short bf16x8;
typedef __attribute__((ext_vector_type(4))) float f32x4;
typedef __attribute__((ext_vector_type(4))) int i32x4;
typedef __attribute__((ext_vector_type(8))) int i32x8;
typedef __attribute__((ext_vector_type(8))) unsigned short u16x8;
typedef __attribute__((ext_vector_type(4))) unsigned short u16x4;

#define DI static __device__ __forceinline__

constexpr int CB = 8;          // batch (total)
constexpr int BCH = 4;         // batches per chunk (2 chunks)
constexpr int CC = 512;        // channels
constexpr int CN = 4096;       // H*W
constexpr int K1 = CC * 9;     // 4608
constexpr int MR = 3 * CC;     // 1536 output rows (q|k|v)
constexpr int KSPL = 8;        // QK^T split-K factor (r13: 4->8, 2 blocks/CU)
constexpr size_t XSPLIT = (size_t)BCH * 66 * 66 * 512;

DI unsigned short f2bf(float f) {
  union { float f; uint32_t u; } v; v.f = f;
  uint32_t r = (v.u + 0x7FFFu + ((v.u >> 16) & 1u)) >> 16;  // RNE
  return (unsigned short)r;
}
DI float bf2f(unsigned short h) {
  union { uint32_t u; float f; } v; v.u = ((uint32_t)h) << 16;
  return v.f;
}
// manual OCP e4m3fn convert (RNE on mantissa; sat to 448); input |x| << 448 here
DI unsigned char f2e4m3(float x) {
  union { float f; uint32_t u; } v; v.f = x;
  uint32_t sgn = (v.u >> 24) & 0x80u;
  float a = fabsf(x);
  if (a < 0.015625f) {                       // subnormal: quantum 2^-9
    int qi = (int)rintf(a * 512.f);          // 0..8 (8 -> min normal 0x08)
    return (unsigned char)(sgn | (uint32_t)qi);
  }
  int e = (int)((v.u >> 23) & 0xff) - 127;
  uint32_t m3 = (v.u >> 20) & 7u;
  uint32_t rest = v.u & 0xFFFFFu;
  if (rest > 0x80000u || (rest == 0x80000u && (m3 & 1u))) {
    if (++m3 == 8u) { m3 = 0; ++e; }
  }
  if (e > 8 || (e == 8 && m3 == 7u)) return (unsigned char)(sgn | 0x7Eu);
  return (unsigned char)(sgn | ((uint32_t)(e + 7) << 3) | m3);
}

DI void g2lds16(const void* g, void* l) {
  __builtin_amdgcn_global_load_lds((const __attribute__((address_space(1))) void*)g,
                                   (__attribute__((address_space(3))) void*)l, 16, 0, 0);
}
#define SBAR()  __builtin_amdgcn_s_barrier()
#define SCHED() __builtin_amdgcn_sched_barrier(0)

// ---- prep 0: zero only the pad border cells (r13: replaces 53MB memset) ----
// Pads are the only cells attn/P aliasing can corrupt that prep_xpad doesn't
// rewrite. 260 border pixels per batch; 16 threads x 32 channels each.
__global__ __launch_bounds__(256) void pad_zero(unsigned short* __restrict__ Xhi,
                                                unsigned char* __restrict__ X8) {
  int id = blockIdx.x * 256 + threadIdx.x;
  if (id >= 4 * 260 * 16) return;
  int t = id & 15;
  int pp = (id >> 4) % 260;
  int b = id / (260 * 16);
  int hh, ww;
  if (pp < 66)       { hh = 0;  ww = pp; }
  else if (pp < 132) { hh = 65; ww = pp - 66; }
  else if (pp < 196) { hh = pp - 131; ww = 0; }
  else               { hh = pp - 195; ww = 65; }
  size_t pix = (((size_t)b * 66 + hh) * 66 + ww) * 512 + (size_t)t * 32;
  const u16x8 z = {0, 0, 0, 0, 0, 0, 0, 0};
  *(u16x8*)&Xhi[pix] = z;  *(u16x8*)&Xhi[pix + 8] = z;
  *(u16x8*)&Xhi[pix + 16] = z;  *(u16x8*)&Xhi[pix + 24] = z;
  const i32x4 z4 = {0, 0, 0, 0};
  *(i32x4*)&X8[pix] = z4;  *(i32x4*)&X8[pix + 16] = z4;
  *(i32x4*)&X8[XSPLIT + pix] = z4;  *(i32x4*)&X8[XSPLIT + pix + 16] = z4;
}

// ---- prep 1: Xhi (bf16, x2^7), X8 split0=Xlo8 (x2^8), split1=Xhi8 (x1) -----
__global__ __launch_bounds__(256) void prep_xpad(const float* __restrict__ x,
                                                 unsigned short* __restrict__ Xhi,
                                                 unsigned char* __restrict__ X8) {
  int tid = threadIdx.x;
  int w = tid & 63;
  int ccl = tid >> 6;
  int blk = blockIdx.x;               // 4096 = b(4) * ccg(16) * h(64)
  int h = blk & 63;
  int ccg = (blk >> 6) & 15;
  int b = blk >> 10;
  int c0 = (ccg * 4 + ccl) * 8;
  const float* xp = x + ((size_t)b * CC) * CN + h * 64 + w;
  u16x8 hi;
  unsigned long long lo8 = 0, hi8 = 0;
#pragma unroll
  for (int j = 0; j < 8; ++j) {
    float v = xp[(size_t)(c0 + j) * CN];
    unsigned short h16 = f2bf(v);
    float vhi = bf2f(h16);
    hi[j] = f2bf(vhi * 128.f);                    // exact shift
    lo8 |= (unsigned long long)f2e4m3((v - vhi) * 256.f) << (8 * j);
    hi8 |= (unsigned long long)f2e4m3(vhi) << (8 * j);
  }
  size_t pix = (((size_t)b * 66 + (h + 1)) * 66 + (w + 1)) * 512;
  *(u16x8*)&Xhi[pix + c0] = hi;
  *(unsigned long long*)&X8[pix + c0] = lo8;
  *(unsigned long long*)&X8[XSPLIT + pix + c0] = hi8;
}

// ---- prep 2: Ahi [1536][4608] bf16 (x2^7), A8 [1536][9216] fp8 plain -------
__global__ __launch_bounds__(256) void prep_abig(
    const float* __restrict__ wq, const float* __restrict__ wk,
    const float* __restrict__ wv, const float* __restrict__ bq,
    const float* __restrict__ bk, const float* __restrict__ bv,
    unsigned short* __restrict__ Ahi, unsigned char* __restrict__ A8,
    float* __restrict__ bias) {
  unsigned id = blockIdx.x * 256 + threadIdx.x;   // total 1536*4608
  int m = id / K1;
  int r = id - m * K1;
  int t = r >> 9;
  int c = r & 511;
  int ky = t / 3;
  int kx = t - ky * 3;
  size_t ip = (size_t)m * 9216 + r;
  if (m < 1024) {
    const float* wp = (m < 512) ? wq : wk;
    int mm = (m < 512) ? m : m - 512;
    float wval = wp[(((size_t)mm * 512 + c) * 3 + ky) * 3 + kx];
    float whi = bf2f(f2bf(wval));
    Ahi[id] = f2bf(whi * 128.f);
    A8[ip] = f2e4m3(whi * 64.f);
    A8[ip + 4608] = f2e4m3((wval - whi) * 16384.f);
  } else {
    float wval = wv[(((size_t)(m - 1024) * 512 + c) * 3 + ky) * 3 + kx];
    Ahi[id] = f2bf(wval * 128.f);
    A8[ip] = 0;
    A8[ip + 4608] = 0;
  }
  if (id < 1536) {
    int mm = (int)id;
    bias[mm] = (mm < 512) ? bq[mm] : (mm < 1024) ? bk[mm - 512] : bv[mm - 1024];
  }
}

// ---- conv GEMM: 4-slot ring, bf16 phase1 + MX-scaled fp8 K=128 phase2 ------
// r13: odd LDS slots stage with chunk-XOR^1 (source byte +-16, per-thread
// const) and phase-2 reads for odd-slot groups apply the same XOR -- each
// row's 4 group-reads now cover 4 DISTINCT bank quads (cross-slot conflict
// candidate from r12's 1.4e7 counter). Bijective both-sides, math unchanged.
__global__ __launch_bounds__(512, 2) void conv_k(
    const unsigned short* __restrict__ Ahi,
    const unsigned char* __restrict__ A8,
    const unsigned short* __restrict__ Xhi,
    const unsigned char* __restrict__ X8,
    const float* __restrict__ bias,
    unsigned short* __restrict__ Qhi, unsigned short* __restrict__ Qlo,
    unsigned short* __restrict__ Khi, unsigned short* __restrict__ Klo,
    unsigned short* __restrict__ Vt)
{
  __shared__ __align__(16) unsigned char smem[4 * 32768];
  const int tid = threadIdx.x;
  const int lane = tid & 63;
  const int wid = tid >> 6;
  const int wr = wid >> 2;            // 0..1 (M)
  const int wc = wid & 3;             // 0..3 (N)

  // XCD-local mapping: xcd = id&7 owns nb panels [8x, 8x+8) for heavy+light.
  int orig = blockIdx.x;
  int xcd, nbl, m0;
  if (orig < 256) {                   // heavy q/k: 256x256
    xcd = orig & 7; int j = orig >> 3;
    nbl = j >> 2;
    m0 = (j & 3) * 256;               // 0..768
  } else {                            // light v: 128x256
    int o = orig - 256;
    xcd = o & 7; int j = o >> 3;      // 0..31
    nbl = j >> 2;
    m0 = 1024 + (j & 3) * 128;        // 1024..1408
  }
  const int nb = xcd * 8 + nbl;
  const int n0 = nb * 256;
  const int bidx = n0 >> 12;
  const int nl0 = n0 & (CN - 1);
  const int h0 = nl0 >> 6;

  // per-thread staging bases; source chunk pre-swizzled by f(srow)
  const int srow = tid >> 2;          // 0..127
  const int scu = tid & 3;
  const int scuS = scu ^ ((srow >> 1) & 3);
  const int d8 = (scuS & 1) ? -16 : 16;   // odd-slot chunk-XOR^1 byte delta
  const size_t pixOfs = (((size_t)(bidx * 66 + h0 + (srow >> 6))) * 66 + (srow & 63)) * 512;
  const unsigned short* gAh0 = Ahi + (size_t)(m0 + srow) * K1 + scuS * 8;
  const unsigned short* gAh1 = gAh0 + (size_t)128 * K1;
  const unsigned short* gBh0 = Xhi + pixOfs + scuS * 8;
  const unsigned short* gBh1 = gBh0 + (size_t)2 * 66 * 512;
  const unsigned char* gA80 = A8 + (size_t)(m0 + srow) * 9216 + scuS * 16;
  const unsigned char* gA81 = gA80 + (size_t)128 * 9216;
  const unsigned char* gB80 = X8 + pixOfs + scuS * 16;
  const unsigned char* gB81 = gB80 + (size_t)2 * 66 * 512;
  const int wofs = wid * 1024;

  // phase-1 cursor (s0: tap 0..8 x c0 step 32 -> 144 ktiles)
  int c0S = 0, kxS = 0, tapS = 0;
  size_t tapOfs = 0;
  auto stage1 = [&](int slot) {       // heavy: 4 loads
    int aOfs = tapS * 512 + c0S;
    size_t bOfs = tapOfs + (size_t)c0S;
    unsigned char* lA = smem + slot * 32768 + wofs;
    unsigned char* lB = smem + slot * 32768 + 16384 + wofs;
    g2lds16(gAh0 + aOfs, lA);
    g2lds16(gAh1 + aOfs, lA + 8192);
    g2lds16(gBh0 + bOfs, lB);
    g2lds16(gBh1 + bOfs, lB + 8192);
    c0S += 32;
    if (c0S == 512) {
      c0S = 0; ++tapS;
      if (kxS == 2) { kxS = 0; tapOfs += (size_t)64 * 512; }
      else { ++kxS; tapOfs += 512; }
    }
  };
  auto stage1v = [&](int slot) {      // light: 3 loads (A is 128 rows)
    int aOfs = tapS * 512 + c0S;
    size_t bOfs = tapOfs + (size_t)c0S;
    unsigned char* lA = smem + slot * 32768 + wofs;
    unsigned char* lB = smem + slot * 32768 + 16384 + wofs;
    g2lds16(gAh0 + aOfs, lA);
    g2lds16(gBh0 + bOfs, lB);
    g2lds16(gBh1 + bOfs, lB + 8192);
    c0S += 32;
    if (c0S == 512) {
      c0S = 0; ++tapS;
      if (kxS == 2) { kxS = 0; tapOfs += (size_t)64 * 512; }
      else { ++kxS; tapOfs += 512; }
    }
  };
  // phase-2 cursor (s'=0:Whi8*Xlo8, s'=1:Wlo8*Xhi8; tap 0..8 x c0 step 64)
  int c8 = 0, kx8 = 0, tap8 = 0, s8 = 0;
  size_t tapOfs8 = 0;
  auto stage2 = [&](int slot) {
    int so = (slot & 1) ? d8 : 0;     // r13 slot-parity source XOR
    int aOfs = s8 * 4608 + tap8 * 512 + c8;
    size_t bOfs = (size_t)s8 * XSPLIT + tapOfs8 + (size_t)c8;
    unsigned char* lA = smem + slot * 32768 + wofs;
    unsigned char* lB = smem + slot * 32768 + 16384 + wofs;
    g2lds16(gA80 + aOfs + so, lA);
    g2lds16(gA81 + aOfs + so, lA + 8192);
    g2lds16(gB80 + bOfs + so, lB);
    g2lds16(gB81 + bOfs + so, lB + 8192);
    c8 += 64;
    if (c8 == 512) {
      c8 = 0; ++tap8;
      if (tap8 == 9) { tap8 = 0; kx8 = 0; tapOfs8 = 0; ++s8; }
      else if (kx8 == 2) { kx8 = 0; tapOfs8 += (size_t)64 * 512; }
      else { ++kx8; tapOfs8 += 512; }
    }
  };

  f32x4 acc[8][4];
  const f32x4 fz = {0.f, 0.f, 0.f, 0.f};
#pragma unroll
  for (int i = 0; i < 8; ++i)
#pragma unroll
    for (int j = 0; j < 4; ++j) acc[i][j] = fz;

  const int kq = (lane >> 4) * 16;
  int slotC, slotS, t2;

  if (m0 < 1024) {
    // =================== HEAVY: 256x256, bf16 s0 + scaled-fp8 s1,s2 ========
    const int rA = wr * 128 + (lane & 15);
    const int rB = wc * 64 + (lane & 15);
    const int kqA = kq ^ (((rA >> 1) & 3) << 4);   // r7 swizzle (0-conflict)
    const int kqB = kq ^ (((rB >> 1) & 3) << 4);

    // ---- phase 1: bf16 s0, 144 ktiles (unchanged from r10/r11) ----
    stage1(0);
    stage1(1);
    asm volatile("s_waitcnt vmcnt(4)" ::: "memory");
    SCHED(); SBAR(); SCHED();
    {
      bf16x8 afA[4], bfA[4], afB[4], bfB[4], af1[4];
#pragma unroll
      for (int mf = 0; mf < 4; ++mf)
        afA[mf] = *(const bf16x8*)(smem + (rA + mf * 16) * 64 + kqA);
#pragma unroll
      for (int nf = 0; nf < 4; ++nf)
        bfA[nf] = *(const bf16x8*)(smem + 16384 + (rB + nf * 16) * 64 + kqB);
      slotC = 0; slotS = 2; t2 = 2;

#define CONV_BF(CURA, CURB, NXTA, NXTB)                                       \
  {                                                                           \
    if (t2 < 144) {                                                           \
      stage1(slotS); slotS = (slotS + 1) & 3;                                 \
      asm volatile("s_waitcnt vmcnt(4)" ::: "memory");                        \
    } else {                                                                  \
      asm volatile("s_waitcnt vmcnt(0)" ::: "memory");                        \
    }                                                                         \
    SCHED(); SBAR(); SCHED();                                                 \
    const unsigned char* lA = smem + slotC * 32768;                           \
    const int slotN = (slotC + 1) & 3;                                        \
    const unsigned char* lAn = smem + slotN * 32768;                          \
    _Pragma("unroll")                                                         \
    for (int mf = 0; mf < 4; ++mf)                                            \
      af1[mf] = *(const bf16x8*)(lA + (rA + 64 + mf * 16) * 64 + kqA);        \
    __builtin_amdgcn_s_setprio(1);                                            \
    _Pragma("unroll")                                                         \
    for (int mf = 0; mf < 4; ++mf) {                                          \
      _Pragma("unroll")                                                       \
      for (int nf = 0; nf < 4; ++nf)                                          \
        acc[mf][nf] = __builtin_amdgcn_mfma_f32_16x16x32_bf16(                \
            CURA[mf], CURB[nf], acc[mf][nf], 0, 0, 0);                        \
    }                                                                         \
    __builtin_amdgcn_s_setprio(0);                                            \
    _Pragma("unroll")                                                         \
    for (int mf = 0; mf < 4; ++mf)                                            \
      NXTA[mf] = *(const bf16x8*)(lAn + (rA + mf * 16) * 64 + kqA);           \
    _Pragma("unroll")                                                         \
    for (int nf = 0; nf < 4; ++nf)                                            \
      NXTB[nf] = *(const bf16x8*)(lAn + 16384 + (rB + nf * 16) * 64 + kqB);   \
    __builtin_amdgcn_s_setprio(1);                                            \
    _Pragma("unroll")                                                         \
    for (int mf = 0; mf < 4; ++mf) {                                          \
      _Pragma("unroll")                                                       \
      for (int nf = 0; nf < 4; ++nf)                                          \
        acc[mf + 4][nf] = __builtin_amdgcn_mfma_f32_16x16x32_bf16(            \
            af1[mf], CURB[nf], acc[mf + 4][nf], 0, 0, 0);                     \
    }                                                                         \
    __builtin_amdgcn_s_setprio(0);                                            \
    slotC = slotN;                                                            \
    ++t2;                                                                     \
  }

      for (int t = 0; t < 144; t += 2) {
        CONV_BF(afA, bfA, afB, bfB)
        CONV_BF(afB, bfB, afA, bfA)
      }
#undef CONV_BF
    }

    // ---- phase 2': scaled fp8, 72 pair-bodies of K=128 ----
    stage2(0); stage2(1);
    SCHED(); SBAR(); SCHED();          // phase-1 final slot-2/3 reads complete
    stage2(2); stage2(3);
    {
      const int gq = lane >> 4;                  // 0..3: k-range (gq)*32
      const int slotByte = (gq >> 1) << 15;      // lo/hi slot of the pair
      const int cb2 = (gq & 1) * 2;              // 16B chunk base in 64B row
      const int fx = (((lane & 15) >> 1) & 3) ^ (gq >> 1);  // r13 parity XOR
      const int bo0 = ((cb2 ^ fx) << 4);
      const int bo1 = (((cb2 + 1) ^ fx) << 4);
      const int aRow = wr * 128 + (lane & 15);
      const int bRow = wc * 64 + (lane & 15);
      i32x8 aF[4], bF[4];
      for (int p = 0; p < 72; ++p) {
        SCHED(); SBAR(); SCHED();
        if (p < 71) { asm volatile("s_waitcnt vmcnt(8)" ::: "memory"); }
        else        { asm volatile("s_waitcnt vmcnt(0)" ::: "memory"); }
        SCHED();
        const unsigned char* pbA = smem + ((p & 1) << 16) + slotByte + aRow * 64;
        const unsigned char* pbB = smem + ((p & 1) << 16) + slotByte + 16384 + bRow * 64;
#pragma unroll
        for (int t = 0; t < 4; ++t) {
          *(i32x4*)&bF[t] = *(const i32x4*)(pbB + t * 1024 + bo0);
          *((i32x4*)&bF[t] + 1) = *(const i32x4*)(pbB + t * 1024 + bo1);
        }
#pragma unroll
        for (int s = 0; s < 4; ++s) {
          *(i32x4*)&aF[s] = *(const i32x4*)(pbA + s * 1024 + bo0);
          *((i32x4*)&aF[s] + 1) = *(const i32x4*)(pbA + s * 1024 + bo1);
        }
        __builtin_amdgcn_s_setprio(1);
#pragma unroll
        for (int s = 0; s < 4; ++s)
#pragma unroll
          for (int t = 0; t < 4; ++t)
            acc[s][t] = __builtin_amdgcn_mfma_scale_f32_16x16x128_f8f6f4(
                aF[s], bF[t], acc[s][t], 0, 0, 0, 127, 0, 127);
        __builtin_amdgcn_s_setprio(0);
#pragma unroll
        for (int s = 0; s < 4; ++s) {
          *(i32x4*)&aF[s] = *(const i32x4*)(pbA + (4 + s) * 1024 + bo0);
          *((i32x4*)&aF[s] + 1) = *(const i32x4*)(pbA + (4 + s) * 1024 + bo1);
        }
        __builtin_amdgcn_s_setprio(1);
#pragma unroll
        for (int s = 0; s < 4; ++s)
#pragma unroll
          for (int t = 0; t < 4; ++t)
            acc[s + 4][t] = __builtin_amdgcn_mfma_scale_f32_16x16x128_f8f6f4(
                aF[s], bF[t], acc[s + 4][t], 0, 0, 0, 127, 0, 127);
        __builtin_amdgcn_s_setprio(0);
        SCHED(); SBAR(); SCHED();
        if (p + 2 < 72) { stage2(2 * (p & 1)); stage2(2 * (p & 1) + 1); }
      }
    }
  } else {
    // =================== LIGHT v: 128x256, bf16 s0 only (unchanged) ========
    const int rAv = wr * 64 + (lane & 15);         // rows 0..127
    const int rB = wc * 64 + (lane & 15);
    const int kqA = kq ^ (((rAv >> 1) & 3) << 4);
    const int kqB = kq ^ (((rB >> 1) & 3) << 4);

    stage1v(0);
    stage1v(1);
    asm volatile("s_waitcnt vmcnt(3)" ::: "memory");
    SCHED(); SBAR(); SCHED();
    bf16x8 afA[4], bfA[4], afB[4], bfB[4];
#pragma unroll
    for (int mf = 0; mf < 4; ++mf)
      afA[mf] = *(const bf16x8*)(smem + (rAv + mf * 16) * 64 + kqA);
#pragma unroll
    for (int nf = 0; nf < 4; ++nf)
      bfA[nf] = *(const bf16x8*)(smem + 16384 + (rB + nf * 16) * 64 + kqB);
    slotC = 0; slotS = 2; t2 = 2;

#define CONV_LV(CURA, CURB, NXTA, NXTB)                                       \
  {                                                                           \
    if (t2 < 144) {                                                           \
      stage1v(slotS); slotS = (slotS + 1) & 3;                                \
      asm volatile("s_waitcnt vmcnt(3)" ::: "memory");                        \
    } else {                                                                  \
      asm volatile("s_waitcnt vmcnt(0)" ::: "memory");                        \
    }                                                                         \
    SCHED(); SBAR(); SCHED();                                                 \
    const int slotN = (slotC + 1) & 3;                                        \
    const unsigned char* lAn = smem + slotN * 32768;                          \
    _Pragma("unroll")                                                         \
    for (int mf = 0; mf < 4; ++mf)                                            \
      NXTA[mf] = *(const bf16x8*)(lAn + (rAv + mf * 16) * 64 + kqA);          \
    _Pragma("unroll")                                                         \
    for (int nf = 0; nf < 4; ++nf)                                            \
      NXTB[nf] = *(const bf16x8*)(lAn + 16384 + (rB + nf * 16) * 64 + kqB);   \
    __builtin_amdgcn_s_setprio(1);                                            \
    _Pragma("unroll")                                                         \
    for (int mf = 0; mf < 4; ++mf) {                                          \
      _Pragma("unroll")                                                       \
      for (int nf = 0; nf < 4; ++nf)                                          \
        acc[mf][nf] = __builtin_amdgcn_mfma_f32_16x16x32_bf16(                \
            CURA[mf], CURB[nf], acc[mf][nf], 0, 0, 0);                        \
    }                                                                         \
    __builtin_amdgcn_s_setprio(0);                                            \
    slotC = slotN;                                                            \
    ++t2;                                                                     \
  }

    for (int t = 0; t < 144; t += 2) {
      CONV_LV(afA, bfA, afB, bfB)
      CONV_LV(afB, bfB, afA, bfA)
    }
#undef CONV_LV
  }

  // ---- epilogue: all products at scale 2^14 -> * 2^-14 ----
  constexpr float SC = 1.f / 16384.f;
  if (m0 < 1024) {
#pragma unroll
    for (int mf = 0; mf < 8; ++mf) {
#pragma unroll
      for (int nf = 0; nf < 4; ++nf) {
        f32x4 a = acc[mf][nf];
        int mrow = m0 + wr * 128 + mf * 16 + ((lane >> 4) << 2);
        int ncol = nl0 + wc * 64 + nf * 16 + (lane & 15);
        if (m0 < 512) {
#pragma unroll
          for (int j = 0; j < 4; ++j) {
            float v = a[j] * SC + bias[mrow + j];
            unsigned short h16 = f2bf(v);
            size_t o = ((size_t)bidx * CC + (mrow + j)) * CN + ncol;
            Qhi[o] = h16;
            Qlo[o] = f2bf(v - bf2f(h16));
          }
        } else {
#pragma unroll
          for (int j = 0; j < 4; ++j) {
            float v = a[j] * SC + bias[mrow + j];
            unsigned short h16 = f2bf(v);
            size_t o = ((size_t)bidx * CC + (mrow + j - 512)) * CN + ncol;
            Khi[o] = h16;
            Klo[o] = f2bf(v - bf2f(h16));
          }
        }
      }
    }
  } else {
#pragma unroll
    for (int mf = 0; mf < 4; ++mf) {
#pragma unroll
      for (int nf = 0; nf < 4; ++nf) {
        f32x4 a = acc[mf][nf];
        int mrow = m0 + wr * 64 + mf * 16 + ((lane >> 4) << 2);
        int ncol = nl0 + wc * 64 + nf * 16 + (lane & 15);
        u16x4 vs;                     // V written transposed: Vt[b][n][d]
#pragma unroll
        for (int j = 0; j < 4; ++j) vs[j] = f2bf(a[j] * SC + bias[mrow + j]);
        *(u16x4*)&Vt[((size_t)bidx * CN + ncol) * CC + (mrow - 1024)] = vs;
      }
    }
  }
}

// ---- MFMA GEMM: MODE 1=QK^T (3-phase hi/lo, split-K), 2=PV -----------------
DI int sofs(int row, int kb) { return row * 128 + (kb ^ ((row & 7) << 4)); }

template<int MODE>
__global__ __launch_bounds__(256) void gemm_k(
    const unsigned short* __restrict__ Qhi, const unsigned short* __restrict__ Qlo,
    const unsigned short* __restrict__ Khi, const unsigned short* __restrict__ Klo,
    const unsigned short* __restrict__ Vt,
    float* __restrict__ attn,
    const unsigned short* __restrict__ P,
    const float* __restrict__ xin,
    const float* __restrict__ gamma,
    float* __restrict__ out)
{
  __shared__ __align__(16) unsigned char sA[16384];
  __shared__ __align__(16) unsigned char sB[16384];
  const int tid = threadIdx.x;
  const int lane = tid & 63;
  const int wav = tid >> 6;
  const int wr = wav >> 1, wc = wav & 1;

  int m0, n0, bidx, Kbeg = 0, Kend, ks = 0;
  if constexpr (MODE == 1) {
    int tile = blockIdx.x & 15;
    ks = blockIdx.x >> 4;             // 0..KSPL-1
    m0 = (tile & 3) * 128;
    n0 = (tile >> 2) * 128;
    bidx = blockIdx.z;
    Kbeg = ks * (3 * CN / KSPL);
    Kend = Kbeg + (3 * CN / KSPL);
  } else {
    m0 = (blockIdx.x & 3) * 128;
    n0 = (blockIdx.x >> 2) * 128;
    bidx = blockIdx.z;
    Kend = CC;
  }

  auto stage = [&](int k0) {
#pragma unroll
    for (int q = 0; q < 4; ++q) {
      int ci = q * 256 + tid;
      int row = ci >> 3;
      int ke = ((ci & 7) ^ (row & 7)) * 8;
      const unsigned short* ap;
      const unsigned short* bp;
      if constexpr (MODE == 1) {
        int ph = k0 >> 12;
        int kin = k0 & (CN - 1);
        const unsigned short* Aq = (ph == 2) ? Qlo : Qhi;
        const unsigned short* Bk = (ph == 1) ? Klo : Khi;
        ap = Aq + ((size_t)bidx * CC + (m0 + row)) * CN + (kin + ke);
        bp = Bk + ((size_t)bidx * CC + (n0 + row)) * CN + (kin + ke);
      } else {
        ap = P + ((size_t)bidx * CC + (m0 + row)) * CC + (k0 + ke);
        bp = Vt + ((size_t)bidx * CN + (n0 + row)) * CC + (k0 + ke);
      }
      int wbase = (q * 256 + wav * 64) * 16;
      g2lds16(ap, sA + wbase);
      g2lds16(bp, sB + wbase);
    }
  };

  f32x4 acc[4][4];
  const f32x4 fz = {0.f, 0.f, 0.f, 0.f};
#pragma unroll
  for (int i = 0; i < 4; ++i)
#pragma unroll
    for (int j = 0; j < 4; ++j) acc[i][j] = fz;

  for (int k0 = Kbeg; k0 < Kend; k0 += 64) {
    stage(k0);
    __syncthreads();
#pragma unroll
    for (int kkp = 0; kkp < 2; ++kkp) {
      bf16x8 af[4], bfv[4];
#pragma unroll
      for (int mf = 0; mf < 4; ++mf)
        af[mf] = *(const bf16x8*)&sA[sofs(wr * 64 + mf * 16 + (lane & 15),
                                          kkp * 64 + (lane >> 4) * 16)];
#pragma unroll
      for (int nf = 0; nf < 4; ++nf)
        bfv[nf] = *(const bf16x8*)&sB[sofs(wc * 64 + nf * 16 + (lane & 15),
                                           kkp * 64 + (lane >> 4) * 16)];
#pragma unroll
      for (int mf = 0; mf < 4; ++mf)
#pragma unroll
        for (int nf = 0; nf < 4; ++nf)
          acc[mf][nf] = __builtin_amdgcn_mfma_f32_16x16x32_bf16(
              af[mf], bfv[nf], acc[mf][nf], 0, 0, 0);
    }
    __syncthreads();
  }

  float g = 0.f;
  if constexpr (MODE == 2) g = gamma[0];
#pragma unroll
  for (int mf = 0; mf < 4; ++mf) {
#pragma unroll
    for (int nf = 0; nf < 4; ++nf) {
      f32x4 a = acc[mf][nf];
      int mrow = m0 + wr * 64 + mf * 16 + ((lane >> 4) << 2);
      int ncol = n0 + wc * 64 + nf * 16 + (lane & 15);
      if constexpr (MODE == 1) {
        size_t pbase = (size_t)ks * ((size_t)BCH * CC * CC);
#pragma unroll
        for (int j = 0; j < 4; ++j)
          attn[pbase + ((size_t)bidx * CC + (mrow + j)) * CC + ncol] = a[j];
      } else {
#pragma unroll
        for (int j = 0; j < 4; ++j) {
          size_t o = ((size_t)bidx * CC + (mrow + j)) * CN + ncol;
          out[o] = g * a[j] + xin[o];
        }
      }
    }
  }
}

// ---- softmax over d (512): sum KSPL split-K partials, one wave per row -----
__global__ __launch_bounds__(256) void softmax_k(const float* __restrict__ attn,
                                                 unsigned short* __restrict__ P) {
  int row = blockIdx.x * 4 + (threadIdx.x >> 6);
  int lane = threadIdx.x & 63;
  constexpr size_t PS = (size_t)BCH * CC * CC;
  const float* rp = attn + (size_t)row * 512 + lane * 8;
  f32x4 a = {0.f, 0.f, 0.f, 0.f};
  f32x4 b = {0.f, 0.f, 0.f, 0.f};
#pragma unroll
  for (int ksp = 0; ksp < KSPL; ++ksp) {
    a += *(const f32x4*)(rp + (size_t)ksp * PS);
    b += *(const f32x4*)(rp + (size_t)ksp * PS + 4);
  }
  float mx = fmaxf(fmaxf(fmaxf(a[0], a[1]), fmaxf(a[2], a[3])),
                   fmaxf(fmaxf(b[0], b[1]), fmaxf(b[2], b[3])));
#pragma unroll
  for (int s = 32; s > 0; s >>= 1) mx = fmaxf(mx, __shfl_xor(mx, s, 64));
  float e[8];
  float sum = 0.f;
#pragma unroll
  for (int j = 0; j < 4; ++j) { e[j] = __expf(a[j] - mx); sum += e[j]; }
#pragma unroll
  for (int j = 0; j < 4; ++j) { e[4 + j] = __expf(b[j] - mx); sum += e[4 + j]; }
#pragma unroll
  for (int s = 32; s > 0; s >>= 1) sum += __shfl_xor(sum, s, 64);
  float inv = 1.0f / sum;
  u16x8 o;
#pragma unroll
  for (int j = 0; j < 8; ++j) o[j] = f2bf(e[j] * inv);
  *(u16x8*)&P[(size_t)row * 512 + lane * 8] = o;
}

// ---- diagnostic: fill out with sentinel if workspace is too small ----------
__global__ __launch_bounds__(256) void fill_sentinel(float* __restrict__ out, int n) {
  int i = blockIdx.x * 256 + threadIdx.x;
  if (i < n) out[i] = 1.0e4f;
}

// ---------------------------------------------------------------------------
extern "C" void kernel_launch(void* const* d_in, const int* in_sizes, int n_in,
                              void* d_out, int out_size, void* d_ws, size_t ws_size,
                              hipStream_t stream) {
  (void)in_sizes; (void)n_in;
  const float* x  = (const float*)d_in[0];
  const float* wq = (const float*)d_in[1];
  const float* bq = (const float*)d_in[2];
  const float* wk = (const float*)d_in[3];
  const float* bk = (const float*)d_in[4];
  const float* wv = (const float*)d_in[5];
  const float* bv = (const float*)d_in[6];
  const float* gm = (const float*)d_in[7];
  float* out = (float*)d_out;

  uint8_t* wsp = (uint8_t*)d_ws;
  auto take = [&](size_t bytes) {
    uint8_t* p = wsp;
    wsp += (bytes + 255) & ~(size_t)255;
    return p;
  };
  unsigned short* Xhi = (unsigned short*)take(XSPLIT * 2);          // 17.8 MB
  unsigned char*  X8  = (unsigned char*)take(2 * XSPLIT);           // 17.8 MB
  unsigned short* Ahi = (unsigned short*)take((size_t)MR * K1 * 2); // 13.5 MB
  unsigned char*  A8  = (unsigned char*)take((size_t)MR * 2 * K1);  // 13.5 MB
  float* bias         = (float*)take((size_t)MR * 4);
  unsigned short* Khi = (unsigned short*)take((size_t)BCH * CC * CN * 2);  // 16.8 MB
  unsigned short* Klo = (unsigned short*)take((size_t)BCH * CC * CN * 2);  // 16.8 MB
  unsigned short* Vt  = (unsigned short*)take((size_t)BCH * CN * CC * 2);  // 16.8 MB
  // attn (KSPL=8 partials, 33.55MB) + P (2.1MB) alias Xhi+X8 (35.68MB region,
  // dead after conv); interiors rewritten by prep_xpad, pads re-zeroed/chunk.
  float* attn         = (float*)Xhi;
  unsigned short* P   = (unsigned short*)((uint8_t*)Xhi +
                          (size_t)KSPL * BCH * CC * CC * 4 + 256);

  size_t needed = (size_t)(wsp - (uint8_t*)d_ws);   // ~113 MB
  if (ws_size < needed) {
    fill_sentinel<<<(out_size + 255) / 256, 256, 0, stream>>>(out, out_size);
    return;
  }

  for (int ch = 0; ch < CB / BCH; ++ch) {
    const float* xch = x + (size_t)ch * BCH * CC * CN;
    float* outch = out + (size_t)ch * BCH * CC * CN;
    unsigned short* Qhi = (unsigned short*)outch;   // Q pair lives in d_out
    unsigned short* Qlo = Qhi + (size_t)BCH * CC * CN;

    pad_zero<<<(4 * 260 * 16 + 255) / 256, 256, 0, stream>>>(Xhi, X8);
    prep_xpad<<<BCH * 16 * 64, 256, 0, stream>>>(xch, Xhi, X8);
    if (ch == 0)
      prep_abig<<<(MR * K1) / 256, 256, 0, stream>>>(wq, wk, wv, bq, bk, bv,
                                                     Ahi, A8, bias);
    conv_k<<<dim3(512), 512, 0, stream>>>(Ahi, A8, Xhi, X8, bias,
                                          Qhi, Qlo, Khi, Klo, Vt);
    gemm_k<1><<<dim3(16 * KSPL, 1, BCH), 256, 0, stream>>>(Qhi, Qlo, Khi, Klo, Vt,
                                                           attn, P, xch, gm, outch);
    softmax_k<<<BCH * 128, 256, 0, stream>>>(attn, P);
    gemm_k<2><<<dim3(128, 1, BCH), 256, 0, stream>>>(Qhi, Qlo, Khi, Klo, Vt,
                                                     attn, P, xch, gm, outch);
  }
}

// Round 14
// 945.155 us; speedup vs baseline: 1.8311x; 1.0191x over previous
//
#include <hip/hip_runtime.h>
#include <stdint.h>

typedef __attribute__((ext_vector_type(8))) short bf16x8;
typedef __attribute__((ext_vector_type(4))) float f32x4;
typedef __attribute__((ext_vector_type(4))) int i32x4;
typedef __attribute__((ext_vector_type(8))) int i32x8;
typedef __attribute__((ext_vector_type(8))) unsigned short u16x8;
typedef __attribute__((ext_vector_type(4))) unsigned short u16x4;

#define DI static __device__ __forceinline__

constexpr int CB = 8;          // batch (total)
constexpr int BCH = 4;         // batches per chunk (2 chunks)
constexpr int CC = 512;        // channels
constexpr int CN = 4096;       // H*W
constexpr int K1 = CC * 9;     // 4608
constexpr int MR = 3 * CC;     // 1536 output rows (q|k|v)
constexpr int KSPL = 8;        // QK^T split-K factor
constexpr size_t XSPLIT = (size_t)BCH * 66 * 66 * 512;

DI unsigned short f2bf(float f) {
  union { float f; uint32_t u; } v; v.f = f;
  uint32_t r = (v.u + 0x7FFFu + ((v.u >> 16) & 1u)) >> 16;  // RNE
  return (unsigned short)r;
}
DI float bf2f(unsigned short h) {
  union { uint32_t u; float f; } v; v.u = ((uint32_t)h) << 16;
  return v.f;
}
// manual OCP e4m3fn convert (RNE on mantissa; sat to 448); input |x| << 448 here
DI unsigned char f2e4m3(float x) {
  union { float f; uint32_t u; } v; v.f = x;
  uint32_t sgn = (v.u >> 24) & 0x80u;
  float a = fabsf(x);
  if (a < 0.015625f) {                       // subnormal: quantum 2^-9
    int qi = (int)rintf(a * 512.f);          // 0..8 (8 -> min normal 0x08)
    return (unsigned char)(sgn | (uint32_t)qi);
  }
  int e = (int)((v.u >> 23) & 0xff) - 127;
  uint32_t m3 = (v.u >> 20) & 7u;
  uint32_t rest = v.u & 0xFFFFFu;
  if (rest > 0x80000u || (rest == 0x80000u && (m3 & 1u))) {
    if (++m3 == 8u) { m3 = 0; ++e; }
  }
  if (e > 8 || (e == 8 && m3 == 7u)) return (unsigned char)(sgn | 0x7Eu);
  return (unsigned char)(sgn | ((uint32_t)(e + 7) << 3) | m3);
}

DI void g2lds16(const void* g, void* l) {
  __builtin_amdgcn_global_load_lds((const __attribute__((address_space(1))) void*)g,
                                   (__attribute__((address_space(3))) void*)l, 16, 0, 0);
}
#define SBAR()  __builtin_amdgcn_s_barrier()
#define SCHED() __builtin_amdgcn_sched_barrier(0)

// ---- prep 0: zero only the pad border cells --------------------------------
__global__ __launch_bounds__(256) void pad_zero(unsigned short* __restrict__ Xhi,
                                                unsigned char* __restrict__ X8) {
  int id = blockIdx.x * 256 + threadIdx.x;
  if (id >= 4 * 260 * 16) return;
  int t = id & 15;
  int pp = (id >> 4) % 260;
  int b = id / (260 * 16);
  int hh, ww;
  if (pp < 66)       { hh = 0;  ww = pp; }
  else if (pp < 132) { hh = 65; ww = pp - 66; }
  else if (pp < 196) { hh = pp - 131; ww = 0; }
  else               { hh = pp - 195; ww = 65; }
  size_t pix = (((size_t)b * 66 + hh) * 66 + ww) * 512 + (size_t)t * 32;
  const u16x8 z = {0, 0, 0, 0, 0, 0, 0, 0};
  *(u16x8*)&Xhi[pix] = z;  *(u16x8*)&Xhi[pix + 8] = z;
  *(u16x8*)&Xhi[pix + 16] = z;  *(u16x8*)&Xhi[pix + 24] = z;
  const i32x4 z4 = {0, 0, 0, 0};
  *(i32x4*)&X8[pix] = z4;  *(i32x4*)&X8[pix + 16] = z4;
  *(i32x4*)&X8[XSPLIT + pix] = z4;  *(i32x4*)&X8[XSPLIT + pix + 16] = z4;
}

// ---- prep 1: Xhi (bf16, x2^7), X8 split0=Xlo8 (x2^8), split1=Xhi8 (x1) -----
__global__ __launch_bounds__(256) void prep_xpad(const float* __restrict__ x,
                                                 unsigned short* __restrict__ Xhi,
                                                 unsigned char* __restrict__ X8) {
  int tid = threadIdx.x;
  int w = tid & 63;
  int ccl = tid >> 6;
  int blk = blockIdx.x;               // 4096 = b(4) * ccg(16) * h(64)
  int h = blk & 63;
  int ccg = (blk >> 6) & 15;
  int b = blk >> 10;
  int c0 = (ccg * 4 + ccl) * 8;
  const float* xp = x + ((size_t)b * CC) * CN + h * 64 + w;
  u16x8 hi;
  unsigned long long lo8 = 0, hi8 = 0;
#pragma unroll
  for (int j = 0; j < 8; ++j) {
    float v = xp[(size_t)(c0 + j) * CN];
    unsigned short h16 = f2bf(v);
    float vhi = bf2f(h16);
    hi[j] = f2bf(vhi * 128.f);                    // exact shift
    lo8 |= (unsigned long long)f2e4m3((v - vhi) * 256.f) << (8 * j);
    hi8 |= (unsigned long long)f2e4m3(vhi) << (8 * j);
  }
  size_t pix = (((size_t)b * 66 + (h + 1)) * 66 + (w + 1)) * 512;
  *(u16x8*)&Xhi[pix + c0] = hi;
  *(unsigned long long*)&X8[pix + c0] = lo8;
  *(unsigned long long*)&X8[XSPLIT + pix + c0] = hi8;
}

// ---- prep 2: Ahi [1536][4608] bf16 (x2^7), A8 [1536][9216] fp8 plain -------
__global__ __launch_bounds__(256) void prep_abig(
    const float* __restrict__ wq, const float* __restrict__ wk,
    const float* __restrict__ wv, const float* __restrict__ bq,
    const float* __restrict__ bk, const float* __restrict__ bv,
    unsigned short* __restrict__ Ahi, unsigned char* __restrict__ A8,
    float* __restrict__ bias) {
  unsigned id = blockIdx.x * 256 + threadIdx.x;   // total 1536*4608
  int m = id / K1;
  int r = id - m * K1;
  int t = r >> 9;
  int c = r & 511;
  int ky = t / 3;
  int kx = t - ky * 3;
  size_t ip = (size_t)m * 9216 + r;
  if (m < 1024) {
    const float* wp = (m < 512) ? wq : wk;
    int mm = (m < 512) ? m : m - 512;
    float wval = wp[(((size_t)mm * 512 + c) * 3 + ky) * 3 + kx];
    float whi = bf2f(f2bf(wval));
    Ahi[id] = f2bf(whi * 128.f);
    A8[ip] = f2e4m3(whi * 64.f);
    A8[ip + 4608] = f2e4m3((wval - whi) * 16384.f);
  } else {
    float wval = wv[(((size_t)(m - 1024) * 512 + c) * 3 + ky) * 3 + kx];
    Ahi[id] = f2bf(wval * 128.f);
    A8[ip] = 0;
    A8[ip + 4608] = 0;
  }
  if (id < 1536) {
    int mm = (int)id;
    bias[mm] = (mm < 512) ? bq[mm] : (mm < 1024) ? bk[mm - 512] : bv[mm - 1024];
  }
}

// ---- conv GEMM: 4-slot ring, bf16 phase1 + MX-scaled fp8 K=128 phase2 ------
// (unchanged from r13; the r13 parity XOR was conflict-neutral but harmless)
__global__ __launch_bounds__(512, 2) void conv_k(
    const unsigned short* __restrict__ Ahi,
    const unsigned char* __restrict__ A8,
    const unsigned short* __restrict__ Xhi,
    const unsigned char* __restrict__ X8,
    const float* __restrict__ bias,
    unsigned short* __restrict__ Qhi, unsigned short* __restrict__ Qlo,
    unsigned short* __restrict__ Khi, unsigned short* __restrict__ Klo,
    unsigned short* __restrict__ Vt)
{
  __shared__ __align__(16) unsigned char smem[4 * 32768];
  const int tid = threadIdx.x;
  const int lane = tid & 63;
  const int wid = tid >> 6;
  const int wr = wid >> 2;            // 0..1 (M)
  const int wc = wid & 3;             // 0..3 (N)

  int orig = blockIdx.x;
  int xcd, nbl, m0;
  if (orig < 256) {                   // heavy q/k: 256x256
    xcd = orig & 7; int j = orig >> 3;
    nbl = j >> 2;
    m0 = (j & 3) * 256;               // 0..768
  } else {                            // light v: 128x256
    int o = orig - 256;
    xcd = o & 7; int j = o >> 3;      // 0..31
    nbl = j >> 2;
    m0 = 1024 + (j & 3) * 128;        // 1024..1408
  }
  const int nb = xcd * 8 + nbl;
  const int n0 = nb * 256;
  const int bidx = n0 >> 12;
  const int nl0 = n0 & (CN - 1);
  const int h0 = nl0 >> 6;

  const int srow = tid >> 2;          // 0..127
  const int scu = tid & 3;
  const int scuS = scu ^ ((srow >> 1) & 3);
  const int d8 = (scuS & 1) ? -16 : 16;
  const size_t pixOfs = (((size_t)(bidx * 66 + h0 + (srow >> 6))) * 66 + (srow & 63)) * 512;
  const unsigned short* gAh0 = Ahi + (size_t)(m0 + srow) * K1 + scuS * 8;
  const unsigned short* gAh1 = gAh0 + (size_t)128 * K1;
  const unsigned short* gBh0 = Xhi + pixOfs + scuS * 8;
  const unsigned short* gBh1 = gBh0 + (size_t)2 * 66 * 512;
  const unsigned char* gA80 = A8 + (size_t)(m0 + srow) * 9216 + scuS * 16;
  const unsigned char* gA81 = gA80 + (size_t)128 * 9216;
  const unsigned char* gB80 = X8 + pixOfs + scuS * 16;
  const unsigned char* gB81 = gB80 + (size_t)2 * 66 * 512;
  const int wofs = wid * 1024;

  int c0S = 0, kxS = 0, tapS = 0;
  size_t tapOfs = 0;
  auto stage1 = [&](int slot) {       // heavy: 4 loads
    int aOfs = tapS * 512 + c0S;
    size_t bOfs = tapOfs + (size_t)c0S;
    unsigned char* lA = smem + slot * 32768 + wofs;
    unsigned char* lB = smem + slot * 32768 + 16384 + wofs;
    g2lds16(gAh0 + aOfs, lA);
    g2lds16(gAh1 + aOfs, lA + 8192);
    g2lds16(gBh0 + bOfs, lB);
    g2lds16(gBh1 + bOfs, lB + 8192);
    c0S += 32;
    if (c0S == 512) {
      c0S = 0; ++tapS;
      if (kxS == 2) { kxS = 0; tapOfs += (size_t)64 * 512; }
      else { ++kxS; tapOfs += 512; }
    }
  };
  auto stage1v = [&](int slot) {      // light: 3 loads (A is 128 rows)
    int aOfs = tapS * 512 + c0S;
    size_t bOfs = tapOfs + (size_t)c0S;
    unsigned char* lA = smem + slot * 32768 + wofs;
    unsigned char* lB = smem + slot * 32768 + 16384 + wofs;
    g2lds16(gAh0 + aOfs, lA);
    g2lds16(gBh0 + bOfs, lB);
    g2lds16(gBh1 + bOfs, lB + 8192);
    c0S += 32;
    if (c0S == 512) {
      c0S = 0; ++tapS;
      if (kxS == 2) { kxS = 0; tapOfs += (size_t)64 * 512; }
      else { ++kxS; tapOfs += 512; }
    }
  };
  int c8 = 0, kx8 = 0, tap8 = 0, s8 = 0;
  size_t tapOfs8 = 0;
  auto stage2 = [&](int slot) {
    int so = (slot & 1) ? d8 : 0;
    int aOfs = s8 * 4608 + tap8 * 512 + c8;
    size_t bOfs = (size_t)s8 * XSPLIT + tapOfs8 + (size_t)c8;
    unsigned char* lA = smem + slot * 32768 + wofs;
    unsigned char* lB = smem + slot * 32768 + 16384 + wofs;
    g2lds16(gA80 + aOfs + so, lA);
    g2lds16(gA81 + aOfs + so, lA + 8192);
    g2lds16(gB80 + bOfs + so, lB);
    g2lds16(gB81 + bOfs + so, lB + 8192);
    c8 += 64;
    if (c8 == 512) {
      c8 = 0; ++tap8;
      if (tap8 == 9) { tap8 = 0; kx8 = 0; tapOfs8 = 0; ++s8; }
      else if (kx8 == 2) { kx8 = 0; tapOfs8 += (size_t)64 * 512; }
      else { ++kx8; tapOfs8 += 512; }
    }
  };

  f32x4 acc[8][4];
  const f32x4 fz = {0.f, 0.f, 0.f, 0.f};
#pragma unroll
  for (int i = 0; i < 8; ++i)
#pragma unroll
    for (int j = 0; j < 4; ++j) acc[i][j] = fz;

  const int kq = (lane >> 4) * 16;
  int slotC, slotS, t2;

  if (m0 < 1024) {
    const int rA = wr * 128 + (lane & 15);
    const int rB = wc * 64 + (lane & 15);
    const int kqA = kq ^ (((rA >> 1) & 3) << 4);
    const int kqB = kq ^ (((rB >> 1) & 3) << 4);

    stage1(0);
    stage1(1);
    asm volatile("s_waitcnt vmcnt(4)" ::: "memory");
    SCHED(); SBAR(); SCHED();
    {
      bf16x8 afA[4], bfA[4], afB[4], bfB[4], af1[4];
#pragma unroll
      for (int mf = 0; mf < 4; ++mf)
        afA[mf] = *(const bf16x8*)(smem + (rA + mf * 16) * 64 + kqA);
#pragma unroll
      for (int nf = 0; nf < 4; ++nf)
        bfA[nf] = *(const bf16x8*)(smem + 16384 + (rB + nf * 16) * 64 + kqB);
      slotC = 0; slotS = 2; t2 = 2;

#define CONV_BF(CURA, CURB, NXTA, NXTB)                                       \
  {                                                                           \
    if (t2 < 144) {                                                           \
      stage1(slotS); slotS = (slotS + 1) & 3;                                 \
      asm volatile("s_waitcnt vmcnt(4)" ::: "memory");                        \
    } else {                                                                  \
      asm volatile("s_waitcnt vmcnt(0)" ::: "memory");                        \
    }                                                                         \
    SCHED(); SBAR(); SCHED();                                                 \
    const unsigned char* lA = smem + slotC * 32768;                           \
    const int slotN = (slotC + 1) & 3;                                        \
    const unsigned char* lAn = smem + slotN * 32768;                          \
    _Pragma("unroll")                                                         \
    for (int mf = 0; mf < 4; ++mf)                                            \
      af1[mf] = *(const bf16x8*)(lA + (rA + 64 + mf * 16) * 64 + kqA);        \
    __builtin_amdgcn_s_setprio(1);                                            \
    _Pragma("unroll")                                                         \
    for (int mf = 0; mf < 4; ++mf) {                                          \
      _Pragma("unroll")                                                       \
      for (int nf = 0; nf < 4; ++nf)                                          \
        acc[mf][nf] = __builtin_amdgcn_mfma_f32_16x16x32_bf16(                \
            CURA[mf], CURB[nf], acc[mf][nf], 0, 0, 0);                        \
    }                                                                         \
    __builtin_amdgcn_s_setprio(0);                                            \
    _Pragma("unroll")                                                         \
    for (int mf = 0; mf < 4; ++mf)                                            \
      NXTA[mf] = *(const bf16x8*)(lAn + (rA + mf * 16) * 64 + kqA);           \
    _Pragma("unroll")                                                         \
    for (int nf = 0; nf < 4; ++nf)                                            \
      NXTB[nf] = *(const bf16x8*)(lAn + 16384 + (rB + nf * 16) * 64 + kqB);   \
    __builtin_amdgcn_s_setprio(1);                                            \
    _Pragma("unroll")                                                         \
    for (int mf = 0; mf < 4; ++mf) {                                          \
      _Pragma("unroll")                                                       \
      for (int nf = 0; nf < 4; ++nf)                                          \
        acc[mf + 4][nf] = __builtin_amdgcn_mfma_f32_16x16x32_bf16(            \
            af1[mf], CURB[nf], acc[mf + 4][nf], 0, 0, 0);                     \
    }                                                                         \
    __builtin_amdgcn_s_setprio(0);                                            \
    slotC = slotN;                                                            \
    ++t2;                                                                     \
  }

      for (int t = 0; t < 144; t += 2) {
        CONV_BF(afA, bfA, afB, bfB)
        CONV_BF(afB, bfB, afA, bfA)
      }
#undef CONV_BF
    }

    // ---- phase 2': scaled fp8, 72 pair-bodies of K=128 ----
    stage2(0); stage2(1);
    SCHED(); SBAR(); SCHED();
    stage2(2); stage2(3);
    {
      const int gq = lane >> 4;
      const int slotByte = (gq >> 1) << 15;
      const int cb2 = (gq & 1) * 2;
      const int fx = (((lane & 15) >> 1) & 3) ^ (gq >> 1);
      const int bo0 = ((cb2 ^ fx) << 4);
      const int bo1 = (((cb2 + 1) ^ fx) << 4);
      const int aRow = wr * 128 + (lane & 15);
      const int bRow = wc * 64 + (lane & 15);
      i32x8 aF[4], bF[4];
      for (int p = 0; p < 72; ++p) {
        SCHED(); SBAR(); SCHED();
        if (p < 71) { asm volatile("s_waitcnt vmcnt(8)" ::: "memory"); }
        else        { asm volatile("s_waitcnt vmcnt(0)" ::: "memory"); }
        SCHED();
        const unsigned char* pbA = smem + ((p & 1) << 16) + slotByte + aRow * 64;
        const unsigned char* pbB = smem + ((p & 1) << 16) + slotByte + 16384 + bRow * 64;
#pragma unroll
        for (int t = 0; t < 4; ++t) {
          *(i32x4*)&bF[t] = *(const i32x4*)(pbB + t * 1024 + bo0);
          *((i32x4*)&bF[t] + 1) = *(const i32x4*)(pbB + t * 1024 + bo1);
        }
#pragma unroll
        for (int s = 0; s < 4; ++s) {
          *(i32x4*)&aF[s] = *(const i32x4*)(pbA + s * 1024 + bo0);
          *((i32x4*)&aF[s] + 1) = *(const i32x4*)(pbA + s * 1024 + bo1);
        }
        __builtin_amdgcn_s_setprio(1);
#pragma unroll
        for (int s = 0; s < 4; ++s)
#pragma unroll
          for (int t = 0; t < 4; ++t)
            acc[s][t] = __builtin_amdgcn_mfma_scale_f32_16x16x128_f8f6f4(
                aF[s], bF[t], acc[s][t], 0, 0, 0, 127, 0, 127);
        __builtin_amdgcn_s_setprio(0);
#pragma unroll
        for (int s = 0; s < 4; ++s) {
          *(i32x4*)&aF[s] = *(const i32x4*)(pbA + (4 + s) * 1024 + bo0);
          *((i32x4*)&aF[s] + 1) = *(const i32x4*)(pbA + (4 + s) * 1024 + bo1);
        }
        __builtin_amdgcn_s_setprio(1);
#pragma unroll
        for (int s = 0; s < 4; ++s)
#pragma unroll
          for (int t = 0; t < 4; ++t)
            acc[s + 4][t] = __builtin_amdgcn_mfma_scale_f32_16x16x128_f8f6f4(
                aF[s], bF[t], acc[s + 4][t], 0, 0, 0, 127, 0, 127);
        __builtin_amdgcn_s_setprio(0);
        SCHED(); SBAR(); SCHED();
        if (p + 2 < 72) { stage2(2 * (p & 1)); stage2(2 * (p & 1) + 1); }
      }
    }
  } else {
    // =================== LIGHT v: 128x256, bf16 s0 only ====================
    const int rAv = wr * 64 + (lane & 15);
    const int rB = wc * 64 + (lane & 15);
    const int kqA = kq ^ (((rAv >> 1) & 3) << 4);
    const int kqB = kq ^ (((rB >> 1) & 3) << 4);

    stage1v(0);
    stage1v(1);
    asm volatile("s_waitcnt vmcnt(3)" ::: "memory");
    SCHED(); SBAR(); SCHED();
    bf16x8 afA[4], bfA[4], afB[4], bfB[4];
#pragma unroll
    for (int mf = 0; mf < 4; ++mf)
      afA[mf] = *(const bf16x8*)(smem + (rAv + mf * 16) * 64 + kqA);
#pragma unroll
    for (int nf = 0; nf < 4; ++nf)
      bfA[nf] = *(const bf16x8*)(smem + 16384 + (rB + nf * 16) * 64 + kqB);
    slotC = 0; slotS = 2; t2 = 2;

#define CONV_LV(CURA, CURB, NXTA, NXTB)                                       \
  {                                                                           \
    if (t2 < 144) {                                                           \
      stage1v(slotS); slotS = (slotS + 1) & 3;                                \
      asm volatile("s_waitcnt vmcnt(3)" ::: "memory");                        \
    } else {                                                                  \
      asm volatile("s_waitcnt vmcnt(0)" ::: "memory");                        \
    }                                                                         \
    SCHED(); SBAR(); SCHED();                                                 \
    const int slotN = (slotC + 1) & 3;                                        \
    const unsigned char* lAn = smem + slotN * 32768;                          \
    _Pragma("unroll")                                                         \
    for (int mf = 0; mf < 4; ++mf)                                            \
      NXTA[mf] = *(const bf16x8*)(lAn + (rAv + mf * 16) * 64 + kqA);          \
    _Pragma("unroll")                                                         \
    for (int nf = 0; nf < 4; ++nf)                                            \
      NXTB[nf] = *(const bf16x8*)(lAn + 16384 + (rB + nf * 16) * 64 + kqB);   \
    __builtin_amdgcn_s_setprio(1);                                            \
    _Pragma("unroll")                                                         \
    for (int mf = 0; mf < 4; ++mf) {                                          \
      _Pragma("unroll")                                                       \
      for (int nf = 0; nf < 4; ++nf)                                          \
        acc[mf][nf] = __builtin_amdgcn_mfma_f32_16x16x32_bf16(                \
            CURA[mf], CURB[nf], acc[mf][nf], 0, 0, 0);                        \
    }                                                                         \
    __builtin_amdgcn_s_setprio(0);                                            \
    slotC = slotN;                                                            \
    ++t2;                                                                     \
  }

    for (int t = 0; t < 144; t += 2) {
      CONV_LV(afA, bfA, afB, bfB)
      CONV_LV(afB, bfB, afA, bfA)
    }
#undef CONV_LV
  }

  // ---- epilogue: all products at scale 2^14 -> * 2^-14 ----
  constexpr float SC = 1.f / 16384.f;
  if (m0 < 1024) {
#pragma unroll
    for (int mf = 0; mf < 8; ++mf) {
#pragma unroll
      for (int nf = 0; nf < 4; ++nf) {
        f32x4 a = acc[mf][nf];
        int mrow = m0 + wr * 128 + mf * 16 + ((lane >> 4) << 2);
        int ncol = nl0 + wc * 64 + nf * 16 + (lane & 15);
        if (m0 < 512) {
#pragma unroll
          for (int j = 0; j < 4; ++j) {
            float v = a[j] * SC + bias[mrow + j];
            unsigned short h16 = f2bf(v);
            size_t o = ((size_t)bidx * CC + (mrow + j)) * CN + ncol;
            Qhi[o] = h16;
            Qlo[o] = f2bf(v - bf2f(h16));
          }
        } else {
#pragma unroll
          for (int j = 0; j < 4; ++j) {
            float v = a[j] * SC + bias[mrow + j];
            unsigned short h16 = f2bf(v);
            size_t o = ((size_t)bidx * CC + (mrow + j - 512)) * CN + ncol;
            Khi[o] = h16;
            Klo[o] = f2bf(v - bf2f(h16));
          }
        }
      }
    }
  } else {
#pragma unroll
    for (int mf = 0; mf < 4; ++mf) {
#pragma unroll
      for (int nf = 0; nf < 4; ++nf) {
        f32x4 a = acc[mf][nf];
        int mrow = m0 + wr * 64 + mf * 16 + ((lane >> 4) << 2);
        int ncol = nl0 + wc * 64 + nf * 16 + (lane & 15);
        u16x4 vs;                     // V written transposed: Vt[b][n][d]
#pragma unroll
        for (int j = 0; j < 4; ++j) vs[j] = f2bf(a[j] * SC + bias[mrow + j]);
        *(u16x4*)&Vt[((size_t)bidx * CN + ncol) * CC + (mrow - 1024)] = vs;
      }
    }
  }
}

// ---- QK^T: r14 rewrite on the 4-slot/1-barrier template ---------------------
// 128(M)x256(N) tile, 8 waves (2x4), wave 64x64, 48 BK32 ktiles (=1536 k of
// the 12288 3-phase K), KSPL=8. Slot = A 8KB + B 16KB = 24KB; 3 loads/stage ->
// vmcnt(3); control flow identical to conv's light-v loop (proven r11+).
// Segment (Qhi/Qlo x Khi/Klo) resolved per-stage; crossings ktile-aligned.
__global__ __launch_bounds__(512, 2) void qk_k(
    const unsigned short* __restrict__ Qhi, const unsigned short* __restrict__ Qlo,
    const unsigned short* __restrict__ Khi, const unsigned short* __restrict__ Klo,
    float* __restrict__ attn)
{
  __shared__ __align__(16) unsigned char smem[4 * 24576];
  const int tid = threadIdx.x;
  const int lane = tid & 63;
  const int wid = tid >> 6;
  const int wr = wid >> 2;            // 0..1 (M)
  const int wc = wid & 3;             // 0..3 (N)

  // XCD swizzle: xcd gets 8 consecutive works = 2 (nt,ks) B-panels x 4 mt
  int orig = blockIdx.x;              // 0..63
  int work = (orig & 7) * 8 + (orig >> 3);
  const int mt = work & 3;
  const int nt = (work >> 2) & 1;
  const int ks = work >> 3;           // 0..7
  const int bidx = blockIdx.z;
  const int m0 = mt * 128;
  const int n0 = nt * 256;

  const int srow = tid >> 2;          // 0..127
  const int scu = tid & 3;
  const int scuS = scu ^ ((srow >> 1) & 3);
  const size_t rowA = ((size_t)bidx * CC + m0 + srow) * CN + scuS * 8;
  const size_t rowB = ((size_t)bidx * CC + n0 + srow) * CN + scuS * 8;
  const size_t rowB2 = rowB + (size_t)128 * CN;
  const int wofs = wid * 1024;

  int kk = ks * 1536;                 // scalar K cursor over [0, 12288)
  auto stageQ = [&](int slot) {
    int ph = kk >> 12;
    int kin = kk & (CN - 1);
    const unsigned short* Aq = (ph == 2) ? Qlo : Qhi;
    const unsigned short* Bk = (ph == 1) ? Klo : Khi;
    unsigned char* lA = smem + slot * 24576 + wofs;
    unsigned char* lB = smem + slot * 24576 + 8192 + wofs;
    g2lds16(Aq + rowA + kin, lA);
    g2lds16(Bk + rowB + kin, lB);
    g2lds16(Bk + rowB2 + kin, lB + 8192);
    kk += 32;
  };

  f32x4 acc[4][4];
  const f32x4 fz = {0.f, 0.f, 0.f, 0.f};
#pragma unroll
  for (int i = 0; i < 4; ++i)
#pragma unroll
    for (int j = 0; j < 4; ++j) acc[i][j] = fz;

  const int rAv = wr * 64 + (lane & 15);     // A rows 0..127
  const int rB = wc * 64 + (lane & 15);      // B rows 0..255
  const int kq = (lane >> 4) * 16;
  const int kqA = kq ^ (((rAv >> 1) & 3) << 4);
  const int kqB = kq ^ (((rB >> 1) & 3) << 4);

  stageQ(0);
  stageQ(1);
  asm volatile("s_waitcnt vmcnt(3)" ::: "memory");
  SCHED(); SBAR(); SCHED();
  bf16x8 afA[4], bfA[4], afB[4], bfB[4];
#pragma unroll
  for (int mf = 0; mf < 4; ++mf)
    afA[mf] = *(const bf16x8*)(smem + (rAv + mf * 16) * 64 + kqA);
#pragma unroll
  for (int nf = 0; nf < 4; ++nf)
    bfA[nf] = *(const bf16x8*)(smem + 8192 + (rB + nf * 16) * 64 + kqB);
  int slotC = 0, slotS = 2, t2 = 2;

#define QK_BODY(CURA, CURB, NXTA, NXTB)                                       \
  {                                                                           \
    if (t2 < 48) {                                                            \
      stageQ(slotS); slotS = (slotS + 1) & 3;                                 \
      asm volatile("s_waitcnt vmcnt(3)" ::: "memory");                        \
    } else {                                                                  \
      asm volatile("s_waitcnt vmcnt(0)" ::: "memory");                        \
    }                                                                         \
    SCHED(); SBAR(); SCHED();                                                 \
    const int slotN = (slotC + 1) & 3;                                        \
    const unsigned char* lAn = smem + slotN * 24576;                          \
    _Pragma("unroll")                                                         \
    for (int mf = 0; mf < 4; ++mf)                                            \
      NXTA[mf] = *(const bf16x8*)(lAn + (rAv + mf * 16) * 64 + kqA);          \
    _Pragma("unroll")                                                         \
    for (int nf = 0; nf < 4; ++nf)                                            \
      NXTB[nf] = *(const bf16x8*)(lAn + 8192 + (rB + nf * 16) * 64 + kqB);    \
    __builtin_amdgcn_s_setprio(1);                                            \
    _Pragma("unroll")                                                         \
    for (int mf = 0; mf < 4; ++mf) {                                          \
      _Pragma("unroll")                                                       \
      for (int nf = 0; nf < 4; ++nf)                                          \
        acc[mf][nf] = __builtin_amdgcn_mfma_f32_16x16x32_bf16(                \
            CURA[mf], CURB[nf], acc[mf][nf], 0, 0, 0);                        \
    }                                                                         \
    __builtin_amdgcn_s_setprio(0);                                            \
    slotC = slotN;                                                            \
    ++t2;                                                                     \
  }

  for (int t = 0; t < 48; t += 2) {
    QK_BODY(afA, bfA, afB, bfB)
    QK_BODY(afB, bfB, afA, bfA)
  }
#undef QK_BODY

  size_t pbase = (size_t)ks * ((size_t)BCH * CC * CC);
#pragma unroll
  for (int mf = 0; mf < 4; ++mf) {
#pragma unroll
    for (int nf = 0; nf < 4; ++nf) {
      f32x4 a = acc[mf][nf];
      int mrow = m0 + wr * 64 + mf * 16 + ((lane >> 4) << 2);
      int ncol = n0 + wc * 64 + nf * 16 + (lane & 15);
#pragma unroll
      for (int j = 0; j < 4; ++j)
        attn[pbase + ((size_t)bidx * CC + (mrow + j)) * CC + ncol] = a[j];
    }
  }
}

// ---- PV GEMM (old MODE-2 path, unchanged) ----------------------------------
DI int sofs(int row, int kb) { return row * 128 + (kb ^ ((row & 7) << 4)); }

__global__ __launch_bounds__(256) void pv_k(
    const unsigned short* __restrict__ Vt,
    const unsigned short* __restrict__ P,
    const float* __restrict__ xin,
    const float* __restrict__ gamma,
    float* __restrict__ out)
{
  __shared__ __align__(16) unsigned char sA[16384];
  __shared__ __align__(16) unsigned char sB[16384];
  const int tid = threadIdx.x;
  const int lane = tid & 63;
  const int wav = tid >> 6;
  const int wr = wav >> 1, wc = wav & 1;

  const int m0 = (blockIdx.x & 3) * 128;
  const int n0 = (blockIdx.x >> 2) * 128;
  const int bidx = blockIdx.z;

  auto stage = [&](int k0) {
#pragma unroll
    for (int q = 0; q < 4; ++q) {
      int ci = q * 256 + tid;
      int row = ci >> 3;
      int ke = ((ci & 7) ^ (row & 7)) * 8;
      const unsigned short* ap = P + ((size_t)bidx * CC + (m0 + row)) * CC + (k0 + ke);
      const unsigned short* bp = Vt + ((size_t)bidx * CN + (n0 + row)) * CC + (k0 + ke);
      int wbase = (q * 256 + wav * 64) * 16;
      g2lds16(ap, sA + wbase);
      g2lds16(bp, sB + wbase);
    }
  };

  f32x4 acc[4][4];
  const f32x4 fz = {0.f, 0.f, 0.f, 0.f};
#pragma unroll
  for (int i = 0; i < 4; ++i)
#pragma unroll
    for (int j = 0; j < 4; ++j) acc[i][j] = fz;

  for (int k0 = 0; k0 < CC; k0 += 64) {
    stage(k0);
    __syncthreads();
#pragma unroll
    for (int kkp = 0; kkp < 2; ++kkp) {
      bf16x8 af[4], bfv[4];
#pragma unroll
      for (int mf = 0; mf < 4; ++mf)
        af[mf] = *(const bf16x8*)&sA[sofs(wr * 64 + mf * 16 + (lane & 15),
                                          kkp * 64 + (lane >> 4) * 16)];
#pragma unroll
      for (int nf = 0; nf < 4; ++nf)
        bfv[nf] = *(const bf16x8*)&sB[sofs(wc * 64 + nf * 16 + (lane & 15),
                                           kkp * 64 + (lane >> 4) * 16)];
#pragma unroll
      for (int mf = 0; mf < 4; ++mf)
#pragma unroll
        for (int nf = 0; nf < 4; ++nf)
          acc[mf][nf] = __builtin_amdgcn_mfma_f32_16x16x32_bf16(
              af[mf], bfv[nf], acc[mf][nf], 0, 0, 0);
    }
    __syncthreads();
  }

  float g = gamma[0];
#pragma unroll
  for (int mf = 0; mf < 4; ++mf) {
#pragma unroll
    for (int nf = 0; nf < 4; ++nf) {
      f32x4 a = acc[mf][nf];
      int mrow = m0 + wr * 64 + mf * 16 + ((lane >> 4) << 2);
      int ncol = n0 + wc * 64 + nf * 16 + (lane & 15);
#pragma unroll
      for (int j = 0; j < 4; ++j) {
        size_t o = ((size_t)bidx * CC + (mrow + j)) * CN + ncol;
        out[o] = g * a[j] + xin[o];
      }
    }
  }
}

// ---- softmax over d (512): sum KSPL split-K partials, one wave per row -----
__global__ __launch_bounds__(256) void softmax_k(const float* __restrict__ attn,
                                                 unsigned short* __restrict__ P) {
  int row = blockIdx.x * 4 + (threadIdx.x >> 6);
  int lane = threadIdx.x & 63;
  constexpr size_t PS = (size_t)BCH * CC * CC;
  const float* rp = attn + (size_t)row * 512 + lane * 8;
  f32x4 a = {0.f, 0.f, 0.f, 0.f};
  f32x4 b = {0.f, 0.f, 0.f, 0.f};
#pragma unroll
  for (int ksp = 0; ksp < KSPL; ++ksp) {
    a += *(const f32x4*)(rp + (size_t)ksp * PS);
    b += *(const f32x4*)(rp + (size_t)ksp * PS + 4);
  }
  float mx = fmaxf(fmaxf(fmaxf(a[0], a[1]), fmaxf(a[2], a[3])),
                   fmaxf(fmaxf(b[0], b[1]), fmaxf(b[2], b[3])));
#pragma unroll
  for (int s = 32; s > 0; s >>= 1) mx = fmaxf(mx, __shfl_xor(mx, s, 64));
  float e[8];
  float sum = 0.f;
#pragma unroll
  for (int j = 0; j < 4; ++j) { e[j] = __expf(a[j] - mx); sum += e[j]; }
#pragma unroll
  for (int j = 0; j < 4; ++j) { e[4 + j] = __expf(b[j] - mx); sum += e[4 + j]; }
#pragma unroll
  for (int s = 32; s > 0; s >>= 1) sum += __shfl_xor(sum, s, 64);
  float inv = 1.0f / sum;
  u16x8 o;
#pragma unroll
  for (int j = 0; j < 8; ++j) o[j] = f2bf(e[j] * inv);
  *(u16x8*)&P[(size_t)row * 512 + lane * 8] = o;
}

// ---- diagnostic: fill out with sentinel if workspace is too small ----------
__global__ __launch_bounds__(256) void fill_sentinel(float* __restrict__ out, int n) {
  int i = blockIdx.x * 256 + threadIdx.x;
  if (i < n) out[i] = 1.0e4f;
}

// ---------------------------------------------------------------------------
extern "C" void kernel_launch(void* const* d_in, const int* in_sizes, int n_in,
                              void* d_out, int out_size, void* d_ws, size_t ws_size,
                              hipStream_t stream) {
  (void)in_sizes; (void)n_in;
  const float* x  = (const float*)d_in[0];
  const float* wq = (const float*)d_in[1];
  const float* bq = (const float*)d_in[2];
  const float* wk = (const float*)d_in[3];
  const float* bk = (const float*)d_in[4];
  const float* wv = (const float*)d_in[5];
  const float* bv = (const float*)d_in[6];
  const float* gm = (const float*)d_in[7];
  float* out = (float*)d_out;

  uint8_t* wsp = (uint8_t*)d_ws;
  auto take = [&](size_t bytes) {
    uint8_t* p = wsp;
    wsp += (bytes + 255) & ~(size_t)255;
    return p;
  };
  unsigned short* Xhi = (unsigned short*)take(XSPLIT * 2);          // 17.8 MB
  unsigned char*  X8  = (unsigned char*)take(2 * XSPLIT);           // 35.7 MB
  unsigned short* Ahi = (unsigned short*)take((size_t)MR * K1 * 2); // 13.5 MB
  unsigned char*  A8  = (unsigned char*)take((size_t)MR * 2 * K1);  // 13.5 MB
  float* bias         = (float*)take((size_t)MR * 4);
  unsigned short* Khi = (unsigned short*)take((size_t)BCH * CC * CN * 2);  // 16.8 MB
  unsigned short* Klo = (unsigned short*)take((size_t)BCH * CC * CN * 2);  // 16.8 MB
  unsigned short* Vt  = (unsigned short*)take((size_t)BCH * CN * CC * 2);  // 16.8 MB
  // attn (KSPL=8 partials, 33.55MB) + P (2.1MB) alias Xhi+X8 (53.5MB region,
  // dead after conv); interiors rewritten by prep_xpad, pads re-zeroed/chunk.
  float* attn         = (float*)Xhi;
  unsigned short* P   = (unsigned short*)((uint8_t*)Xhi +
                          (size_t)KSPL * BCH * CC * CC * 4 + 256);

  size_t needed = (size_t)(wsp - (uint8_t*)d_ws);   // ~113 MB
  if (ws_size < needed) {
    fill_sentinel<<<(out_size + 255) / 256, 256, 0, stream>>>(out, out_size);
    return;
  }

  for (int ch = 0; ch < CB / BCH; ++ch) {
    const float* xch = x + (size_t)ch * BCH * CC * CN;
    float* outch = out + (size_t)ch * BCH * CC * CN;
    unsigned short* Qhi = (unsigned short*)outch;   // Q pair lives in d_out
    unsigned short* Qlo = Qhi + (size_t)BCH * CC * CN;

    pad_zero<<<(4 * 260 * 16 + 255) / 256, 256, 0, stream>>>(Xhi, X8);
    prep_xpad<<<BCH * 16 * 64, 256, 0, stream>>>(xch, Xhi, X8);
    if (ch == 0)
      prep_abig<<<(MR * K1) / 256, 256, 0, stream>>>(wq, wk, wv, bq, bk, bv,
                                                     Ahi, A8, bias);
    conv_k<<<dim3(512), 512, 0, stream>>>(Ahi, A8, Xhi, X8, bias,
                                          Qhi, Qlo, Khi, Klo, Vt);
    qk_k<<<dim3(64, 1, BCH), 512, 0, stream>>>(Qhi, Qlo, Khi, Klo, attn);
    softmax_k<<<BCH * 128, 256, 0, stream>>>(attn, P);
    pv_k<<<dim3(128, 1, BCH), 256, 0, stream>>>(Vt, P, xch, gm, outch);
  }
}

// Round 15
// 942.167 us; speedup vs baseline: 1.8369x; 1.0032x over previous
//
#include <hip/hip_runtime.h>
#include <stdint.h>

typedef __attribute__((ext_vector_type(8))) short bf16x8;
typedef __attribute__((ext_vector_type(4))) float f32x4;
typedef __attribute__((ext_vector_type(4))) int i32x4;
typedef __attribute__((ext_vector_type(8))) int i32x8;
typedef __attribute__((ext_vector_type(8))) unsigned short u16x8;
typedef __attribute__((ext_vector_type(4))) unsigned short u16x4;

#define DI static __device__ __forceinline__

constexpr int CB = 8;          // batch (total)
constexpr int BCH = 4;         // batches per chunk (2 chunks)
constexpr int CC = 512;        // channels
constexpr int CN = 4096;       // H*W
constexpr int K1 = CC * 9;     // 4608
constexpr int MR = 3 * CC;     // 1536 output rows (q|k|v)
constexpr int KSPL = 8;        // QK^T split-K factor
constexpr size_t XSPLIT = (size_t)BCH * 66 * 66 * 512;

DI unsigned short f2bf(float f) {
  union { float f; uint32_t u; } v; v.f = f;
  uint32_t r = (v.u + 0x7FFFu + ((v.u >> 16) & 1u)) >> 16;  // RNE
  return (unsigned short)r;
}
DI float bf2f(unsigned short h) {
  union { uint32_t u; float f; } v; v.u = ((uint32_t)h) << 16;
  return v.f;
}
// manual OCP e4m3fn convert (RNE on mantissa; sat to 448); input |x| << 448 here
DI unsigned char f2e4m3(float x) {
  union { float f; uint32_t u; } v; v.f = x;
  uint32_t sgn = (v.u >> 24) & 0x80u;
  float a = fabsf(x);
  if (a < 0.015625f) {                       // subnormal: quantum 2^-9
    int qi = (int)rintf(a * 512.f);          // 0..8 (8 -> min normal 0x08)
    return (unsigned char)(sgn | (uint32_t)qi);
  }
  int e = (int)((v.u >> 23) & 0xff) - 127;
  uint32_t m3 = (v.u >> 20) & 7u;
  uint32_t rest = v.u & 0xFFFFFu;
  if (rest > 0x80000u || (rest == 0x80000u && (m3 & 1u))) {
    if (++m3 == 8u) { m3 = 0; ++e; }
  }
  if (e > 8 || (e == 8 && m3 == 7u)) return (unsigned char)(sgn | 0x7Eu);
  return (unsigned char)(sgn | ((uint32_t)(e + 7) << 3) | m3);
}

DI void g2lds16(const void* g, void* l) {
  __builtin_amdgcn_global_load_lds((const __attribute__((address_space(1))) void*)g,
                                   (__attribute__((address_space(3))) void*)l, 16, 0, 0);
}
#define SBAR()  __builtin_amdgcn_s_barrier()
#define SCHED() __builtin_amdgcn_sched_barrier(0)
// T19: LLVM SchedGroupMask MFMA=0x8, DS_READ=0x100
#define SGB(mask, n) __builtin_amdgcn_sched_group_barrier(mask, n, 0)

// ---- prep 0: zero only the pad border cells --------------------------------
__global__ __launch_bounds__(256) void pad_zero(unsigned short* __restrict__ Xhi,
                                                unsigned char* __restrict__ X8) {
  int id = blockIdx.x * 256 + threadIdx.x;
  if (id >= 4 * 260 * 16) return;
  int t = id & 15;
  int pp = (id >> 4) % 260;
  int b = id / (260 * 16);
  int hh, ww;
  if (pp < 66)       { hh = 0;  ww = pp; }
  else if (pp < 132) { hh = 65; ww = pp - 66; }
  else if (pp < 196) { hh = pp - 131; ww = 0; }
  else               { hh = pp - 195; ww = 65; }
  size_t pix = (((size_t)b * 66 + hh) * 66 + ww) * 512 + (size_t)t * 32;
  const u16x8 z = {0, 0, 0, 0, 0, 0, 0, 0};
  *(u16x8*)&Xhi[pix] = z;  *(u16x8*)&Xhi[pix + 8] = z;
  *(u16x8*)&Xhi[pix + 16] = z;  *(u16x8*)&Xhi[pix + 24] = z;
  const i32x4 z4 = {0, 0, 0, 0};
  *(i32x4*)&X8[pix] = z4;  *(i32x4*)&X8[pix + 16] = z4;
  *(i32x4*)&X8[XSPLIT + pix] = z4;  *(i32x4*)&X8[XSPLIT + pix + 16] = z4;
}

// ---- prep 1: Xhi (bf16, x2^7), X8 split0=Xlo8 (x2^8), split1=Xhi8 (x1) -----
__global__ __launch_bounds__(256) void prep_xpad(const float* __restrict__ x,
                                                 unsigned short* __restrict__ Xhi,
                                                 unsigned char* __restrict__ X8) {
  int tid = threadIdx.x;
  int w = tid & 63;
  int ccl = tid >> 6;
  int blk = blockIdx.x;               // 4096 = b(4) * ccg(16) * h(64)
  int h = blk & 63;
  int ccg = (blk >> 6) & 15;
  int b = blk >> 10;
  int c0 = (ccg * 4 + ccl) * 8;
  const float* xp = x + ((size_t)b * CC) * CN + h * 64 + w;
  u16x8 hi;
  unsigned long long lo8 = 0, hi8 = 0;
#pragma unroll
  for (int j = 0; j < 8; ++j) {
    float v = xp[(size_t)(c0 + j) * CN];
    unsigned short h16 = f2bf(v);
    float vhi = bf2f(h16);
    hi[j] = f2bf(vhi * 128.f);                    // exact shift
    lo8 |= (unsigned long long)f2e4m3((v - vhi) * 256.f) << (8 * j);
    hi8 |= (unsigned long long)f2e4m3(vhi) << (8 * j);
  }
  size_t pix = (((size_t)b * 66 + (h + 1)) * 66 + (w + 1)) * 512;
  *(u16x8*)&Xhi[pix + c0] = hi;
  *(unsigned long long*)&X8[pix + c0] = lo8;
  *(unsigned long long*)&X8[XSPLIT + pix + c0] = hi8;
}

// ---- prep 2: Ahi [1536][4608] bf16 (x2^7), A8 [1536][9216] fp8 plain -------
__global__ __launch_bounds__(256) void prep_abig(
    const float* __restrict__ wq, const float* __restrict__ wk,
    const float* __restrict__ wv, const float* __restrict__ bq,
    const float* __restrict__ bk, const float* __restrict__ bv,
    unsigned short* __restrict__ Ahi, unsigned char* __restrict__ A8,
    float* __restrict__ bias) {
  unsigned id = blockIdx.x * 256 + threadIdx.x;   // total 1536*4608
  int m = id / K1;
  int r = id - m * K1;
  int t = r >> 9;
  int c = r & 511;
  int ky = t / 3;
  int kx = t - ky * 3;
  size_t ip = (size_t)m * 9216 + r;
  if (m < 1024) {
    const float* wp = (m < 512) ? wq : wk;
    int mm = (m < 512) ? m : m - 512;
    float wval = wp[(((size_t)mm * 512 + c) * 3 + ky) * 3 + kx];
    float whi = bf2f(f2bf(wval));
    Ahi[id] = f2bf(whi * 128.f);
    A8[ip] = f2e4m3(whi * 64.f);
    A8[ip + 4608] = f2e4m3((wval - whi) * 16384.f);
  } else {
    float wval = wv[(((size_t)(m - 1024) * 512 + c) * 3 + ky) * 3 + kx];
    Ahi[id] = f2bf(wval * 128.f);
    A8[ip] = 0;
    A8[ip + 4608] = 0;
  }
  if (id < 1536) {
    int mm = (int)id;
    bias[mm] = (mm < 512) ? bq[mm] : (mm < 1024) ? bk[mm - 512] : bv[mm - 1024];
  }
}

// ---- conv GEMM: 4-slot ring, bf16 phase1 + MX-scaled fp8 K=128 phase2 ------
// r15: T19 sched_group_barrier interleave. r14's cycle ledger shows wall/body
// (~2700cy) = LDS-pipe busy (1408) + MFMA busy (1242) SERIAL: waves issue
// ds_reads in clusters between MFMA clusters, so the pipes alternate. The
// SGB patterns force the emitter to spread DS_READs among MFMAs (pure
// compile-time directive: no sync or numeric change).
__global__ __launch_bounds__(512, 2) void conv_k(
    const unsigned short* __restrict__ Ahi,
    const unsigned char* __restrict__ A8,
    const unsigned short* __restrict__ Xhi,
    const unsigned char* __restrict__ X8,
    const float* __restrict__ bias,
    unsigned short* __restrict__ Qhi, unsigned short* __restrict__ Qlo,
    unsigned short* __restrict__ Khi, unsigned short* __restrict__ Klo,
    unsigned short* __restrict__ Vt)
{
  __shared__ __align__(16) unsigned char smem[4 * 32768];
  const int tid = threadIdx.x;
  const int lane = tid & 63;
  const int wid = tid >> 6;
  const int wr = wid >> 2;            // 0..1 (M)
  const int wc = wid & 3;             // 0..3 (N)

  int orig = blockIdx.x;
  int xcd, nbl, m0;
  if (orig < 256) {                   // heavy q/k: 256x256
    xcd = orig & 7; int j = orig >> 3;
    nbl = j >> 2;
    m0 = (j & 3) * 256;               // 0..768
  } else {                            // light v: 128x256
    int o = orig - 256;
    xcd = o & 7; int j = o >> 3;      // 0..31
    nbl = j >> 2;
    m0 = 1024 + (j & 3) * 128;        // 1024..1408
  }
  const int nb = xcd * 8 + nbl;
  const int n0 = nb * 256;
  const int bidx = n0 >> 12;
  const int nl0 = n0 & (CN - 1);
  const int h0 = nl0 >> 6;

  const int srow = tid >> 2;          // 0..127
  const int scu = tid & 3;
  const int scuS = scu ^ ((srow >> 1) & 3);
  const int d8 = (scuS & 1) ? -16 : 16;
  const size_t pixOfs = (((size_t)(bidx * 66 + h0 + (srow >> 6))) * 66 + (srow & 63)) * 512;
  const unsigned short* gAh0 = Ahi + (size_t)(m0 + srow) * K1 + scuS * 8;
  const unsigned short* gAh1 = gAh0 + (size_t)128 * K1;
  const unsigned short* gBh0 = Xhi + pixOfs + scuS * 8;
  const unsigned short* gBh1 = gBh0 + (size_t)2 * 66 * 512;
  const unsigned char* gA80 = A8 + (size_t)(m0 + srow) * 9216 + scuS * 16;
  const unsigned char* gA81 = gA80 + (size_t)128 * 9216;
  const unsigned char* gB80 = X8 + pixOfs + scuS * 16;
  const unsigned char* gB81 = gB80 + (size_t)2 * 66 * 512;
  const int wofs = wid * 1024;

  int c0S = 0, kxS = 0, tapS = 0;
  size_t tapOfs = 0;
  auto stage1 = [&](int slot) {       // heavy: 4 loads
    int aOfs = tapS * 512 + c0S;
    size_t bOfs = tapOfs + (size_t)c0S;
    unsigned char* lA = smem + slot * 32768 + wofs;
    unsigned char* lB = smem + slot * 32768 + 16384 + wofs;
    g2lds16(gAh0 + aOfs, lA);
    g2lds16(gAh1 + aOfs, lA + 8192);
    g2lds16(gBh0 + bOfs, lB);
    g2lds16(gBh1 + bOfs, lB + 8192);
    c0S += 32;
    if (c0S == 512) {
      c0S = 0; ++tapS;
      if (kxS == 2) { kxS = 0; tapOfs += (size_t)64 * 512; }
      else { ++kxS; tapOfs += 512; }
    }
  };
  auto stage1v = [&](int slot) {      // light: 3 loads (A is 128 rows)
    int aOfs = tapS * 512 + c0S;
    size_t bOfs = tapOfs + (size_t)c0S;
    unsigned char* lA = smem + slot * 32768 + wofs;
    unsigned char* lB = smem + slot * 32768 + 16384 + wofs;
    g2lds16(gAh0 + aOfs, lA);
    g2lds16(gBh0 + bOfs, lB);
    g2lds16(gBh1 + bOfs, lB + 8192);
    c0S += 32;
    if (c0S == 512) {
      c0S = 0; ++tapS;
      if (kxS == 2) { kxS = 0; tapOfs += (size_t)64 * 512; }
      else { ++kxS; tapOfs += 512; }
    }
  };
  int c8 = 0, kx8 = 0, tap8 = 0, s8 = 0;
  size_t tapOfs8 = 0;
  auto stage2 = [&](int slot) {
    int so = (slot & 1) ? d8 : 0;
    int aOfs = s8 * 4608 + tap8 * 512 + c8;
    size_t bOfs = (size_t)s8 * XSPLIT + tapOfs8 + (size_t)c8;
    unsigned char* lA = smem + slot * 32768 + wofs;
    unsigned char* lB = smem + slot * 32768 + 16384 + wofs;
    g2lds16(gA80 + aOfs + so, lA);
    g2lds16(gA81 + aOfs + so, lA + 8192);
    g2lds16(gB80 + bOfs + so, lB);
    g2lds16(gB81 + bOfs + so, lB + 8192);
    c8 += 64;
    if (c8 == 512) {
      c8 = 0; ++tap8;
      if (tap8 == 9) { tap8 = 0; kx8 = 0; tapOfs8 = 0; ++s8; }
      else if (kx8 == 2) { kx8 = 0; tapOfs8 += (size_t)64 * 512; }
      else { ++kx8; tapOfs8 += 512; }
    }
  };

  f32x4 acc[8][4];
  const f32x4 fz = {0.f, 0.f, 0.f, 0.f};
#pragma unroll
  for (int i = 0; i < 8; ++i)
#pragma unroll
    for (int j = 0; j < 4; ++j) acc[i][j] = fz;

  const int kq = (lane >> 4) * 16;
  int slotC, slotS, t2;

  if (m0 < 1024) {
    const int rA = wr * 128 + (lane & 15);
    const int rB = wc * 64 + (lane & 15);
    const int kqA = kq ^ (((rA >> 1) & 3) << 4);
    const int kqB = kq ^ (((rB >> 1) & 3) << 4);

    stage1(0);
    stage1(1);
    asm volatile("s_waitcnt vmcnt(4)" ::: "memory");
    SCHED(); SBAR(); SCHED();
    {
      bf16x8 afA[4], bfA[4], afB[4], bfB[4], af1[4];
#pragma unroll
      for (int mf = 0; mf < 4; ++mf)
        afA[mf] = *(const bf16x8*)(smem + (rA + mf * 16) * 64 + kqA);
#pragma unroll
      for (int nf = 0; nf < 4; ++nf)
        bfA[nf] = *(const bf16x8*)(smem + 16384 + (rB + nf * 16) * 64 + kqB);
      slotC = 0; slotS = 2; t2 = 2;

#define CONV_BF(CURA, CURB, NXTA, NXTB)                                       \
  {                                                                           \
    if (t2 < 144) {                                                           \
      stage1(slotS); slotS = (slotS + 1) & 3;                                 \
      asm volatile("s_waitcnt vmcnt(4)" ::: "memory");                        \
    } else {                                                                  \
      asm volatile("s_waitcnt vmcnt(0)" ::: "memory");                        \
    }                                                                         \
    SCHED(); SBAR(); SCHED();                                                 \
    const unsigned char* lA = smem + slotC * 32768;                           \
    const int slotN = (slotC + 1) & 3;                                        \
    const unsigned char* lAn = smem + slotN * 32768;                          \
    _Pragma("unroll")                                                         \
    for (int mf = 0; mf < 4; ++mf)                                            \
      af1[mf] = *(const bf16x8*)(lA + (rA + 64 + mf * 16) * 64 + kqA);        \
    __builtin_amdgcn_s_setprio(1);                                            \
    _Pragma("unroll")                                                         \
    for (int mf = 0; mf < 4; ++mf) {                                          \
      _Pragma("unroll")                                                       \
      for (int nf = 0; nf < 4; ++nf)                                          \
        acc[mf][nf] = __builtin_amdgcn_mfma_f32_16x16x32_bf16(                \
            CURA[mf], CURB[nf], acc[mf][nf], 0, 0, 0);                        \
    }                                                                         \
    _Pragma("unroll")                                                         \
    for (int mf = 0; mf < 4; ++mf)                                            \
      NXTA[mf] = *(const bf16x8*)(lAn + (rA + mf * 16) * 64 + kqA);           \
    _Pragma("unroll")                                                         \
    for (int nf = 0; nf < 4; ++nf)                                            \
      NXTB[nf] = *(const bf16x8*)(lAn + 16384 + (rB + nf * 16) * 64 + kqB);   \
    _Pragma("unroll")                                                         \
    for (int mf = 0; mf < 4; ++mf) {                                          \
      _Pragma("unroll")                                                       \
      for (int nf = 0; nf < 4; ++nf)                                          \
        acc[mf + 4][nf] = __builtin_amdgcn_mfma_f32_16x16x32_bf16(            \
            af1[mf], CURB[nf], acc[mf + 4][nf], 0, 0, 0);                     \
    }                                                                         \
    __builtin_amdgcn_s_setprio(0);                                            \
    SGB(0x100, 3); SGB(0x8, 8);                                               \
    SGB(0x100, 3); SGB(0x8, 8);                                               \
    SGB(0x100, 3); SGB(0x8, 8);                                               \
    SGB(0x100, 3); SGB(0x8, 8);                                               \
    slotC = slotN;                                                            \
    ++t2;                                                                     \
  }

      for (int t = 0; t < 144; t += 2) {
        CONV_BF(afA, bfA, afB, bfB)
        CONV_BF(afB, bfB, afA, bfA)
      }
#undef CONV_BF
    }

    // ---- phase 2': scaled fp8, 72 pair-bodies of K=128 ----
    stage2(0); stage2(1);
    SCHED(); SBAR(); SCHED();
    stage2(2); stage2(3);
    {
      const int gq = lane >> 4;
      const int slotByte = (gq >> 1) << 15;
      const int cb2 = (gq & 1) * 2;
      const int fx = (((lane & 15) >> 1) & 3) ^ (gq >> 1);
      const int bo0 = ((cb2 ^ fx) << 4);
      const int bo1 = (((cb2 + 1) ^ fx) << 4);
      const int aRow = wr * 128 + (lane & 15);
      const int bRow = wc * 64 + (lane & 15);
      i32x8 aF[4], bF[4];
      for (int p = 0; p < 72; ++p) {
        SCHED(); SBAR(); SCHED();
        if (p < 71) { asm volatile("s_waitcnt vmcnt(8)" ::: "memory"); }
        else        { asm volatile("s_waitcnt vmcnt(0)" ::: "memory"); }
        SCHED();
        const unsigned char* pbA = smem + ((p & 1) << 16) + slotByte + aRow * 64;
        const unsigned char* pbB = smem + ((p & 1) << 16) + slotByte + 16384 + bRow * 64;
#pragma unroll
        for (int t = 0; t < 4; ++t) {
          *(i32x4*)&bF[t] = *(const i32x4*)(pbB + t * 1024 + bo0);
          *((i32x4*)&bF[t] + 1) = *(const i32x4*)(pbB + t * 1024 + bo1);
        }
#pragma unroll
        for (int s = 0; s < 4; ++s) {
          *(i32x4*)&aF[s] = *(const i32x4*)(pbA + s * 1024 + bo0);
          *((i32x4*)&aF[s] + 1) = *(const i32x4*)(pbA + s * 1024 + bo1);
        }
        __builtin_amdgcn_s_setprio(1);
#pragma unroll
        for (int s = 0; s < 4; ++s)
#pragma unroll
          for (int t = 0; t < 4; ++t)
            acc[s][t] = __builtin_amdgcn_mfma_scale_f32_16x16x128_f8f6f4(
                aF[s], bF[t], acc[s][t], 0, 0, 0, 127, 0, 127);
#pragma unroll
        for (int s = 0; s < 4; ++s) {
          *(i32x4*)&aF[s] = *(const i32x4*)(pbA + (4 + s) * 1024 + bo0);
          *((i32x4*)&aF[s] + 1) = *(const i32x4*)(pbA + (4 + s) * 1024 + bo1);
        }
#pragma unroll
        for (int s = 0; s < 4; ++s)
#pragma unroll
          for (int t = 0; t < 4; ++t)
            acc[s + 4][t] = __builtin_amdgcn_mfma_scale_f32_16x16x128_f8f6f4(
                aF[s], bF[t], acc[s + 4][t], 0, 0, 0, 127, 0, 127);
        __builtin_amdgcn_s_setprio(0);
        SGB(0x100, 3); SGB(0x8, 4);
        SGB(0x100, 3); SGB(0x8, 4);
        SGB(0x100, 3); SGB(0x8, 4);
        SGB(0x100, 3); SGB(0x8, 4);
        SGB(0x100, 3); SGB(0x8, 4);
        SGB(0x100, 3); SGB(0x8, 4);
        SGB(0x100, 3); SGB(0x8, 4);
        SGB(0x100, 3); SGB(0x8, 4);
        SCHED(); SBAR(); SCHED();
        if (p + 2 < 72) { stage2(2 * (p & 1)); stage2(2 * (p & 1) + 1); }
      }
    }
  } else {
    // =================== LIGHT v: 128x256, bf16 s0 only ====================
    const int rAv = wr * 64 + (lane & 15);
    const int rB = wc * 64 + (lane & 15);
    const int kqA = kq ^ (((rAv >> 1) & 3) << 4);
    const int kqB = kq ^ (((rB >> 1) & 3) << 4);

    stage1v(0);
    stage1v(1);
    asm volatile("s_waitcnt vmcnt(3)" ::: "memory");
    SCHED(); SBAR(); SCHED();
    bf16x8 afA[4], bfA[4], afB[4], bfB[4];
#pragma unroll
    for (int mf = 0; mf < 4; ++mf)
      afA[mf] = *(const bf16x8*)(smem + (rAv + mf * 16) * 64 + kqA);
#pragma unroll
    for (int nf = 0; nf < 4; ++nf)
      bfA[nf] = *(const bf16x8*)(smem + 16384 + (rB + nf * 16) * 64 + kqB);
    slotC = 0; slotS = 2; t2 = 2;

#define CONV_LV(CURA, CURB, NXTA, NXTB)                                       \
  {                                                                           \
    if (t2 < 144) {                                                           \
      stage1v(slotS); slotS = (slotS + 1) & 3;                                \
      asm volatile("s_waitcnt vmcnt(3)" ::: "memory");                        \
    } else {                                                                  \
      asm volatile("s_waitcnt vmcnt(0)" ::: "memory");                        \
    }                                                                         \
    SCHED(); SBAR(); SCHED();                                                 \
    const int slotN = (slotC + 1) & 3;                                        \
    const unsigned char* lAn = smem + slotN * 32768;                          \
    _Pragma("unroll")                                                         \
    for (int mf = 0; mf < 4; ++mf)                                            \
      NXTA[mf] = *(const bf16x8*)(lAn + (rAv + mf * 16) * 64 + kqA);          \
    _Pragma("unroll")                                                         \
    for (int nf = 0; nf < 4; ++nf)                                            \
      NXTB[nf] = *(const bf16x8*)(lAn + 16384 + (rB + nf * 16) * 64 + kqB);   \
    __builtin_amdgcn_s_setprio(1);                                            \
    _Pragma("unroll")                                                         \
    for (int mf = 0; mf < 4; ++mf) {                                          \
      _Pragma("unroll")                                                       \
      for (int nf = 0; nf < 4; ++nf)                                          \
        acc[mf][nf] = __builtin_amdgcn_mfma_f32_16x16x32_bf16(                \
            CURA[mf], CURB[nf], acc[mf][nf], 0, 0, 0);                        \
    }                                                                         \
    __builtin_amdgcn_s_setprio(0);                                            \
    SGB(0x100, 2); SGB(0x8, 4);                                               \
    SGB(0x100, 2); SGB(0x8, 4);                                               \
    SGB(0x100, 2); SGB(0x8, 4);                                               \
    SGB(0x100, 2); SGB(0x8, 4);                                               \
    slotC = slotN;                                                            \
    ++t2;                                                                     \
  }

    for (int t = 0; t < 144; t += 2) {
      CONV_LV(afA, bfA, afB, bfB)
      CONV_LV(afB, bfB, afA, bfA)
    }
#undef CONV_LV
  }

  // ---- epilogue: all products at scale 2^14 -> * 2^-14 ----
  constexpr float SC = 1.f / 16384.f;
  if (m0 < 1024) {
#pragma unroll
    for (int mf = 0; mf < 8; ++mf) {
#pragma unroll
      for (int nf = 0; nf < 4; ++nf) {
        f32x4 a = acc[mf][nf];
        int mrow = m0 + wr * 128 + mf * 16 + ((lane >> 4) << 2);
        int ncol = nl0 + wc * 64 + nf * 16 + (lane & 15);
        if (m0 < 512) {
#pragma unroll
          for (int j = 0; j < 4; ++j) {
            float v = a[j] * SC + bias[mrow + j];
            unsigned short h16 = f2bf(v);
            size_t o = ((size_t)bidx * CC + (mrow + j)) * CN + ncol;
            Qhi[o] = h16;
            Qlo[o] = f2bf(v - bf2f(h16));
          }
        } else {
#pragma unroll
          for (int j = 0; j < 4; ++j) {
            float v = a[j] * SC + bias[mrow + j];
            unsigned short h16 = f2bf(v);
            size_t o = ((size_t)bidx * CC + (mrow + j - 512)) * CN + ncol;
            Khi[o] = h16;
            Klo[o] = f2bf(v - bf2f(h16));
          }
        }
      }
    }
  } else {
#pragma unroll
    for (int mf = 0; mf < 4; ++mf) {
#pragma unroll
      for (int nf = 0; nf < 4; ++nf) {
        f32x4 a = acc[mf][nf];
        int mrow = m0 + wr * 64 + mf * 16 + ((lane >> 4) << 2);
        int ncol = nl0 + wc * 64 + nf * 16 + (lane & 15);
        u16x4 vs;                     // V written transposed: Vt[b][n][d]
#pragma unroll
        for (int j = 0; j < 4; ++j) vs[j] = f2bf(a[j] * SC + bias[mrow + j]);
        *(u16x4*)&Vt[((size_t)bidx * CN + ncol) * CC + (mrow - 1024)] = vs;
      }
    }
  }
}

// ---- QK^T: 4-slot/1-barrier template (r14) + T19 interleave ----------------
__global__ __launch_bounds__(512, 2) void qk_k(
    const unsigned short* __restrict__ Qhi, const unsigned short* __restrict__ Qlo,
    const unsigned short* __restrict__ Khi, const unsigned short* __restrict__ Klo,
    float* __restrict__ attn)
{
  __shared__ __align__(16) unsigned char smem[4 * 24576];
  const int tid = threadIdx.x;
  const int lane = tid & 63;
  const int wid = tid >> 6;
  const int wr = wid >> 2;            // 0..1 (M)
  const int wc = wid & 3;             // 0..3 (N)

  int orig = blockIdx.x;              // 0..63
  int work = (orig & 7) * 8 + (orig >> 3);
  const int mt = work & 3;
  const int nt = (work >> 2) & 1;
  const int ks = work >> 3;           // 0..7
  const int bidx = blockIdx.z;
  const int m0 = mt * 128;
  const int n0 = nt * 256;

  const int srow = tid >> 2;          // 0..127
  const int scu = tid & 3;
  const int scuS = scu ^ ((srow >> 1) & 3);
  const size_t rowA = ((size_t)bidx * CC + m0 + srow) * CN + scuS * 8;
  const size_t rowB = ((size_t)bidx * CC + n0 + srow) * CN + scuS * 8;
  const size_t rowB2 = rowB + (size_t)128 * CN;
  const int wofs = wid * 1024;

  int kk = ks * 1536;                 // scalar K cursor over [0, 12288)
  auto stageQ = [&](int slot) {
    int ph = kk >> 12;
    int kin = kk & (CN - 1);
    const unsigned short* Aq = (ph == 2) ? Qlo : Qhi;
    const unsigned short* Bk = (ph == 1) ? Klo : Khi;
    unsigned char* lA = smem + slot * 24576 + wofs;
    unsigned char* lB = smem + slot * 24576 + 8192 + wofs;
    g2lds16(Aq + rowA + kin, lA);
    g2lds16(Bk + rowB + kin, lB);
    g2lds16(Bk + rowB2 + kin, lB + 8192);
    kk += 32;
  };

  f32x4 acc[4][4];
  const f32x4 fz = {0.f, 0.f, 0.f, 0.f};
#pragma unroll
  for (int i = 0; i < 4; ++i)
#pragma unroll
    for (int j = 0; j < 4; ++j) acc[i][j] = fz;

  const int rAv = wr * 64 + (lane & 15);     // A rows 0..127
  const int rB = wc * 64 + (lane & 15);      // B rows 0..255
  const int kq = (lane >> 4) * 16;
  const int kqA = kq ^ (((rAv >> 1) & 3) << 4);
  const int kqB = kq ^ (((rB >> 1) & 3) << 4);

  stageQ(0);
  stageQ(1);
  asm volatile("s_waitcnt vmcnt(3)" ::: "memory");
  SCHED(); SBAR(); SCHED();
  bf16x8 afA[4], bfA[4], afB[4], bfB[4];
#pragma unroll
  for (int mf = 0; mf < 4; ++mf)
    afA[mf] = *(const bf16x8*)(smem + (rAv + mf * 16) * 64 + kqA);
#pragma unroll
  for (int nf = 0; nf < 4; ++nf)
    bfA[nf] = *(const bf16x8*)(smem + 8192 + (rB + nf * 16) * 64 + kqB);
  int slotC = 0, slotS = 2, t2 = 2;

#define QK_BODY(CURA, CURB, NXTA, NXTB)                                       \
  {                                                                           \
    if (t2 < 48) {                                                            \
      stageQ(slotS); slotS = (slotS + 1) & 3;                                 \
      asm volatile("s_waitcnt vmcnt(3)" ::: "memory");                        \
    } else {                                                                  \
      asm volatile("s_waitcnt vmcnt(0)" ::: "memory");                        \
    }                                                                         \
    SCHED(); SBAR(); SCHED();                                                 \
    const int slotN = (slotC + 1) & 3;                                        \
    const unsigned char* lAn = smem + slotN * 24576;                          \
    _Pragma("unroll")                                                         \
    for (int mf = 0; mf < 4; ++mf)                                            \
      NXTA[mf] = *(const bf16x8*)(lAn + (rAv + mf * 16) * 64 + kqA);          \
    _Pragma("unroll")                                                         \
    for (int nf = 0; nf < 4; ++nf)                                            \
      NXTB[nf] = *(const bf16x8*)(lAn + 8192 + (rB + nf * 16) * 64 + kqB);    \
    __builtin_amdgcn_s_setprio(1);                                            \
    _Pragma("unroll")                                                         \
    for (int mf = 0; mf < 4; ++mf) {                                          \
      _Pragma("unroll")                                                       \
      for (int nf = 0; nf < 4; ++nf)                                          \
        acc[mf][nf] = __builtin_amdgcn_mfma_f32_16x16x32_bf16(                \
            CURA[mf], CURB[nf], acc[mf][nf], 0, 0, 0);                        \
    }                                                                         \
    __builtin_amdgcn_s_setprio(0);                                            \
    SGB(0x100, 2); SGB(0x8, 4);                                               \
    SGB(0x100, 2); SGB(0x8, 4);                                               \
    SGB(0x100, 2); SGB(0x8, 4);                                               \
    SGB(0x100, 2); SGB(0x8, 4);                                               \
    slotC = slotN;                                                            \
    ++t2;                                                                     \
  }

  for (int t = 0; t < 48; t += 2) {
    QK_BODY(afA, bfA, afB, bfB)
    QK_BODY(afB, bfB, afA, bfA)
  }
#undef QK_BODY

  size_t pbase = (size_t)ks * ((size_t)BCH * CC * CC);
#pragma unroll
  for (int mf = 0; mf < 4; ++mf) {
#pragma unroll
    for (int nf = 0; nf < 4; ++nf) {
      f32x4 a = acc[mf][nf];
      int mrow = m0 + wr * 64 + mf * 16 + ((lane >> 4) << 2);
      int ncol = n0 + wc * 64 + nf * 16 + (lane & 15);
#pragma unroll
      for (int j = 0; j < 4; ++j)
        attn[pbase + ((size_t)bidx * CC + (mrow + j)) * CC + ncol] = a[j];
    }
  }
}

// ---- PV GEMM (unchanged) ---------------------------------------------------
DI int sofs(int row, int kb) { return row * 128 + (kb ^ ((row & 7) << 4)); }

__global__ __launch_bounds__(256) void pv_k(
    const unsigned short* __restrict__ Vt,
    const unsigned short* __restrict__ P,
    const float* __restrict__ xin,
    const float* __restrict__ gamma,
    float* __restrict__ out)
{
  __shared__ __align__(16) unsigned char sA[16384];
  __shared__ __align__(16) unsigned char sB[16384];
  const int tid = threadIdx.x;
  const int lane = tid & 63;
  const int wav = tid >> 6;
  const int wr = wav >> 1, wc = wav & 1;

  const int m0 = (blockIdx.x & 3) * 128;
  const int n0 = (blockIdx.x >> 2) * 128;
  const int bidx = blockIdx.z;

  auto stage = [&](int k0) {
#pragma unroll
    for (int q = 0; q < 4; ++q) {
      int ci = q * 256 + tid;
      int row = ci >> 3;
      int ke = ((ci & 7) ^ (row & 7)) * 8;
      const unsigned short* ap = P + ((size_t)bidx * CC + (m0 + row)) * CC + (k0 + ke);
      const unsigned short* bp = Vt + ((size_t)bidx * CN + (n0 + row)) * CC + (k0 + ke);
      int wbase = (q * 256 + wav * 64) * 16;
      g2lds16(ap, sA + wbase);
      g2lds16(bp, sB + wbase);
    }
  };

  f32x4 acc[4][4];
  const f32x4 fz = {0.f, 0.f, 0.f, 0.f};
#pragma unroll
  for (int i = 0; i < 4; ++i)
#pragma unroll
    for (int j = 0; j < 4; ++j) acc[i][j] = fz;

  for (int k0 = 0; k0 < CC; k0 += 64) {
    stage(k0);
    __syncthreads();
#pragma unroll
    for (int kkp = 0; kkp < 2; ++kkp) {
      bf16x8 af[4], bfv[4];
#pragma unroll
      for (int mf = 0; mf < 4; ++mf)
        af[mf] = *(const bf16x8*)&sA[sofs(wr * 64 + mf * 16 + (lane & 15),
                                          kkp * 64 + (lane >> 4) * 16)];
#pragma unroll
      for (int nf = 0; nf < 4; ++nf)
        bfv[nf] = *(const bf16x8*)&sB[sofs(wc * 64 + nf * 16 + (lane & 15),
                                           kkp * 64 + (lane >> 4) * 16)];
#pragma unroll
      for (int mf = 0; mf < 4; ++mf)
#pragma unroll
        for (int nf = 0; nf < 4; ++nf)
          acc[mf][nf] = __builtin_amdgcn_mfma_f32_16x16x32_bf16(
              af[mf], bfv[nf], acc[mf][nf], 0, 0, 0);
    }
    __syncthreads();
  }

  float g = gamma[0];
#pragma unroll
  for (int mf = 0; mf < 4; ++mf) {
#pragma unroll
    for (int nf = 0; nf < 4; ++nf) {
      f32x4 a = acc[mf][nf];
      int mrow = m0 + wr * 64 + mf * 16 + ((lane >> 4) << 2);
      int ncol = n0 + wc * 64 + nf * 16 + (lane & 15);
#pragma unroll
      for (int j = 0; j < 4; ++j) {
        size_t o = ((size_t)bidx * CC + (mrow + j)) * CN + ncol;
        out[o] = g * a[j] + xin[o];
      }
    }
  }
}

// ---- softmax over d (512): sum KSPL split-K partials, one wave per row -----
__global__ __launch_bounds__(256) void softmax_k(const float* __restrict__ attn,
                                                 unsigned short* __restrict__ P) {
  int row = blockIdx.x * 4 + (threadIdx.x >> 6);
  int lane = threadIdx.x & 63;
  constexpr size_t PS = (size_t)BCH * CC * CC;
  const float* rp = attn + (size_t)row * 512 + lane * 8;
  f32x4 a = {0.f, 0.f, 0.f, 0.f};
  f32x4 b = {0.f, 0.f, 0.f, 0.f};
#pragma unroll
  for (int ksp = 0; ksp < KSPL; ++ksp) {
    a += *(const f32x4*)(rp + (size_t)ksp * PS);
    b += *(const f32x4*)(rp + (size_t)ksp * PS + 4);
  }
  float mx = fmaxf(fmaxf(fmaxf(a[0], a[1]), fmaxf(a[2], a[3])),
                   fmaxf(fmaxf(b[0], b[1]), fmaxf(b[2], b[3])));
#pragma unroll
  for (int s = 32; s > 0; s >>= 1) mx = fmaxf(mx, __shfl_xor(mx, s, 64));
  float e[8];
  float sum = 0.f;
#pragma unroll
  for (int j = 0; j < 4; ++j) { e[j] = __expf(a[j] - mx); sum += e[j]; }
#pragma unroll
  for (int j = 0; j < 4; ++j) { e[4 + j] = __expf(b[j] - mx); sum += e[4 + j]; }
#pragma unroll
  for (int s = 32; s > 0; s >>= 1) sum += __shfl_xor(sum, s, 64);
  float inv = 1.0f / sum;
  u16x8 o;
#pragma unroll
  for (int j = 0; j < 8; ++j) o[j] = f2bf(e[j] * inv);
  *(u16x8*)&P[(size_t)row * 512 + lane * 8] = o;
}

// ---- diagnostic: fill out with sentinel if workspace is too small ----------
__global__ __launch_bounds__(256) void fill_sentinel(float* __restrict__ out, int n) {
  int i = blockIdx.x * 256 + threadIdx.x;
  if (i < n) out[i] = 1.0e4f;
}

// ---------------------------------------------------------------------------
extern "C" void kernel_launch(void* const* d_in, const int* in_sizes, int n_in,
                              void* d_out, int out_size, void* d_ws, size_t ws_size,
                              hipStream_t stream) {
  (void)in_sizes; (void)n_in;
  const float* x  = (const float*)d_in[0];
  const float* wq = (const float*)d_in[1];
  const float* bq = (const float*)d_in[2];
  const float* wk = (const float*)d_in[3];
  const float* bk = (const float*)d_in[4];
  const float* wv = (const float*)d_in[5];
  const float* bv = (const float*)d_in[6];
  const float* gm = (const float*)d_in[7];
  float* out = (float*)d_out;

  uint8_t* wsp = (uint8_t*)d_ws;
  auto take = [&](size_t bytes) {
    uint8_t* p = wsp;
    wsp += (bytes + 255) & ~(size_t)255;
    return p;
  };
  unsigned short* Xhi = (unsigned short*)take(XSPLIT * 2);          // 17.8 MB
  unsigned char*  X8  = (unsigned char*)take(2 * XSPLIT);           // 35.7 MB
  unsigned short* Ahi = (unsigned short*)take((size_t)MR * K1 * 2); // 13.5 MB
  unsigned char*  A8  = (unsigned char*)take((size_t)MR * 2 * K1);  // 13.5 MB
  float* bias         = (float*)take((size_t)MR * 4);
  unsigned short* Khi = (unsigned short*)take((size_t)BCH * CC * CN * 2);  // 16.8 MB
  unsigned short* Klo = (unsigned short*)take((size_t)BCH * CC * CN * 2);  // 16.8 MB
  unsigned short* Vt  = (unsigned short*)take((size_t)BCH * CN * CC * 2);  // 16.8 MB
  float* attn         = (float*)Xhi;
  unsigned short* P   = (unsigned short*)((uint8_t*)Xhi +
                          (size_t)KSPL * BCH * CC * CC * 4 + 256);

  size_t needed = (size_t)(wsp - (uint8_t*)d_ws);   // ~113 MB
  if (ws_size < needed) {
    fill_sentinel<<<(out_size + 255) / 256, 256, 0, stream>>>(out, out_size);
    return;
  }

  for (int ch = 0; ch < CB / BCH; ++ch) {
    const float* xch = x + (size_t)ch * BCH * CC * CN;
    float* outch = out + (size_t)ch * BCH * CC * CN;
    unsigned short* Qhi = (unsigned short*)outch;   // Q pair lives in d_out
    unsigned short* Qlo = Qhi + (size_t)BCH * CC * CN;

    pad_zero<<<(4 * 260 * 16 + 255) / 256, 256, 0, stream>>>(Xhi, X8);
    prep_xpad<<<BCH * 16 * 64, 256, 0, stream>>>(xch, Xhi, X8);
    if (ch == 0)
      prep_abig<<<(MR * K1) / 256, 256, 0, stream>>>(wq, wk, wv, bq, bk, bv,
                                                     Ahi, A8, bias);
    conv_k<<<dim3(512), 512, 0, stream>>>(Ahi, A8, Xhi, X8, bias,
                                          Qhi, Qlo, Khi, Klo, Vt);
    qk_k<<<dim3(64, 1, BCH), 512, 0, stream>>>(Qhi, Qlo, Khi, Klo, attn);
    softmax_k<<<BCH * 128, 256, 0, stream>>>(attn, P);
    pv_k<<<dim3(128, 1, BCH), 256, 0, stream>>>(Vt, P, xch, gm, outch);
  }
}